// Round 11
// baseline (720.524 us; speedup 1.0000x reference)
//
#include <hip/hip_runtime.h>
#include <math.h>

static constexpr int NB = 2, NN = 256, HH = 256, DD = 64, LL = 6;
static constexpr int RN = NB * NN * HH;  // 131072

typedef __attribute__((ext_vector_type(8))) short bf16x8;
typedef __attribute__((ext_vector_type(4))) float f32x4;
typedef __attribute__((ext_vector_type(4))) float float4v;
typedef __attribute__((ext_vector_type(4))) unsigned int u32x4;

__device__ __forceinline__ float fsilu(float v) {
    return v * __builtin_amdgcn_rcpf(1.0f + __expf(-v));
}
__device__ __forceinline__ unsigned short f2bf(float f) {
    union { float f; unsigned int u; } x; x.f = f;
    unsigned int r = x.u + 0x7fffu + ((x.u >> 16) & 1u);
    return (unsigned short)(r >> 16);
}
__device__ __forceinline__ float bitsf(unsigned int u) {
    union { float f; unsigned int u; } x; x.u = u; return x.f;
}
__device__ __forceinline__ float bflo(unsigned int w) { return bitsf(w << 16); }
__device__ __forceinline__ float bfhi(unsigned int w) { return bitsf(w & 0xffff0000u); }
__device__ __forceinline__ unsigned int cvtpk(float lo, float hi) {
    unsigned int w;
    asm("v_cvt_pk_bf16_f32 %0, %1, %2" : "=v"(w) : "v"(lo), "v"(hi));
    return w;
}

// ---------------------------------------------------------------- convert (edge fragment-packed)
__global__ void k_convert(const float* __restrict__ ew2, const float* __restrict__ cw1,
                          unsigned short* __restrict__ ew2P, unsigned short* __restrict__ cw1P) {
    int g = blockIdx.x * blockDim.x + threadIdx.x;
    if (g >= LL * 8192) return;
    int l = g >> 13;
    int r = g & 8191;
    int lane = r & 63;
    int fidx = r >> 6;
    int ks = fidx >> 4;
    int wv = (fidx >> 1) & 7;
    int ct = fidx & 1;
    int col = wv * 32 + ct * 16 + (lane & 15);
    int k0 = ks * 32 + (lane >> 4) * 8;
    #pragma unroll
    for (int e = 0; e < 8; ++e) {
        ew2P[(size_t)g * 8 + e] = f2bf(ew2[((size_t)l * HH + k0 + e) * HH + col]);
        cw1P[(size_t)g * 8 + e] = f2bf(cw1[((size_t)l * HH + k0 + e) * HH + col]);
    }
}

// ---------------------------------------------------------------- convert2 (bf16 pair-packed GEMV weights)
__global__ void k_convert2(const float* __restrict__ nw1, const float* __restrict__ nw2,
                           const float* __restrict__ ew1,
                           unsigned short* __restrict__ nw1B, unsigned short* __restrict__ nw2B,
                           unsigned short* __restrict__ ew1B) {
    int idx = blockIdx.x * blockDim.x + threadIdx.x;
    if (idx >= LL * 131072) return;
    int l = idx >> 17;
    int r = idx & 131071;
    int c = r >> 8, col = r & 255;
    int dst = (l << 17) + ((c >> 1) << 9) + (col << 1) + (c & 1);
    nw1B[dst] = f2bf(nw1[(size_t)l * 131072 + c * 256 + col]);
    ew1B[dst] = f2bf(ew1[(size_t)l * 131328 + c * 256 + col]);  // 513*256 stride
    if (r < 65536) {
        int d2 = (l << 16) + ((c >> 1) << 9) + (col << 1) + (c & 1);
        nw2B[d2] = f2bf(nw2[(size_t)l * 65536 + c * 256 + col]);
    }
}

// ---------------------------------------------------------------- encoder (2 rows/block, broadcast staging)
__global__ __launch_bounds__(256) void k_encoder(
    const float* __restrict__ coords, const float* __restrict__ feats, const float* __restrict__ t,
    const float* __restrict__ pw1, const float* __restrict__ pb1,
    const float* __restrict__ pw2, const float* __restrict__ pb2,
    const float* __restrict__ pw3, const float* __restrict__ pb3,
    const float* __restrict__ tw1, const float* __restrict__ tb1,
    const float* __restrict__ tw2, const float* __restrict__ tb2,
    float* __restrict__ h, float* __restrict__ x) {
    __shared__ float spinT[68][2];
    __shared__ float shaT[HH][2];
    __shared__ float shbT[HH][2];
    __shared__ float ste1[HH];
    int tid = threadIdx.x;
    int base = blockIdx.x * 2;
    int b = base / NN;

    #pragma unroll
    for (int r = 0; r < 2; ++r) {
        int row = base + r;
        if (tid < 3) spinT[tid][r] = coords[row * 3 + tid];
        if (tid < DD) spinT[3 + tid][r] = feats[row * DD + tid];
    }
    float tv = t[b];
    ste1[tid] = fmaxf(tv * tw1[tid] + tb1[tid], 0.0f);
    if (tid < 6) {
        int r = tid / 3, c = tid % 3;
        x[(base + r) * 3 + c] = coords[(base + r) * 3 + c];
    }
    __syncthreads();

    float a0 = pb1[tid], a1 = a0;
    for (int c = 0; c < 67; ++c) {
        float w = pw1[c * HH + tid];
        float2 s = *(const float2*)&spinT[c][0];
        a0 += s.x * w; a1 += s.y * w;
    }
    shaT[tid][0] = fmaxf(a0, 0.f); shaT[tid][1] = fmaxf(a1, 0.f);
    __syncthreads();
    a0 = pb2[tid]; a1 = a0;
    for (int c = 0; c < HH; ++c) {
        float w = pw2[c * HH + tid];
        float2 s = *(const float2*)&shaT[c][0];
        a0 += s.x * w; a1 += s.y * w;
    }
    shbT[tid][0] = fmaxf(a0, 0.f); shbT[tid][1] = fmaxf(a1, 0.f);
    __syncthreads();
    a0 = pb3[tid]; a1 = a0;
    float te = tb2[tid];
    for (int c = 0; c < HH; ++c) {
        float w = pw3[c * HH + tid];
        float2 s = *(const float2*)&shbT[c][0];
        a0 += s.x * w; a1 += s.y * w;
        te += ste1[c] * tw2[c * HH + tid];
    }
    h[(base + 0) * HH + tid] = fmaxf(a0, 0.f) + te;
    h[(base + 1) * HH + tid] = fmaxf(a1, 0.f) + te;
}

// ---------------------------------------------------------------- LayerNorm + Ai/Aj (layer 0; bf16 ew1)
__global__ __launch_bounds__(256) void k_ln_aiaj(
    const float* __restrict__ h, const float* __restrict__ g, const float* __restrict__ bta,
    const unsigned int* __restrict__ ew1w, const float* __restrict__ eb1l,
    float* __restrict__ hn, float* __restrict__ Ai, unsigned short* __restrict__ AjB) {
    __shared__ float shnT[HH][2];
    int tid = threadIdx.x, wv = tid >> 6, lane = tid & 63;
    int base = blockIdx.x * 2;

    if (wv < 2) {
        int row = base + wv;
        float v[4];
        #pragma unroll
        for (int q = 0; q < 4; ++q) v[q] = h[row * HH + lane + 64 * q];
        float s = v[0] + v[1] + v[2] + v[3];
        #pragma unroll
        for (int m = 1; m < 64; m <<= 1) s += __shfl_xor(s, m);
        float mu = s * (1.0f / HH);
        float var = 0.f;
        #pragma unroll
        for (int q = 0; q < 4; ++q) { v[q] -= mu; var += v[q] * v[q]; }
        #pragma unroll
        for (int m = 1; m < 64; m <<= 1) var += __shfl_xor(var, m);
        float rstd = rsqrtf(var * (1.0f / HH) + 1e-5f);
        #pragma unroll
        for (int q = 0; q < 4; ++q) {
            int k = lane + 64 * q;
            float hv = v[q] * rstd * g[k] + bta[k];
            shnT[k][wv] = hv;
            hn[row * HH + k] = hv;
        }
    }
    __syncthreads();

    float ai0 = eb1l[tid], ai1 = ai0;
    float aj0 = 0.f, aj1 = 0.f;
    for (int c2 = 0; c2 < 128; ++c2) {
        unsigned int wip = ew1w[c2 * 256 + tid];
        unsigned int wjp = ew1w[(128 + c2) * 256 + tid];
        float4 s = *(const float4*)&shnT[c2 * 2][0];
        ai0 += s.x * bflo(wip) + s.z * bfhi(wip);
        ai1 += s.y * bflo(wip) + s.w * bfhi(wip);
        aj0 += s.x * bflo(wjp) + s.z * bfhi(wjp);
        aj1 += s.y * bflo(wjp) + s.w * bfhi(wjp);
    }
    Ai[(base + 0) * HH + tid] = ai0; AjB[(base + 0) * HH + tid] = f2bf(aj0);
    Ai[(base + 1) * HH + tid] = ai1; AjB[(base + 1) * HH + tid] = f2bf(aj1);
}

// ---------------------------------------------------------------- fused edge pipeline (MFMA)
// Round-8 structure (256 threads = 4 waves, 33KB LDS, j-halves; occupancy 45%
// proven) with the load-bearing fix: __launch_bounds__(256, 1). Round 8's
// (256,4) capped regalloc at 64 VGPR -> 90MB spill; min-blocks=1 un-caps
// (rounds 6/7/9: 120-128 VGPR, no spill). DO NOT raise arg2.
__global__ __launch_bounds__(256, 1) void k_edge(
    const float* __restrict__ x, const float* __restrict__ Ai, const unsigned short* __restrict__ AjB,
    const float* __restrict__ wd, const float* __restrict__ eb2v,
    const unsigned short* __restrict__ ew2P, const unsigned short* __restrict__ cw1P,
    const float* __restrict__ cb1v, const float* __restrict__ cw2v, const float* __restrict__ cb2p,
    float* __restrict__ maggH, float* __restrict__ xdeltaH) {
    __shared__ float cwpart[4][32];
    __shared__ unsigned short s_tile[32 * 256];  // 16KB, rows of 512B, XOR ((row&7)<<4)
    __shared__ unsigned short m_tile[32 * 256];  // 16KB

    int tid = threadIdx.x, wv = tid >> 6, lane = tid & 63;
    int g4 = lane >> 4, l15 = lane & 15;
    int bi = blockIdx.x;
    int half = bi & 1;
    int i = (bi >> 1) & 255;
    int b = bi >> 9;
    int ni = b * NN + i;
    int jb = b * NN + half * 128;

    int k0p = (tid & 31) << 3;
    float aiv[8], wdv[8];
    {
        float4v a0 = *(const float4v*)(Ai + (size_t)ni * HH + k0p);
        float4v a1 = *(const float4v*)(Ai + (size_t)ni * HH + k0p + 4);
        float4v w0 = *(const float4v*)(wd + k0p);
        float4v w1 = *(const float4v*)(wd + k0p + 4);
        #pragma unroll
        for (int e = 0; e < 4; ++e) { aiv[e] = a0[e]; aiv[4 + e] = a1[e]; wdv[e] = w0[e]; wdv[4 + e] = w1[e]; }
    }
    float eb2r[4], cb1r[4], cw2r[4];
    #pragma unroll
    for (int cc = 0; cc < 4; ++cc) {
        int col = wv * 64 + (cc >> 1) * 32 + (cc & 1) * 16 + l15;
        eb2r[cc] = eb2v[col]; cb1r[cc] = cb1v[col]; cw2r[cc] = cw2v[col];
    }
    float xi0 = x[ni * 3 + 0], xi1 = x[ni * 3 + 1], xi2 = x[ni * 3 + 2];
    float cb2 = cb2p[0];

    float mg[4] = {0.f, 0.f, 0.f, 0.f};
    float xd0 = 0.f, xd1 = 0.f, xd2 = 0.f;

    #pragma unroll 1
    for (int jc = 0; jc < 4; ++jc) {
        int j0 = jc * 32;

        // ---- phase 1: s tile = silu(Ai + Aj + d2*wd), 32x256 bf16 (d2 inline)
        #pragma unroll
        for (int it = 0; it < 4; ++it) {
            int row = it * 8 + (tid >> 5);
            int j = jb + j0 + row;
            float rx = xi0 - x[j * 3 + 0];
            float ry = xi1 - x[j * 3 + 1];
            float rz = xi2 - x[j * 3 + 2];
            float d2v = rx * rx + ry * ry + rz * rz;
            u32x4 ajw = *(const u32x4*)(AjB + ((size_t)j * HH + k0p));
            unsigned int uw0, uw1, uw2, uw3;
            uw0 = cvtpk(fsilu(aiv[0] + bflo(ajw[0]) + d2v * wdv[0]), fsilu(aiv[1] + bfhi(ajw[0]) + d2v * wdv[1]));
            uw1 = cvtpk(fsilu(aiv[2] + bflo(ajw[1]) + d2v * wdv[2]), fsilu(aiv[3] + bfhi(ajw[1]) + d2v * wdv[3]));
            uw2 = cvtpk(fsilu(aiv[4] + bflo(ajw[2]) + d2v * wdv[4]), fsilu(aiv[5] + bfhi(ajw[2]) + d2v * wdv[5]));
            uw3 = cvtpk(fsilu(aiv[6] + bflo(ajw[3]) + d2v * wdv[6]), fsilu(aiv[7] + bfhi(ajw[3]) + d2v * wdv[7]));
            u32x4 sv = {uw0, uw1, uw2, uw3};
            unsigned off = (unsigned)(row * 512 + k0p * 2) ^ (unsigned)((row & 7) << 4);
            *reinterpret_cast<u32x4*>(reinterpret_cast<char*>(s_tile) + off) = sv;
        }
        __syncthreads();

        // ---- phase 2: m = silu(s @ ew2 + eb2), two ct-passes
        #pragma unroll 1
        for (int ctp = 0; ctp < 2; ++ctp) {
            f32x4 acc[2][2];
            acc[0][0] = (f32x4){0.f,0.f,0.f,0.f}; acc[0][1] = (f32x4){0.f,0.f,0.f,0.f};
            acc[1][0] = (f32x4){0.f,0.f,0.f,0.f}; acc[1][1] = (f32x4){0.f,0.f,0.f,0.f};
            int bofs = ((wv * 4 + ctp * 2) << 9) + (lane << 3);
            bf16x8 bc0 = *(const bf16x8*)(ew2P + bofs);
            bf16x8 bc1 = *(const bf16x8*)(ew2P + 512 + bofs);
            #pragma unroll
            for (int ks = 0; ks < 8; ++ks) {
                bf16x8 bn0, bn1;
                if (ks < 7) {
                    bn0 = *(const bf16x8*)(ew2P + ((ks + 1) << 13) + bofs);
                    bn1 = *(const bf16x8*)(ew2P + ((ks + 1) << 13) + 512 + bofs);
                }
                int ak = ks * 32 + g4 * 8;
                int row0 = l15, row1 = l15 + 16;
                unsigned off0 = (unsigned)(row0 * 512 + ak * 2) ^ (unsigned)((row0 & 7) << 4);
                unsigned off1 = (unsigned)(row1 * 512 + ak * 2) ^ (unsigned)((row1 & 7) << 4);
                bf16x8 a0 = *reinterpret_cast<const bf16x8*>(reinterpret_cast<const char*>(s_tile) + off0);
                bf16x8 a1 = *reinterpret_cast<const bf16x8*>(reinterpret_cast<const char*>(s_tile) + off1);
                acc[0][0] = __builtin_amdgcn_mfma_f32_16x16x32_bf16(a0, bc0, acc[0][0], 0, 0, 0);
                acc[0][1] = __builtin_amdgcn_mfma_f32_16x16x32_bf16(a0, bc1, acc[0][1], 0, 0, 0);
                acc[1][0] = __builtin_amdgcn_mfma_f32_16x16x32_bf16(a1, bc0, acc[1][0], 0, 0, 0);
                acc[1][1] = __builtin_amdgcn_mfma_f32_16x16x32_bf16(a1, bc1, acc[1][1], 0, 0, 0);
                if (ks < 7) { bc0 = bn0; bc1 = bn1; }
            }
            int cc0 = ctp * 2, cc1 = ctp * 2 + 1;
            int col0 = wv * 64 + ctp * 32 + l15;
            #pragma unroll
            for (int rt = 0; rt < 2; ++rt) {
                #pragma unroll
                for (int r = 0; r < 4; ++r) {
                    int row = rt * 16 + g4 * 4 + r;
                    float v0 = fsilu(acc[rt][0][r] + eb2r[cc0]);
                    float v1 = fsilu(acc[rt][1][r] + eb2r[cc1]);
                    mg[cc0] += v0; mg[cc1] += v1;
                    unsigned int w = cvtpk(v0, v1);
                    unsigned swz = (unsigned)((row & 7) << 4);
                    unsigned o0 = (unsigned)(row * 512 + col0 * 2) ^ swz;
                    unsigned o1 = (unsigned)(row * 512 + (col0 + 16) * 2) ^ swz;
                    *reinterpret_cast<unsigned short*>(reinterpret_cast<char*>(m_tile) + o0) = (unsigned short)w;
                    *reinterpret_cast<unsigned short*>(reinterpret_cast<char*>(m_tile) + o1) = (unsigned short)(w >> 16);
                }
            }
        }
        __syncthreads();

        // ---- phase 3: c = silu(m @ cw1 + cb1); row-dot with cw2
        {
            float rs[8];
            #pragma unroll
            for (int q = 0; q < 8; ++q) rs[q] = 0.f;
            #pragma unroll 1
            for (int ctp = 0; ctp < 2; ++ctp) {
                f32x4 acc[2][2];
                acc[0][0] = (f32x4){0.f,0.f,0.f,0.f}; acc[0][1] = (f32x4){0.f,0.f,0.f,0.f};
                acc[1][0] = (f32x4){0.f,0.f,0.f,0.f}; acc[1][1] = (f32x4){0.f,0.f,0.f,0.f};
                int bofs = ((wv * 4 + ctp * 2) << 9) + (lane << 3);
                bf16x8 bc0 = *(const bf16x8*)(cw1P + bofs);
                bf16x8 bc1 = *(const bf16x8*)(cw1P + 512 + bofs);
                #pragma unroll
                for (int ks = 0; ks < 8; ++ks) {
                    bf16x8 bn0, bn1;
                    if (ks < 7) {
                        bn0 = *(const bf16x8*)(cw1P + ((ks + 1) << 13) + bofs);
                        bn1 = *(const bf16x8*)(cw1P + ((ks + 1) << 13) + 512 + bofs);
                    }
                    int ak = ks * 32 + g4 * 8;
                    int row0 = l15, row1 = l15 + 16;
                    unsigned off0 = (unsigned)(row0 * 512 + ak * 2) ^ (unsigned)((row0 & 7) << 4);
                    unsigned off1 = (unsigned)(row1 * 512 + ak * 2) ^ (unsigned)((row1 & 7) << 4);
                    bf16x8 a0 = *reinterpret_cast<const bf16x8*>(reinterpret_cast<const char*>(m_tile) + off0);
                    bf16x8 a1 = *reinterpret_cast<const bf16x8*>(reinterpret_cast<const char*>(m_tile) + off1);
                    acc[0][0] = __builtin_amdgcn_mfma_f32_16x16x32_bf16(a0, bc0, acc[0][0], 0, 0, 0);
                    acc[0][1] = __builtin_amdgcn_mfma_f32_16x16x32_bf16(a0, bc1, acc[0][1], 0, 0, 0);
                    acc[1][0] = __builtin_amdgcn_mfma_f32_16x16x32_bf16(a1, bc0, acc[1][0], 0, 0, 0);
                    acc[1][1] = __builtin_amdgcn_mfma_f32_16x16x32_bf16(a1, bc1, acc[1][1], 0, 0, 0);
                    if (ks < 7) { bc0 = bn0; bc1 = bn1; }
                }
                int cc0 = ctp * 2, cc1 = ctp * 2 + 1;
                #pragma unroll
                for (int rt = 0; rt < 2; ++rt)
                    #pragma unroll
                    for (int r = 0; r < 4; ++r)
                        rs[rt * 4 + r] += fsilu(acc[rt][0][r] + cb1r[cc0]) * cw2r[cc0]
                                        + fsilu(acc[rt][1][r] + cb1r[cc1]) * cw2r[cc1];
            }
            #pragma unroll
            for (int m = 1; m <= 8; m <<= 1)
                #pragma unroll
                for (int q = 0; q < 8; ++q) rs[q] += __shfl_xor(rs[q], m);
            if (l15 == 0) {
                #pragma unroll
                for (int rt = 0; rt < 2; ++rt)
                    #pragma unroll
                    for (int r = 0; r < 4; ++r)
                        cwpart[wv][rt * 16 + g4 * 4 + r] = rs[rt * 4 + r];
            }
        }
        __syncthreads();

        if (tid < 32) {
            float cwv = cb2 + cwpart[0][tid] + cwpart[1][tid] + cwpart[2][tid] + cwpart[3][tid];
            int j = jb + j0 + tid;
            float p0 = (xi0 - x[j * 3 + 0]) * cwv;
            float p1 = (xi1 - x[j * 3 + 1]) * cwv;
            float p2 = (xi2 - x[j * 3 + 2]) * cwv;
            #pragma unroll
            for (int m = 1; m < 32; m <<= 1) {
                p0 += __shfl_xor(p0, m); p1 += __shfl_xor(p1, m); p2 += __shfl_xor(p2, m);
            }
            xd0 += p0; xd1 += p1; xd2 += p2;
        }
        __syncthreads();
    }

    #pragma unroll
    for (int cc = 0; cc < 4; ++cc) {
        mg[cc] += __shfl_xor(mg[cc], 16);
        mg[cc] += __shfl_xor(mg[cc], 32);
    }
    if (lane < 16) {
        #pragma unroll
        for (int cc = 0; cc < 4; ++cc)
            maggH[(size_t)half * RN + (size_t)ni * HH + wv * 64 + (cc >> 1) * 32 + (cc & 1) * 16 + lane] = mg[cc];
    }
    if (tid == 0) {
        xdeltaH[half * 2048 + ni * 3 + 0] = xd0 * (1.0f / NN);
        xdeltaH[half * 2048 + ni * 3 + 1] = xd1 * (1.0f / NN);
        xdeltaH[half * 2048 + ni * 3 + 2] = xd2 * (1.0f / NN);
    }
}

// ---------------------------------------------------------------- fused node update + next-layer LN/Ai/Aj
// bf16 pair-packed weights; sums the two j-half magg/xdelta buffers.
__global__ __launch_bounds__(256) void k_node_ln(
    const float* __restrict__ hn, const float* __restrict__ magg,
    const unsigned int* __restrict__ nw1w, const float* __restrict__ nb1l,
    const unsigned int* __restrict__ nw2w, const float* __restrict__ nb2l,
    float* __restrict__ h, float* __restrict__ x, const float* __restrict__ xdeltaH,
    const float* __restrict__ g, const float* __restrict__ bta,
    const unsigned int* __restrict__ ew1w, const float* __restrict__ eb1l,
    float* __restrict__ hnout, float* __restrict__ Ai, unsigned short* __restrict__ AjB,
    int has_ln) {
    __shared__ float s2T[2 * HH][2];
    __shared__ float suT[HH][2];
    __shared__ float sh[2][HH];
    __shared__ float shnT[HH][2];
    int tid = threadIdx.x;
    int base = blockIdx.x * 2;
    #pragma unroll
    for (int r = 0; r < 2; ++r) {
        s2T[tid][r] = hn[(base + r) * HH + tid];
        s2T[HH + tid][r] = magg[(base + r) * HH + tid] + magg[(size_t)RN + (base + r) * HH + tid];
    }
    if (tid < 6) {
        int r = tid / 3, c = tid % 3;
        x[(base + r) * 3 + c] += xdeltaH[(base + r) * 3 + c] + xdeltaH[2048 + (base + r) * 3 + c];
    }
    __syncthreads();
    float a0 = nb1l[tid], a1 = a0;
    for (int c2 = 0; c2 < 256; ++c2) {
        unsigned int wp = nw1w[c2 * 256 + tid];
        float4 s = *(const float4*)&s2T[c2 * 2][0];
        a0 += s.x * bflo(wp) + s.z * bfhi(wp);
        a1 += s.y * bflo(wp) + s.w * bfhi(wp);
    }
    suT[tid][0] = fsilu(a0); suT[tid][1] = fsilu(a1);
    __syncthreads();
    float d0 = nb2l[tid], d1 = d0;
    for (int c2 = 0; c2 < 128; ++c2) {
        unsigned int wp = nw2w[c2 * 256 + tid];
        float4 s = *(const float4*)&suT[c2 * 2][0];
        d0 += s.x * bflo(wp) + s.z * bfhi(wp);
        d1 += s.y * bflo(wp) + s.w * bfhi(wp);
    }
    float h0 = h[(base + 0) * HH + tid] + d0;
    float h1 = h[(base + 1) * HH + tid] + d1;
    h[(base + 0) * HH + tid] = h0;
    h[(base + 1) * HH + tid] = h1;
    if (!has_ln) return;
    sh[0][tid] = h0; sh[1][tid] = h1;
    __syncthreads();

    int wv = tid >> 6, lane = tid & 63;
    if (wv < 2) {
        int row = base + wv;
        float v[4];
        #pragma unroll
        for (int q = 0; q < 4; ++q) v[q] = sh[wv][lane + 64 * q];
        float s = v[0] + v[1] + v[2] + v[3];
        #pragma unroll
        for (int m = 1; m < 64; m <<= 1) s += __shfl_xor(s, m);
        float mu = s * (1.0f / HH);
        float var = 0.f;
        #pragma unroll
        for (int q = 0; q < 4; ++q) { v[q] -= mu; var += v[q] * v[q]; }
        #pragma unroll
        for (int m = 1; m < 64; m <<= 1) var += __shfl_xor(var, m);
        float rstd = rsqrtf(var * (1.0f / HH) + 1e-5f);
        #pragma unroll
        for (int q = 0; q < 4; ++q) {
            int k = lane + 64 * q;
            float hv = v[q] * rstd * g[k] + bta[k];
            shnT[k][wv] = hv;
            hnout[row * HH + k] = hv;
        }
    }
    __syncthreads();

    float ai0 = eb1l[tid], ai1 = ai0;
    float aj0 = 0.f, aj1 = 0.f;
    for (int c2 = 0; c2 < 128; ++c2) {
        unsigned int wip = ew1w[c2 * 256 + tid];
        unsigned int wjp = ew1w[(128 + c2) * 256 + tid];
        float4 s = *(const float4*)&shnT[c2 * 2][0];
        ai0 += s.x * bflo(wip) + s.z * bfhi(wip);
        ai1 += s.y * bflo(wip) + s.w * bfhi(wip);
        aj0 += s.x * bflo(wjp) + s.z * bfhi(wjp);
        aj1 += s.y * bflo(wjp) + s.w * bfhi(wjp);
    }
    Ai[(base + 0) * HH + tid] = ai0; AjB[(base + 0) * HH + tid] = f2bf(aj0);
    Ai[(base + 1) * HH + tid] = ai1; AjB[(base + 1) * HH + tid] = f2bf(aj1);
}

// ---------------------------------------------------------------- decoder (2 rows/block)
__global__ __launch_bounds__(256) void k_decoder(
    const float* __restrict__ h,
    const float* __restrict__ dw1, const float* __restrict__ db1,
    const float* __restrict__ dw2, const float* __restrict__ db2,
    const float* __restrict__ dw3, const float* __restrict__ db3,
    float* __restrict__ out) {
    __shared__ float shT[HH][2];
    __shared__ float so1T[HH][2];
    __shared__ float so2T[HH][2];
    int tid = threadIdx.x;
    int base = blockIdx.x * 2;
    #pragma unroll
    for (int r = 0; r < 2; ++r) shT[tid][r] = h[(base + r) * HH + tid];
    __syncthreads();
    float a0 = db1[tid], a1 = a0;
    for (int c = 0; c < HH; ++c) {
        float w = dw1[c * HH + tid];
        float2 s = *(const float2*)&shT[c][0];
        a0 += s.x * w; a1 += s.y * w;
    }
    so1T[tid][0] = fmaxf(a0, 0.f); so1T[tid][1] = fmaxf(a1, 0.f);
    __syncthreads();
    a0 = db2[tid]; a1 = a0;
    for (int c = 0; c < HH; ++c) {
        float w = dw2[c * HH + tid];
        float2 s = *(const float2*)&so1T[c][0];
        a0 += s.x * w; a1 += s.y * w;
    }
    so2T[tid][0] = fmaxf(a0, 0.f) + shT[tid][0];
    so2T[tid][1] = fmaxf(a1, 0.f) + shT[tid][1];
    __syncthreads();
    if (tid < 6) {
        int r = tid / 3, c = tid % 3;
        float acc = db3[c];
        for (int k = 0; k < HH; ++k) acc += so2T[k][r] * dw3[k * 3 + c];
        out[(base + r) * 3 + c] = acc;
    }
}

// ---------------------------------------------------------------- launch
extern "C" void kernel_launch(void* const* d_in, const int* in_sizes, int n_in,
                              void* d_out, int out_size, void* d_ws, size_t ws_size,
                              hipStream_t stream) {
    const float* coords = (const float*)d_in[0];
    const float* feats  = (const float*)d_in[1];
    const float* t      = (const float*)d_in[2];
    const float* pe_w1  = (const float*)d_in[3];  const float* pe_b1 = (const float*)d_in[4];
    const float* pe_w2  = (const float*)d_in[5];  const float* pe_b2 = (const float*)d_in[6];
    const float* pe_w3  = (const float*)d_in[7];  const float* pe_b3 = (const float*)d_in[8];
    const float* te_w1  = (const float*)d_in[9];  const float* te_b1 = (const float*)d_in[10];
    const float* te_w2  = (const float*)d_in[11]; const float* te_b2 = (const float*)d_in[12];
    const float* ln_g   = (const float*)d_in[13]; const float* ln_b  = (const float*)d_in[14];
    const float* ew1    = (const float*)d_in[15]; const float* eb1   = (const float*)d_in[16];
    const float* ew2    = (const float*)d_in[17]; const float* eb2   = (const float*)d_in[18];
    const float* cw1    = (const float*)d_in[19]; const float* cb1   = (const float*)d_in[20];
    const float* cw2    = (const float*)d_in[21]; const float* cb2   = (const float*)d_in[22];
    const float* nw1    = (const float*)d_in[23]; const float* nb1   = (const float*)d_in[24];
    const float* nw2    = (const float*)d_in[25]; const float* nb2   = (const float*)d_in[26];
    const float* dec_w1 = (const float*)d_in[27]; const float* dec_b1 = (const float*)d_in[28];
    const float* dec_w2 = (const float*)d_in[29]; const float* dec_b2 = (const float*)d_in[30];
    const float* dec_w3 = (const float*)d_in[31]; const float* dec_b3 = (const float*)d_in[32];

    float* ws = (float*)d_ws;
    float* h      = ws;
    float* hn     = ws + RN;
    float* Ai     = ws + 2 * RN;
    float* magg   = ws + 3 * RN;            // 2*RN (two j-halves)
    float* x      = ws + 5 * RN;            // 1536 (reserve 2048)
    float* xdelta = ws + 5 * RN + 2048;     // 2*2048 (two j-halves)
    unsigned short* AjB  = (unsigned short*)(ws + 5 * RN + 2048 + 4096);
    unsigned short* ew2P = AjB + RN;                       // LL*65536
    unsigned short* cw1P = ew2P + LL * HH * HH;            // LL*65536
    unsigned short* nw1B = cw1P + LL * HH * HH;            // LL*131072
    unsigned short* ew1B = nw1B + LL * 2 * HH * HH;        // LL*131072
    unsigned short* nw2B = ew1B + LL * 2 * HH * HH;        // LL*65536

    k_convert<<<(LL * 8192 + 511) / 512, 512, 0, stream>>>(ew2, cw1, ew2P, cw1P);
    k_convert2<<<(LL * 131072 + 255) / 256, 256, 0, stream>>>(nw1, nw2, ew1, nw1B, nw2B, ew1B);
    k_encoder<<<NB * NN / 2, 256, 0, stream>>>(coords, feats, t,
        pe_w1, pe_b1, pe_w2, pe_b2, pe_w3, pe_b3, te_w1, te_b1, te_w2, te_b2, h, x);
    k_ln_aiaj<<<NB * NN / 2, 256, 0, stream>>>(h, ln_g, ln_b,
        (const unsigned int*)ew1B, eb1, hn, Ai, AjB);

    for (int l = 0; l < LL; ++l) {
        k_edge<<<NB * NN * 2, 256, 0, stream>>>(x, Ai, AjB,
            ew1 + ((size_t)l * 513 + 512) * HH, eb2 + l * HH,
            ew2P + (size_t)l * HH * HH, cw1P + (size_t)l * HH * HH,
            cb1 + l * HH, cw2 + l * HH, cb2 + l, magg, xdelta);
        int ln = (l + 1 < LL) ? (l + 1) : LL - 1;  // params unused when has_ln=0
        k_node_ln<<<NB * NN / 2, 256, 0, stream>>>(hn, magg,
            (const unsigned int*)(nw1B + (size_t)l * 2 * HH * HH), nb1 + l * HH,
            (const unsigned int*)(nw2B + (size_t)l * HH * HH), nb2 + l * HH, h, x, xdelta,
            ln_g + ln * HH, ln_b + ln * HH,
            (const unsigned int*)(ew1B + (size_t)ln * 2 * HH * HH), eb1 + ln * HH,
            hn, Ai, AjB, (l + 1 < LL) ? 1 : 0);
    }

    k_decoder<<<NB * NN / 2, 256, 0, stream>>>(h, dec_w1, dec_b1, dec_w2, dec_b2,
                                               dec_w3, dec_b3, (float*)d_out);
}

// Round 12
// 677.666 us; speedup vs baseline: 1.0632x; 1.0632x over previous
//
#include <hip/hip_runtime.h>
#include <math.h>

static constexpr int NB = 2, NN = 256, HH = 256, DD = 64, LL = 6;
static constexpr int RN = NB * NN * HH;  // 131072
static constexpr int SROWB = 528;        // padded LDS row stride in bytes (+16B: 2-way banks, imm-foldable)

typedef __attribute__((ext_vector_type(8))) short bf16x8;
typedef __attribute__((ext_vector_type(4))) float f32x4;
typedef __attribute__((ext_vector_type(4))) float float4v;
typedef __attribute__((ext_vector_type(4))) unsigned int u32x4;

__device__ __forceinline__ float fsilu(float v) {
    return v * __builtin_amdgcn_rcpf(1.0f + __expf(-v));
}
__device__ __forceinline__ unsigned short f2bf(float f) {
    union { float f; unsigned int u; } x; x.f = f;
    unsigned int r = x.u + 0x7fffu + ((x.u >> 16) & 1u);
    return (unsigned short)(r >> 16);
}
__device__ __forceinline__ float bitsf(unsigned int u) {
    union { float f; unsigned int u; } x; x.u = u; return x.f;
}
__device__ __forceinline__ float bflo(unsigned int w) { return bitsf(w << 16); }
__device__ __forceinline__ float bfhi(unsigned int w) { return bitsf(w & 0xffff0000u); }
__device__ __forceinline__ unsigned int cvtpk(float lo, float hi) {
    unsigned int w;
    asm("v_cvt_pk_bf16_f32 %0, %1, %2" : "=v"(w) : "v"(lo), "v"(hi));
    return w;
}

// ---------------------------------------------------------------- convert (edge fragment-packed)
__global__ void k_convert(const float* __restrict__ ew2, const float* __restrict__ cw1,
                          unsigned short* __restrict__ ew2P, unsigned short* __restrict__ cw1P) {
    int g = blockIdx.x * blockDim.x + threadIdx.x;
    if (g >= LL * 8192) return;
    int l = g >> 13;
    int r = g & 8191;
    int lane = r & 63;
    int fidx = r >> 6;
    int ks = fidx >> 4;
    int wv = (fidx >> 1) & 7;
    int ct = fidx & 1;
    int col = wv * 32 + ct * 16 + (lane & 15);
    int k0 = ks * 32 + (lane >> 4) * 8;
    #pragma unroll
    for (int e = 0; e < 8; ++e) {
        ew2P[(size_t)g * 8 + e] = f2bf(ew2[((size_t)l * HH + k0 + e) * HH + col]);
        cw1P[(size_t)g * 8 + e] = f2bf(cw1[((size_t)l * HH + k0 + e) * HH + col]);
    }
}

// ---------------------------------------------------------------- convert2 (bf16 pair-packed GEMV weights)
__global__ void k_convert2(const float* __restrict__ nw1, const float* __restrict__ nw2,
                           const float* __restrict__ ew1,
                           unsigned short* __restrict__ nw1B, unsigned short* __restrict__ nw2B,
                           unsigned short* __restrict__ ew1B) {
    int idx = blockIdx.x * blockDim.x + threadIdx.x;
    if (idx >= LL * 131072) return;
    int l = idx >> 17;
    int r = idx & 131071;
    int c = r >> 8, col = r & 255;
    int dst = (l << 17) + ((c >> 1) << 9) + (col << 1) + (c & 1);
    nw1B[dst] = f2bf(nw1[(size_t)l * 131072 + c * 256 + col]);
    ew1B[dst] = f2bf(ew1[(size_t)l * 131328 + c * 256 + col]);  // 513*256 stride
    if (r < 65536) {
        int d2 = (l << 16) + ((c >> 1) << 9) + (col << 1) + (c & 1);
        nw2B[d2] = f2bf(nw2[(size_t)l * 65536 + c * 256 + col]);
    }
}

// ---------------------------------------------------------------- encoder (2 rows/block, broadcast staging)
__global__ __launch_bounds__(256) void k_encoder(
    const float* __restrict__ coords, const float* __restrict__ feats, const float* __restrict__ t,
    const float* __restrict__ pw1, const float* __restrict__ pb1,
    const float* __restrict__ pw2, const float* __restrict__ pb2,
    const float* __restrict__ pw3, const float* __restrict__ pb3,
    const float* __restrict__ tw1, const float* __restrict__ tb1,
    const float* __restrict__ tw2, const float* __restrict__ tb2,
    float* __restrict__ h, float* __restrict__ x) {
    __shared__ float spinT[68][2];
    __shared__ float shaT[HH][2];
    __shared__ float shbT[HH][2];
    __shared__ float ste1[HH];
    int tid = threadIdx.x;
    int base = blockIdx.x * 2;
    int b = base / NN;

    #pragma unroll
    for (int r = 0; r < 2; ++r) {
        int row = base + r;
        if (tid < 3) spinT[tid][r] = coords[row * 3 + tid];
        if (tid < DD) spinT[3 + tid][r] = feats[row * DD + tid];
    }
    float tv = t[b];
    ste1[tid] = fmaxf(tv * tw1[tid] + tb1[tid], 0.0f);
    if (tid < 6) {
        int r = tid / 3, c = tid % 3;
        x[(base + r) * 3 + c] = coords[(base + r) * 3 + c];
    }
    __syncthreads();

    float a0 = pb1[tid], a1 = a0;
    for (int c = 0; c < 67; ++c) {
        float w = pw1[c * HH + tid];
        float2 s = *(const float2*)&spinT[c][0];
        a0 += s.x * w; a1 += s.y * w;
    }
    shaT[tid][0] = fmaxf(a0, 0.f); shaT[tid][1] = fmaxf(a1, 0.f);
    __syncthreads();
    a0 = pb2[tid]; a1 = a0;
    for (int c = 0; c < HH; ++c) {
        float w = pw2[c * HH + tid];
        float2 s = *(const float2*)&shaT[c][0];
        a0 += s.x * w; a1 += s.y * w;
    }
    shbT[tid][0] = fmaxf(a0, 0.f); shbT[tid][1] = fmaxf(a1, 0.f);
    __syncthreads();
    a0 = pb3[tid]; a1 = a0;
    float te = tb2[tid];
    for (int c = 0; c < HH; ++c) {
        float w = pw3[c * HH + tid];
        float2 s = *(const float2*)&shbT[c][0];
        a0 += s.x * w; a1 += s.y * w;
        te += ste1[c] * tw2[c * HH + tid];
    }
    h[(base + 0) * HH + tid] = fmaxf(a0, 0.f) + te;
    h[(base + 1) * HH + tid] = fmaxf(a1, 0.f) + te;
}

// ---------------------------------------------------------------- LayerNorm + Ai/Aj (layer 0; bf16 ew1)
__global__ __launch_bounds__(256) void k_ln_aiaj(
    const float* __restrict__ h, const float* __restrict__ g, const float* __restrict__ bta,
    const unsigned int* __restrict__ ew1w, const float* __restrict__ eb1l,
    float* __restrict__ hn, float* __restrict__ Ai, unsigned short* __restrict__ AjB) {
    __shared__ float shnT[HH][2];
    int tid = threadIdx.x, wv = tid >> 6, lane = tid & 63;
    int base = blockIdx.x * 2;

    if (wv < 2) {
        int row = base + wv;
        float v[4];
        #pragma unroll
        for (int q = 0; q < 4; ++q) v[q] = h[row * HH + lane + 64 * q];
        float s = v[0] + v[1] + v[2] + v[3];
        #pragma unroll
        for (int m = 1; m < 64; m <<= 1) s += __shfl_xor(s, m);
        float mu = s * (1.0f / HH);
        float var = 0.f;
        #pragma unroll
        for (int q = 0; q < 4; ++q) { v[q] -= mu; var += v[q] * v[q]; }
        #pragma unroll
        for (int m = 1; m < 64; m <<= 1) var += __shfl_xor(var, m);
        float rstd = rsqrtf(var * (1.0f / HH) + 1e-5f);
        #pragma unroll
        for (int q = 0; q < 4; ++q) {
            int k = lane + 64 * q;
            float hv = v[q] * rstd * g[k] + bta[k];
            shnT[k][wv] = hv;
            hn[row * HH + k] = hv;
        }
    }
    __syncthreads();

    float ai0 = eb1l[tid], ai1 = ai0;
    float aj0 = 0.f, aj1 = 0.f;
    for (int c2 = 0; c2 < 128; ++c2) {
        unsigned int wip = ew1w[c2 * 256 + tid];
        unsigned int wjp = ew1w[(128 + c2) * 256 + tid];
        float4 s = *(const float4*)&shnT[c2 * 2][0];
        ai0 += s.x * bflo(wip) + s.z * bfhi(wip);
        ai1 += s.y * bflo(wip) + s.w * bfhi(wip);
        aj0 += s.x * bflo(wjp) + s.z * bfhi(wjp);
        aj1 += s.y * bflo(wjp) + s.w * bfhi(wjp);
    }
    Ai[(base + 0) * HH + tid] = ai0; AjB[(base + 0) * HH + tid] = f2bf(aj0);
    Ai[(base + 1) * HH + tid] = ai1; AjB[(base + 1) * HH + tid] = f2bf(aj1);
}

// ---------------------------------------------------------------- fused edge pipeline (MFMA)
// Round-7 structure (512 thr, 64-row tile, 87us proven) with PADDED-STRIDE LDS
// (528B rows) replacing the XOR swizzle: per-ks offsets become ds_read/write
// immediates, killing the per-iteration address-calc VALU chains that kept
// VALUBusy at ~40%. Bank cost: 2-way (free, m136).
// __launch_bounds__(512, 1): arg2 is min BLOCKS/CU on hipcc; any higher value
// caps regalloc and spills (rounds 2-5, 8). DO NOT TOUCH.
__global__ __launch_bounds__(512, 1) void k_edge(
    const float* __restrict__ x, const float* __restrict__ Ai, const unsigned short* __restrict__ AjB,
    const float* __restrict__ wd, const float* __restrict__ eb2v,
    const unsigned short* __restrict__ ew2P, const unsigned short* __restrict__ cw1P,
    const float* __restrict__ cb1v, const float* __restrict__ cw2v, const float* __restrict__ cb2p,
    float* __restrict__ magg, float* __restrict__ xdelta) {
    __shared__ float srel[64][3];
    __shared__ float sd2[64];
    __shared__ float cwpart[8][64];
    __shared__ char s_tile[64 * SROWB];  // 33.8KB
    __shared__ char m_tile[64 * SROWB];  // 33.8KB

    int tid = threadIdx.x, wv = tid >> 6, lane = tid & 63;
    int g4 = lane >> 4, l15 = lane & 15;
    int colbase = wv * 32;
    int bi = blockIdx.x;
    int b = bi >> 8, i = bi & 255;
    int ni = b * NN + i;
    int bbase = b * NN;
    int bthr = ((wv << 7) + lane) << 3;

    int k0p = (tid & 31) << 3;
    float aiv[8], wdv[8];
    {
        float4v a0 = *(const float4v*)(Ai + (size_t)ni * HH + k0p);
        float4v a1 = *(const float4v*)(Ai + (size_t)ni * HH + k0p + 4);
        float4v w0 = *(const float4v*)(wd + k0p);
        float4v w1 = *(const float4v*)(wd + k0p + 4);
        #pragma unroll
        for (int e = 0; e < 4; ++e) { aiv[e] = a0[e]; aiv[4 + e] = a1[e]; wdv[e] = w0[e]; wdv[4 + e] = w1[e]; }
    }
    float eb2r[2], cb1r[2], cw2r[2];
    #pragma unroll
    for (int ct = 0; ct < 2; ++ct) {
        int col = colbase + ct * 16 + l15;
        eb2r[ct] = eb2v[col]; cb1r[ct] = cb1v[col]; cw2r[ct] = cw2v[col];
    }
    float xi0 = x[ni * 3 + 0], xi1 = x[ni * 3 + 1], xi2 = x[ni * 3 + 2];
    float cb2 = cb2p[0];

    // per-thread LDS byte bases (all offsets from these are compile-time)
    char* p1w = s_tile + ((tid >> 5) * SROWB + k0p * 2);               // phase-1 write: +it*16*SROWB
    const char* aA = s_tile + (l15 * SROWB + g4 * 16);                 // A-read: +rh*32*SROWB (+16*SROWB) +ks*64
    const char* aM = m_tile + (l15 * SROWB + g4 * 16);
    char* mwA = m_tile + ((g4 * 4) * SROWB + (colbase + l15) * 2);     // m-write: +((rh*32+rt*16+r)*SROWB), +32 cols
    float mgv[2] = {0.f, 0.f};
    float xd0 = 0.f, xd1 = 0.f, xd2 = 0.f;

    #pragma unroll 1
    for (int jc = 0; jc < 4; ++jc) {
        int j0 = jc * 64;
        __syncthreads();
        if (tid < 64) {
            int j = bbase + j0 + tid;
            float rx = xi0 - x[j * 3 + 0];
            float ry = xi1 - x[j * 3 + 1];
            float rz = xi2 - x[j * 3 + 2];
            srel[tid][0] = rx; srel[tid][1] = ry; srel[tid][2] = rz;
            sd2[tid] = rx * rx + ry * ry + rz * rz;
        }
        __syncthreads();

        // ---- phase 1: s tile = silu(Ai + Aj + d2*wd), 64x256 bf16
        #pragma unroll
        for (int it = 0; it < 4; ++it) {
            int row = it * 16 + (tid >> 5);
            float d2v = sd2[row];
            u32x4 ajw = *(const u32x4*)(AjB + ((size_t)(bbase + j0 + row) * HH + k0p));
            unsigned int uw0, uw1, uw2, uw3;
            uw0 = cvtpk(fsilu(aiv[0] + bflo(ajw[0]) + d2v * wdv[0]), fsilu(aiv[1] + bfhi(ajw[0]) + d2v * wdv[1]));
            uw1 = cvtpk(fsilu(aiv[2] + bflo(ajw[1]) + d2v * wdv[2]), fsilu(aiv[3] + bfhi(ajw[1]) + d2v * wdv[3]));
            uw2 = cvtpk(fsilu(aiv[4] + bflo(ajw[2]) + d2v * wdv[4]), fsilu(aiv[5] + bfhi(ajw[2]) + d2v * wdv[5]));
            uw3 = cvtpk(fsilu(aiv[6] + bflo(ajw[3]) + d2v * wdv[6]), fsilu(aiv[7] + bfhi(ajw[3]) + d2v * wdv[7]));
            u32x4 sv = {uw0, uw1, uw2, uw3};
            *reinterpret_cast<u32x4*>(p1w + it * 16 * SROWB) = sv;
        }
        __syncthreads();

        // ---- phase 2: m = silu(s @ ew2 + eb2), two 32-row half-passes
        #pragma unroll 1
        for (int rh = 0; rh < 2; ++rh) {
            f32x4 acc[2][2];
            acc[0][0] = (f32x4){0.f,0.f,0.f,0.f}; acc[0][1] = (f32x4){0.f,0.f,0.f,0.f};
            acc[1][0] = (f32x4){0.f,0.f,0.f,0.f}; acc[1][1] = (f32x4){0.f,0.f,0.f,0.f};
            const char* aBase = aA + rh * 32 * SROWB;
            bf16x8 bc0 = *(const bf16x8*)(ew2P + bthr);
            bf16x8 bc1 = *(const bf16x8*)(ew2P + (1 << 9) + bthr);
            #pragma unroll
            for (int ks = 0; ks < 8; ++ks) {
                bf16x8 bn0, bn1;
                if (ks < 7) {
                    bn0 = *(const bf16x8*)(ew2P + ((ks + 1) << 13) + bthr);
                    bn1 = *(const bf16x8*)(ew2P + ((ks + 1) << 13) + (1 << 9) + bthr);
                }
                bf16x8 a0 = *reinterpret_cast<const bf16x8*>(aBase + ks * 64);
                bf16x8 a1 = *reinterpret_cast<const bf16x8*>(aBase + 16 * SROWB + ks * 64);
                acc[0][0] = __builtin_amdgcn_mfma_f32_16x16x32_bf16(a0, bc0, acc[0][0], 0, 0, 0);
                acc[0][1] = __builtin_amdgcn_mfma_f32_16x16x32_bf16(a0, bc1, acc[0][1], 0, 0, 0);
                acc[1][0] = __builtin_amdgcn_mfma_f32_16x16x32_bf16(a1, bc0, acc[1][0], 0, 0, 0);
                acc[1][1] = __builtin_amdgcn_mfma_f32_16x16x32_bf16(a1, bc1, acc[1][1], 0, 0, 0);
                if (ks < 7) { bc0 = bn0; bc1 = bn1; }
            }
            char* mw = mwA + rh * 32 * SROWB;
            #pragma unroll
            for (int rt = 0; rt < 2; ++rt) {
                #pragma unroll
                for (int r = 0; r < 4; ++r) {
                    float v0 = fsilu(acc[rt][0][r] + eb2r[0]);
                    float v1 = fsilu(acc[rt][1][r] + eb2r[1]);
                    mgv[0] += v0; mgv[1] += v1;
                    unsigned int w = cvtpk(v0, v1);
                    char* p = mw + (rt * 16 + r) * SROWB;
                    *reinterpret_cast<unsigned short*>(p) = (unsigned short)w;
                    *reinterpret_cast<unsigned short*>(p + 32) = (unsigned short)(w >> 16);
                }
            }
        }
        __syncthreads();

        // ---- phase 3: c = silu(m @ cw1 + cb1); cw-row-dot with cw2 (two half-passes)
        #pragma unroll 1
        for (int rh = 0; rh < 2; ++rh) {
            f32x4 acc[2][2];
            acc[0][0] = (f32x4){0.f,0.f,0.f,0.f}; acc[0][1] = (f32x4){0.f,0.f,0.f,0.f};
            acc[1][0] = (f32x4){0.f,0.f,0.f,0.f}; acc[1][1] = (f32x4){0.f,0.f,0.f,0.f};
            const char* aBase = aM + rh * 32 * SROWB;
            bf16x8 bc0 = *(const bf16x8*)(cw1P + bthr);
            bf16x8 bc1 = *(const bf16x8*)(cw1P + (1 << 9) + bthr);
            #pragma unroll
            for (int ks = 0; ks < 8; ++ks) {
                bf16x8 bn0, bn1;
                if (ks < 7) {
                    bn0 = *(const bf16x8*)(cw1P + ((ks + 1) << 13) + bthr);
                    bn1 = *(const bf16x8*)(cw1P + ((ks + 1) << 13) + (1 << 9) + bthr);
                }
                bf16x8 a0 = *reinterpret_cast<const bf16x8*>(aBase + ks * 64);
                bf16x8 a1 = *reinterpret_cast<const bf16x8*>(aBase + 16 * SROWB + ks * 64);
                acc[0][0] = __builtin_amdgcn_mfma_f32_16x16x32_bf16(a0, bc0, acc[0][0], 0, 0, 0);
                acc[0][1] = __builtin_amdgcn_mfma_f32_16x16x32_bf16(a0, bc1, acc[0][1], 0, 0, 0);
                acc[1][0] = __builtin_amdgcn_mfma_f32_16x16x32_bf16(a1, bc0, acc[1][0], 0, 0, 0);
                acc[1][1] = __builtin_amdgcn_mfma_f32_16x16x32_bf16(a1, bc1, acc[1][1], 0, 0, 0);
                if (ks < 7) { bc0 = bn0; bc1 = bn1; }
            }
            float rs[8];
            #pragma unroll
            for (int q = 0; q < 8; ++q) rs[q] = 0.f;
            #pragma unroll
            for (int ct = 0; ct < 2; ++ct) {
                #pragma unroll
                for (int rt = 0; rt < 2; ++rt)
                    #pragma unroll
                    for (int r = 0; r < 4; ++r)
                        rs[rt * 4 + r] += fsilu(acc[rt][ct][r] + cb1r[ct]) * cw2r[ct];
            }
            #pragma unroll
            for (int m = 1; m <= 8; m <<= 1)
                #pragma unroll
                for (int q = 0; q < 8; ++q) rs[q] += __shfl_xor(rs[q], m);
            if (l15 == 0) {
                #pragma unroll
                for (int rt = 0; rt < 2; ++rt)
                    #pragma unroll
                    for (int r = 0; r < 4; ++r)
                        cwpart[wv][rh * 32 + rt * 16 + g4 * 4 + r] = rs[rt * 4 + r];
            }
        }
        __syncthreads();
        if (tid < 64) {
            float cwv = cb2;
            #pragma unroll
            for (int w = 0; w < 8; ++w) cwv += cwpart[w][tid];
            float p0 = srel[tid][0] * cwv;
            float p1 = srel[tid][1] * cwv;
            float p2 = srel[tid][2] * cwv;
            #pragma unroll
            for (int m = 1; m < 64; m <<= 1) {
                p0 += __shfl_xor(p0, m); p1 += __shfl_xor(p1, m); p2 += __shfl_xor(p2, m);
            }
            xd0 += p0; xd1 += p1; xd2 += p2;
        }
    }

    #pragma unroll
    for (int ct = 0; ct < 2; ++ct) {
        mgv[ct] += __shfl_xor(mgv[ct], 16);
        mgv[ct] += __shfl_xor(mgv[ct], 32);
    }
    if (lane < 16) {
        #pragma unroll
        for (int ct = 0; ct < 2; ++ct)
            magg[(size_t)ni * HH + colbase + ct * 16 + lane] = mgv[ct];
    }
    if (tid == 0) {
        xdelta[ni * 3 + 0] = xd0 * (1.0f / NN);
        xdelta[ni * 3 + 1] = xd1 * (1.0f / NN);
        xdelta[ni * 3 + 2] = xd2 * (1.0f / NN);
    }
}

// ---------------------------------------------------------------- fused node update + next-layer LN/Ai/Aj
__global__ __launch_bounds__(256) void k_node_ln(
    const float* __restrict__ hn, const float* __restrict__ magg,
    const unsigned int* __restrict__ nw1w, const float* __restrict__ nb1l,
    const unsigned int* __restrict__ nw2w, const float* __restrict__ nb2l,
    float* __restrict__ h, float* __restrict__ x, const float* __restrict__ xdelta,
    const float* __restrict__ g, const float* __restrict__ bta,
    const unsigned int* __restrict__ ew1w, const float* __restrict__ eb1l,
    float* __restrict__ hnout, float* __restrict__ Ai, unsigned short* __restrict__ AjB,
    int has_ln) {
    __shared__ float s2T[2 * HH][2];
    __shared__ float suT[HH][2];
    __shared__ float sh[2][HH];
    __shared__ float shnT[HH][2];
    int tid = threadIdx.x;
    int base = blockIdx.x * 2;
    #pragma unroll
    for (int r = 0; r < 2; ++r) {
        s2T[tid][r] = hn[(base + r) * HH + tid];
        s2T[HH + tid][r] = magg[(base + r) * HH + tid];
    }
    if (tid < 6) {
        int r = tid / 3, c = tid % 3;
        x[(base + r) * 3 + c] += xdelta[(base + r) * 3 + c];
    }
    __syncthreads();
    float a0 = nb1l[tid], a1 = a0;
    for (int c2 = 0; c2 < 256; ++c2) {
        unsigned int wp = nw1w[c2 * 256 + tid];
        float4 s = *(const float4*)&s2T[c2 * 2][0];
        a0 += s.x * bflo(wp) + s.z * bfhi(wp);
        a1 += s.y * bflo(wp) + s.w * bfhi(wp);
    }
    suT[tid][0] = fsilu(a0); suT[tid][1] = fsilu(a1);
    __syncthreads();
    float d0 = nb2l[tid], d1 = d0;
    for (int c2 = 0; c2 < 128; ++c2) {
        unsigned int wp = nw2w[c2 * 256 + tid];
        float4 s = *(const float4*)&suT[c2 * 2][0];
        d0 += s.x * bflo(wp) + s.z * bfhi(wp);
        d1 += s.y * bflo(wp) + s.w * bfhi(wp);
    }
    float h0 = h[(base + 0) * HH + tid] + d0;
    float h1 = h[(base + 1) * HH + tid] + d1;
    h[(base + 0) * HH + tid] = h0;
    h[(base + 1) * HH + tid] = h1;
    if (!has_ln) return;
    sh[0][tid] = h0; sh[1][tid] = h1;
    __syncthreads();

    int wv = tid >> 6, lane = tid & 63;
    if (wv < 2) {
        int row = base + wv;
        float v[4];
        #pragma unroll
        for (int q = 0; q < 4; ++q) v[q] = sh[wv][lane + 64 * q];
        float s = v[0] + v[1] + v[2] + v[3];
        #pragma unroll
        for (int m = 1; m < 64; m <<= 1) s += __shfl_xor(s, m);
        float mu = s * (1.0f / HH);
        float var = 0.f;
        #pragma unroll
        for (int q = 0; q < 4; ++q) { v[q] -= mu; var += v[q] * v[q]; }
        #pragma unroll
        for (int m = 1; m < 64; m <<= 1) var += __shfl_xor(var, m);
        float rstd = rsqrtf(var * (1.0f / HH) + 1e-5f);
        #pragma unroll
        for (int q = 0; q < 4; ++q) {
            int k = lane + 64 * q;
            float hv = v[q] * rstd * g[k] + bta[k];
            shnT[k][wv] = hv;
            hnout[row * HH + k] = hv;
        }
    }
    __syncthreads();

    float ai0 = eb1l[tid], ai1 = ai0;
    float aj0 = 0.f, aj1 = 0.f;
    for (int c2 = 0; c2 < 128; ++c2) {
        unsigned int wip = ew1w[c2 * 256 + tid];
        unsigned int wjp = ew1w[(128 + c2) * 256 + tid];
        float4 s = *(const float4*)&shnT[c2 * 2][0];
        ai0 += s.x * bflo(wip) + s.z * bfhi(wip);
        ai1 += s.y * bflo(wip) + s.w * bfhi(wip);
        aj0 += s.x * bflo(wjp) + s.z * bfhi(wjp);
        aj1 += s.y * bflo(wjp) + s.w * bfhi(wjp);
    }
    Ai[(base + 0) * HH + tid] = ai0; AjB[(base + 0) * HH + tid] = f2bf(aj0);
    Ai[(base + 1) * HH + tid] = ai1; AjB[(base + 1) * HH + tid] = f2bf(aj1);
}

// ---------------------------------------------------------------- decoder (2 rows/block)
__global__ __launch_bounds__(256) void k_decoder(
    const float* __restrict__ h,
    const float* __restrict__ dw1, const float* __restrict__ db1,
    const float* __restrict__ dw2, const float* __restrict__ db2,
    const float* __restrict__ dw3, const float* __restrict__ db3,
    float* __restrict__ out) {
    __shared__ float shT[HH][2];
    __shared__ float so1T[HH][2];
    __shared__ float so2T[HH][2];
    int tid = threadIdx.x;
    int base = blockIdx.x * 2;
    #pragma unroll
    for (int r = 0; r < 2; ++r) shT[tid][r] = h[(base + r) * HH + tid];
    __syncthreads();
    float a0 = db1[tid], a1 = a0;
    for (int c = 0; c < HH; ++c) {
        float w = dw1[c * HH + tid];
        float2 s = *(const float2*)&shT[c][0];
        a0 += s.x * w; a1 += s.y * w;
    }
    so1T[tid][0] = fmaxf(a0, 0.f); so1T[tid][1] = fmaxf(a1, 0.f);
    __syncthreads();
    a0 = db2[tid]; a1 = a0;
    for (int c = 0; c < HH; ++c) {
        float w = dw2[c * HH + tid];
        float2 s = *(const float2*)&so1T[c][0];
        a0 += s.x * w; a1 += s.y * w;
    }
    so2T[tid][0] = fmaxf(a0, 0.f) + shT[tid][0];
    so2T[tid][1] = fmaxf(a1, 0.f) + shT[tid][1];
    __syncthreads();
    if (tid < 6) {
        int r = tid / 3, c = tid % 3;
        float acc = db3[c];
        for (int k = 0; k < HH; ++k) acc += so2T[k][r] * dw3[k * 3 + c];
        out[(base + r) * 3 + c] = acc;
    }
}

// ---------------------------------------------------------------- launch
extern "C" void kernel_launch(void* const* d_in, const int* in_sizes, int n_in,
                              void* d_out, int out_size, void* d_ws, size_t ws_size,
                              hipStream_t stream) {
    const float* coords = (const float*)d_in[0];
    const float* feats  = (const float*)d_in[1];
    const float* t      = (const float*)d_in[2];
    const float* pe_w1  = (const float*)d_in[3];  const float* pe_b1 = (const float*)d_in[4];
    const float* pe_w2  = (const float*)d_in[5];  const float* pe_b2 = (const float*)d_in[6];
    const float* pe_w3  = (const float*)d_in[7];  const float* pe_b3 = (const float*)d_in[8];
    const float* te_w1  = (const float*)d_in[9];  const float* te_b1 = (const float*)d_in[10];
    const float* te_w2  = (const float*)d_in[11]; const float* te_b2 = (const float*)d_in[12];
    const float* ln_g   = (const float*)d_in[13]; const float* ln_b  = (const float*)d_in[14];
    const float* ew1    = (const float*)d_in[15]; const float* eb1   = (const float*)d_in[16];
    const float* ew2    = (const float*)d_in[17]; const float* eb2   = (const float*)d_in[18];
    const float* cw1    = (const float*)d_in[19]; const float* cb1   = (const float*)d_in[20];
    const float* cw2    = (const float*)d_in[21]; const float* cb2   = (const float*)d_in[22];
    const float* nw1    = (const float*)d_in[23]; const float* nb1   = (const float*)d_in[24];
    const float* nw2    = (const float*)d_in[25]; const float* nb2   = (const float*)d_in[26];
    const float* dec_w1 = (const float*)d_in[27]; const float* dec_b1 = (const float*)d_in[28];
    const float* dec_w2 = (const float*)d_in[29]; const float* dec_b2 = (const float*)d_in[30];
    const float* dec_w3 = (const float*)d_in[31]; const float* dec_b3 = (const float*)d_in[32];

    float* ws = (float*)d_ws;
    float* h      = ws;
    float* hn     = ws + RN;
    float* Ai     = ws + 2 * RN;
    float* magg   = ws + 3 * RN;
    float* x      = ws + 4 * RN;            // 1536 (reserve 2048)
    float* xdelta = ws + 4 * RN + 2048;     // 1536 (reserve 2048)
    unsigned short* AjB  = (unsigned short*)(ws + 4 * RN + 4096);
    unsigned short* ew2P = AjB + RN;                       // LL*65536
    unsigned short* cw1P = ew2P + LL * HH * HH;            // LL*65536
    unsigned short* nw1B = cw1P + LL * HH * HH;            // LL*131072
    unsigned short* ew1B = nw1B + LL * 2 * HH * HH;        // LL*131072
    unsigned short* nw2B = ew1B + LL * 2 * HH * HH;        // LL*65536

    k_convert<<<(LL * 8192 + 511) / 512, 512, 0, stream>>>(ew2, cw1, ew2P, cw1P);
    k_convert2<<<(LL * 131072 + 255) / 256, 256, 0, stream>>>(nw1, nw2, ew1, nw1B, nw2B, ew1B);
    k_encoder<<<NB * NN / 2, 256, 0, stream>>>(coords, feats, t,
        pe_w1, pe_b1, pe_w2, pe_b2, pe_w3, pe_b3, te_w1, te_b1, te_w2, te_b2, h, x);
    k_ln_aiaj<<<NB * NN / 2, 256, 0, stream>>>(h, ln_g, ln_b,
        (const unsigned int*)ew1B, eb1, hn, Ai, AjB);

    for (int l = 0; l < LL; ++l) {
        k_edge<<<NB * NN, 512, 0, stream>>>(x, Ai, AjB,
            ew1 + ((size_t)l * 513 + 512) * HH, eb2 + l * HH,
            ew2P + (size_t)l * HH * HH, cw1P + (size_t)l * HH * HH,
            cb1 + l * HH, cw2 + l * HH, cb2 + l, magg, xdelta);
        int ln = (l + 1 < LL) ? (l + 1) : LL - 1;  // params unused when has_ln=0
        k_node_ln<<<NB * NN / 2, 256, 0, stream>>>(hn, magg,
            (const unsigned int*)(nw1B + (size_t)l * 2 * HH * HH), nb1 + l * HH,
            (const unsigned int*)(nw2B + (size_t)l * HH * HH), nb2 + l * HH, h, x, xdelta,
            ln_g + ln * HH, ln_b + ln * HH,
            (const unsigned int*)(ew1B + (size_t)ln * 2 * HH * HH), eb1 + ln * HH,
            hn, Ai, AjB, (l + 1 < LL) ? 1 : 0);
    }

    k_decoder<<<NB * NN / 2, 256, 0, stream>>>(h, dec_w1, dec_b1, dec_w2, dec_b2,
                                               dec_w3, dec_b3, (float*)d_out);
}

// Round 13
// 644.120 us; speedup vs baseline: 1.1186x; 1.0521x over previous
//
#include <hip/hip_runtime.h>
#include <math.h>

static constexpr int NB = 2, NN = 256, HH = 256, DD = 64, LL = 6;
static constexpr int RN = NB * NN * HH;  // 131072
static constexpr int SROWB = 528;        // padded LDS row stride in bytes (+16B: 2-way banks, imm-foldable)

typedef __attribute__((ext_vector_type(8))) short bf16x8;
typedef __attribute__((ext_vector_type(4))) float f32x4;
typedef __attribute__((ext_vector_type(4))) float float4v;
typedef __attribute__((ext_vector_type(4))) unsigned int u32x4;

__device__ __forceinline__ float fsilu(float v) {
    return v * __builtin_amdgcn_rcpf(1.0f + __expf(-v));
}
__device__ __forceinline__ unsigned short f2bf(float f) {
    union { float f; unsigned int u; } x; x.f = f;
    unsigned int r = x.u + 0x7fffu + ((x.u >> 16) & 1u);
    return (unsigned short)(r >> 16);
}
__device__ __forceinline__ float bitsf(unsigned int u) {
    union { float f; unsigned int u; } x; x.u = u; return x.f;
}
__device__ __forceinline__ float bflo(unsigned int w) { return bitsf(w << 16); }
__device__ __forceinline__ float bfhi(unsigned int w) { return bitsf(w & 0xffff0000u); }
__device__ __forceinline__ unsigned int cvtpk(float lo, float hi) {
    unsigned int w;
    asm("v_cvt_pk_bf16_f32 %0, %1, %2" : "=v"(w) : "v"(lo), "v"(hi));
    return w;
}

// ---------------------------------------------------------------- convert (edge fragment-packed)
__global__ void k_convert(const float* __restrict__ ew2, const float* __restrict__ cw1,
                          unsigned short* __restrict__ ew2P, unsigned short* __restrict__ cw1P) {
    int g = blockIdx.x * blockDim.x + threadIdx.x;
    if (g >= LL * 8192) return;
    int l = g >> 13;
    int r = g & 8191;
    int lane = r & 63;
    int fidx = r >> 6;
    int ks = fidx >> 4;
    int wv = (fidx >> 1) & 7;
    int ct = fidx & 1;
    int col = wv * 32 + ct * 16 + (lane & 15);
    int k0 = ks * 32 + (lane >> 4) * 8;
    #pragma unroll
    for (int e = 0; e < 8; ++e) {
        ew2P[(size_t)g * 8 + e] = f2bf(ew2[((size_t)l * HH + k0 + e) * HH + col]);
        cw1P[(size_t)g * 8 + e] = f2bf(cw1[((size_t)l * HH + k0 + e) * HH + col]);
    }
}

// ---------------------------------------------------------------- convert2 (bf16 pair-packed GEMV weights)
__global__ void k_convert2(const float* __restrict__ nw1, const float* __restrict__ nw2,
                           const float* __restrict__ ew1,
                           unsigned short* __restrict__ nw1B, unsigned short* __restrict__ nw2B,
                           unsigned short* __restrict__ ew1B) {
    int idx = blockIdx.x * blockDim.x + threadIdx.x;
    if (idx >= LL * 131072) return;
    int l = idx >> 17;
    int r = idx & 131071;
    int c = r >> 8, col = r & 255;
    int dst = (l << 17) + ((c >> 1) << 9) + (col << 1) + (c & 1);
    nw1B[dst] = f2bf(nw1[(size_t)l * 131072 + c * 256 + col]);
    ew1B[dst] = f2bf(ew1[(size_t)l * 131328 + c * 256 + col]);  // 513*256 stride
    if (r < 65536) {
        int d2 = (l << 16) + ((c >> 1) << 9) + (col << 1) + (c & 1);
        nw2B[d2] = f2bf(nw2[(size_t)l * 65536 + c * 256 + col]);
    }
}

// ---------------------------------------------------------------- encoder (2 rows/block, broadcast staging)
__global__ __launch_bounds__(256) void k_encoder(
    const float* __restrict__ coords, const float* __restrict__ feats, const float* __restrict__ t,
    const float* __restrict__ pw1, const float* __restrict__ pb1,
    const float* __restrict__ pw2, const float* __restrict__ pb2,
    const float* __restrict__ pw3, const float* __restrict__ pb3,
    const float* __restrict__ tw1, const float* __restrict__ tb1,
    const float* __restrict__ tw2, const float* __restrict__ tb2,
    float* __restrict__ h, float* __restrict__ x) {
    __shared__ float spinT[68][2];
    __shared__ float shaT[HH][2];
    __shared__ float shbT[HH][2];
    __shared__ float ste1[HH];
    int tid = threadIdx.x;
    int base = blockIdx.x * 2;
    int b = base / NN;

    #pragma unroll
    for (int r = 0; r < 2; ++r) {
        int row = base + r;
        if (tid < 3) spinT[tid][r] = coords[row * 3 + tid];
        if (tid < DD) spinT[3 + tid][r] = feats[row * DD + tid];
    }
    float tv = t[b];
    ste1[tid] = fmaxf(tv * tw1[tid] + tb1[tid], 0.0f);
    if (tid < 6) {
        int r = tid / 3, c = tid % 3;
        x[(base + r) * 3 + c] = coords[(base + r) * 3 + c];
    }
    __syncthreads();

    float a0 = pb1[tid], a1 = a0;
    for (int c = 0; c < 67; ++c) {
        float w = pw1[c * HH + tid];
        float2 s = *(const float2*)&spinT[c][0];
        a0 += s.x * w; a1 += s.y * w;
    }
    shaT[tid][0] = fmaxf(a0, 0.f); shaT[tid][1] = fmaxf(a1, 0.f);
    __syncthreads();
    a0 = pb2[tid]; a1 = a0;
    for (int c = 0; c < HH; ++c) {
        float w = pw2[c * HH + tid];
        float2 s = *(const float2*)&shaT[c][0];
        a0 += s.x * w; a1 += s.y * w;
    }
    shbT[tid][0] = fmaxf(a0, 0.f); shbT[tid][1] = fmaxf(a1, 0.f);
    __syncthreads();
    a0 = pb3[tid]; a1 = a0;
    float te = tb2[tid];
    for (int c = 0; c < HH; ++c) {
        float w = pw3[c * HH + tid];
        float2 s = *(const float2*)&shbT[c][0];
        a0 += s.x * w; a1 += s.y * w;
        te += ste1[c] * tw2[c * HH + tid];
    }
    h[(base + 0) * HH + tid] = fmaxf(a0, 0.f) + te;
    h[(base + 1) * HH + tid] = fmaxf(a1, 0.f) + te;
}

// ---------------------------------------------------------------- LayerNorm + Ai/Aj (layer 0; bf16 ew1)
__global__ __launch_bounds__(256) void k_ln_aiaj(
    const float* __restrict__ h, const float* __restrict__ g, const float* __restrict__ bta,
    const unsigned int* __restrict__ ew1w, const float* __restrict__ eb1l,
    float* __restrict__ hn, float* __restrict__ Ai, unsigned short* __restrict__ AjB) {
    __shared__ float shnT[HH][2];
    int tid = threadIdx.x, wv = tid >> 6, lane = tid & 63;
    int base = blockIdx.x * 2;

    if (wv < 2) {
        int row = base + wv;
        float v[4];
        #pragma unroll
        for (int q = 0; q < 4; ++q) v[q] = h[row * HH + lane + 64 * q];
        float s = v[0] + v[1] + v[2] + v[3];
        #pragma unroll
        for (int m = 1; m < 64; m <<= 1) s += __shfl_xor(s, m);
        float mu = s * (1.0f / HH);
        float var = 0.f;
        #pragma unroll
        for (int q = 0; q < 4; ++q) { v[q] -= mu; var += v[q] * v[q]; }
        #pragma unroll
        for (int m = 1; m < 64; m <<= 1) var += __shfl_xor(var, m);
        float rstd = rsqrtf(var * (1.0f / HH) + 1e-5f);
        #pragma unroll
        for (int q = 0; q < 4; ++q) {
            int k = lane + 64 * q;
            float hv = v[q] * rstd * g[k] + bta[k];
            shnT[k][wv] = hv;
            hn[row * HH + k] = hv;
        }
    }
    __syncthreads();

    float ai0 = eb1l[tid], ai1 = ai0;
    float aj0 = 0.f, aj1 = 0.f;
    for (int c2 = 0; c2 < 128; ++c2) {
        unsigned int wip = ew1w[c2 * 256 + tid];
        unsigned int wjp = ew1w[(128 + c2) * 256 + tid];
        float4 s = *(const float4*)&shnT[c2 * 2][0];
        ai0 += s.x * bflo(wip) + s.z * bfhi(wip);
        ai1 += s.y * bflo(wip) + s.w * bfhi(wip);
        aj0 += s.x * bflo(wjp) + s.z * bfhi(wjp);
        aj1 += s.y * bflo(wjp) + s.w * bfhi(wjp);
    }
    Ai[(base + 0) * HH + tid] = ai0; AjB[(base + 0) * HH + tid] = f2bf(aj0);
    Ai[(base + 1) * HH + tid] = ai1; AjB[(base + 1) * HH + tid] = f2bf(aj1);
}

// ---------------------------------------------------------------- fused edge pipeline (MFMA)
// Round-12 structure + RESIDENT B: all 32 B-fragments (ew2+cw1, 128 VGPR)
// loaded ONCE per block. Kills the ~2MB/block L2 B-streaming (~30us of the
// 42us block time). Requires the 256-VGPR budget that ONLY
// __launch_bounds__(512, 1) provides (arg2 = min BLOCKS/CU on hipcc; any
// higher value caps regalloc at <=128 and spills — rounds 2-5, 8). DO NOT TOUCH.
__global__ __launch_bounds__(512, 1) void k_edge(
    const float* __restrict__ x, const float* __restrict__ Ai, const unsigned short* __restrict__ AjB,
    const float* __restrict__ wd, const float* __restrict__ eb2v,
    const unsigned short* __restrict__ ew2P, const unsigned short* __restrict__ cw1P,
    const float* __restrict__ cb1v, const float* __restrict__ cw2v, const float* __restrict__ cb2p,
    float* __restrict__ magg, float* __restrict__ xdelta) {
    __shared__ float srel[64][3];
    __shared__ float sd2[64];
    __shared__ float cwpart[8][64];
    __shared__ char s_tile[64 * SROWB];  // 33.8KB
    __shared__ char m_tile[64 * SROWB];  // 33.8KB

    int tid = threadIdx.x, wv = tid >> 6, lane = tid & 63;
    int g4 = lane >> 4, l15 = lane & 15;
    int colbase = wv * 32;
    int bi = blockIdx.x;
    int b = bi >> 8, i = bi & 255;
    int ni = b * NN + i;
    int bbase = b * NN;
    int bthr = ((wv << 7) + lane) << 3;

    int k0p = (tid & 31) << 3;
    float aiv[8], wdv[8];
    {
        float4v a0 = *(const float4v*)(Ai + (size_t)ni * HH + k0p);
        float4v a1 = *(const float4v*)(Ai + (size_t)ni * HH + k0p + 4);
        float4v w0 = *(const float4v*)(wd + k0p);
        float4v w1 = *(const float4v*)(wd + k0p + 4);
        #pragma unroll
        for (int e = 0; e < 4; ++e) { aiv[e] = a0[e]; aiv[4 + e] = a1[e]; wdv[e] = w0[e]; wdv[4 + e] = w1[e]; }
    }
    float eb2r[2], cb1r[2], cw2r[2];
    #pragma unroll
    for (int ct = 0; ct < 2; ++ct) {
        int col = colbase + ct * 16 + l15;
        eb2r[ct] = eb2v[col]; cb1r[ct] = cb1v[col]; cw2r[ct] = cw2v[col];
    }
    float xi0 = x[ni * 3 + 0], xi1 = x[ni * 3 + 1], xi2 = x[ni * 3 + 2];
    float cb2 = cb2p[0];

    // ---- resident B fragments: 16 + 16 bf16x8 = 128 VGPR, loaded once
    bf16x8 Bew[8][2], Bcw[8][2];
    #pragma unroll
    for (int ks = 0; ks < 8; ++ks) {
        #pragma unroll
        for (int ct = 0; ct < 2; ++ct) {
            Bew[ks][ct] = *(const bf16x8*)(ew2P + (ks << 13) + (ct << 9) + bthr);
            Bcw[ks][ct] = *(const bf16x8*)(cw1P + (ks << 13) + (ct << 9) + bthr);
        }
    }

    // per-thread LDS byte bases (all offsets from these are compile-time)
    char* p1w = s_tile + ((tid >> 5) * SROWB + k0p * 2);
    const char* aA = s_tile + (l15 * SROWB + g4 * 16);
    const char* aM = m_tile + (l15 * SROWB + g4 * 16);
    char* mwA = m_tile + ((g4 * 4) * SROWB + (colbase + l15) * 2);
    float mgv[2] = {0.f, 0.f};
    float xd0 = 0.f, xd1 = 0.f, xd2 = 0.f;

    #pragma unroll 1
    for (int jc = 0; jc < 4; ++jc) {
        int j0 = jc * 64;
        __syncthreads();
        if (tid < 64) {
            int j = bbase + j0 + tid;
            float rx = xi0 - x[j * 3 + 0];
            float ry = xi1 - x[j * 3 + 1];
            float rz = xi2 - x[j * 3 + 2];
            srel[tid][0] = rx; srel[tid][1] = ry; srel[tid][2] = rz;
            sd2[tid] = rx * rx + ry * ry + rz * rz;
        }
        __syncthreads();

        // ---- phase 1: s tile = silu(Ai + Aj + d2*wd), 64x256 bf16
        #pragma unroll
        for (int it = 0; it < 4; ++it) {
            int row = it * 16 + (tid >> 5);
            float d2v = sd2[row];
            u32x4 ajw = *(const u32x4*)(AjB + ((size_t)(bbase + j0 + row) * HH + k0p));
            unsigned int uw0, uw1, uw2, uw3;
            uw0 = cvtpk(fsilu(aiv[0] + bflo(ajw[0]) + d2v * wdv[0]), fsilu(aiv[1] + bfhi(ajw[0]) + d2v * wdv[1]));
            uw1 = cvtpk(fsilu(aiv[2] + bflo(ajw[1]) + d2v * wdv[2]), fsilu(aiv[3] + bfhi(ajw[1]) + d2v * wdv[3]));
            uw2 = cvtpk(fsilu(aiv[4] + bflo(ajw[2]) + d2v * wdv[4]), fsilu(aiv[5] + bfhi(ajw[2]) + d2v * wdv[5]));
            uw3 = cvtpk(fsilu(aiv[6] + bflo(ajw[3]) + d2v * wdv[6]), fsilu(aiv[7] + bfhi(ajw[3]) + d2v * wdv[7]));
            u32x4 sv = {uw0, uw1, uw2, uw3};
            *reinterpret_cast<u32x4*>(p1w + it * 16 * SROWB) = sv;
        }
        __syncthreads();

        // ---- phase 2: m = silu(s @ ew2 + eb2), two 32-row half-passes
        #pragma unroll 1
        for (int rh = 0; rh < 2; ++rh) {
            f32x4 acc[2][2];
            acc[0][0] = (f32x4){0.f,0.f,0.f,0.f}; acc[0][1] = (f32x4){0.f,0.f,0.f,0.f};
            acc[1][0] = (f32x4){0.f,0.f,0.f,0.f}; acc[1][1] = (f32x4){0.f,0.f,0.f,0.f};
            const char* aBase = aA + rh * 32 * SROWB;
            #pragma unroll
            for (int ks = 0; ks < 8; ++ks) {
                bf16x8 a0 = *reinterpret_cast<const bf16x8*>(aBase + ks * 64);
                bf16x8 a1 = *reinterpret_cast<const bf16x8*>(aBase + 16 * SROWB + ks * 64);
                acc[0][0] = __builtin_amdgcn_mfma_f32_16x16x32_bf16(a0, Bew[ks][0], acc[0][0], 0, 0, 0);
                acc[0][1] = __builtin_amdgcn_mfma_f32_16x16x32_bf16(a0, Bew[ks][1], acc[0][1], 0, 0, 0);
                acc[1][0] = __builtin_amdgcn_mfma_f32_16x16x32_bf16(a1, Bew[ks][0], acc[1][0], 0, 0, 0);
                acc[1][1] = __builtin_amdgcn_mfma_f32_16x16x32_bf16(a1, Bew[ks][1], acc[1][1], 0, 0, 0);
            }
            char* mw = mwA + rh * 32 * SROWB;
            #pragma unroll
            for (int rt = 0; rt < 2; ++rt) {
                #pragma unroll
                for (int r = 0; r < 4; ++r) {
                    float v0 = fsilu(acc[rt][0][r] + eb2r[0]);
                    float v1 = fsilu(acc[rt][1][r] + eb2r[1]);
                    mgv[0] += v0; mgv[1] += v1;
                    unsigned int w = cvtpk(v0, v1);
                    char* p = mw + (rt * 16 + r) * SROWB;
                    *reinterpret_cast<unsigned short*>(p) = (unsigned short)w;
                    *reinterpret_cast<unsigned short*>(p + 32) = (unsigned short)(w >> 16);
                }
            }
        }
        __syncthreads();

        // ---- phase 3: c = silu(m @ cw1 + cb1); cw-row-dot with cw2 (two half-passes)
        #pragma unroll 1
        for (int rh = 0; rh < 2; ++rh) {
            f32x4 acc[2][2];
            acc[0][0] = (f32x4){0.f,0.f,0.f,0.f}; acc[0][1] = (f32x4){0.f,0.f,0.f,0.f};
            acc[1][0] = (f32x4){0.f,0.f,0.f,0.f}; acc[1][1] = (f32x4){0.f,0.f,0.f,0.f};
            const char* aBase = aM + rh * 32 * SROWB;
            #pragma unroll
            for (int ks = 0; ks < 8; ++ks) {
                bf16x8 a0 = *reinterpret_cast<const bf16x8*>(aBase + ks * 64);
                bf16x8 a1 = *reinterpret_cast<const bf16x8*>(aBase + 16 * SROWB + ks * 64);
                acc[0][0] = __builtin_amdgcn_mfma_f32_16x16x32_bf16(a0, Bcw[ks][0], acc[0][0], 0, 0, 0);
                acc[0][1] = __builtin_amdgcn_mfma_f32_16x16x32_bf16(a0, Bcw[ks][1], acc[0][1], 0, 0, 0);
                acc[1][0] = __builtin_amdgcn_mfma_f32_16x16x32_bf16(a1, Bcw[ks][0], acc[1][0], 0, 0, 0);
                acc[1][1] = __builtin_amdgcn_mfma_f32_16x16x32_bf16(a1, Bcw[ks][1], acc[1][1], 0, 0, 0);
            }
            float rs[8];
            #pragma unroll
            for (int q = 0; q < 8; ++q) rs[q] = 0.f;
            #pragma unroll
            for (int ct = 0; ct < 2; ++ct) {
                #pragma unroll
                for (int rt = 0; rt < 2; ++rt)
                    #pragma unroll
                    for (int r = 0; r < 4; ++r)
                        rs[rt * 4 + r] += fsilu(acc[rt][ct][r] + cb1r[ct]) * cw2r[ct];
            }
            #pragma unroll
            for (int m = 1; m <= 8; m <<= 1)
                #pragma unroll
                for (int q = 0; q < 8; ++q) rs[q] += __shfl_xor(rs[q], m);
            if (l15 == 0) {
                #pragma unroll
                for (int rt = 0; rt < 2; ++rt)
                    #pragma unroll
                    for (int r = 0; r < 4; ++r)
                        cwpart[wv][rh * 32 + rt * 16 + g4 * 4 + r] = rs[rt * 4 + r];
            }
        }
        __syncthreads();
        if (tid < 64) {
            float cwv = cb2;
            #pragma unroll
            for (int w = 0; w < 8; ++w) cwv += cwpart[w][tid];
            float p0 = srel[tid][0] * cwv;
            float p1 = srel[tid][1] * cwv;
            float p2 = srel[tid][2] * cwv;
            #pragma unroll
            for (int m = 1; m < 64; m <<= 1) {
                p0 += __shfl_xor(p0, m); p1 += __shfl_xor(p1, m); p2 += __shfl_xor(p2, m);
            }
            xd0 += p0; xd1 += p1; xd2 += p2;
        }
    }

    #pragma unroll
    for (int ct = 0; ct < 2; ++ct) {
        mgv[ct] += __shfl_xor(mgv[ct], 16);
        mgv[ct] += __shfl_xor(mgv[ct], 32);
    }
    if (lane < 16) {
        #pragma unroll
        for (int ct = 0; ct < 2; ++ct)
            magg[(size_t)ni * HH + colbase + ct * 16 + lane] = mgv[ct];
    }
    if (tid == 0) {
        xdelta[ni * 3 + 0] = xd0 * (1.0f / NN);
        xdelta[ni * 3 + 1] = xd1 * (1.0f / NN);
        xdelta[ni * 3 + 2] = xd2 * (1.0f / NN);
    }
}

// ---------------------------------------------------------------- fused node update + next-layer LN/Ai/Aj
__global__ __launch_bounds__(256) void k_node_ln(
    const float* __restrict__ hn, const float* __restrict__ magg,
    const unsigned int* __restrict__ nw1w, const float* __restrict__ nb1l,
    const unsigned int* __restrict__ nw2w, const float* __restrict__ nb2l,
    float* __restrict__ h, float* __restrict__ x, const float* __restrict__ xdelta,
    const float* __restrict__ g, const float* __restrict__ bta,
    const unsigned int* __restrict__ ew1w, const float* __restrict__ eb1l,
    float* __restrict__ hnout, float* __restrict__ Ai, unsigned short* __restrict__ AjB,
    int has_ln) {
    __shared__ float s2T[2 * HH][2];
    __shared__ float suT[HH][2];
    __shared__ float sh[2][HH];
    __shared__ float shnT[HH][2];
    int tid = threadIdx.x;
    int base = blockIdx.x * 2;
    #pragma unroll
    for (int r = 0; r < 2; ++r) {
        s2T[tid][r] = hn[(base + r) * HH + tid];
        s2T[HH + tid][r] = magg[(base + r) * HH + tid];
    }
    if (tid < 6) {
        int r = tid / 3, c = tid % 3;
        x[(base + r) * 3 + c] += xdelta[(base + r) * 3 + c];
    }
    __syncthreads();
    float a0 = nb1l[tid], a1 = a0;
    for (int c2 = 0; c2 < 256; ++c2) {
        unsigned int wp = nw1w[c2 * 256 + tid];
        float4 s = *(const float4*)&s2T[c2 * 2][0];
        a0 += s.x * bflo(wp) + s.z * bfhi(wp);
        a1 += s.y * bflo(wp) + s.w * bfhi(wp);
    }
    suT[tid][0] = fsilu(a0); suT[tid][1] = fsilu(a1);
    __syncthreads();
    float d0 = nb2l[tid], d1 = d0;
    for (int c2 = 0; c2 < 128; ++c2) {
        unsigned int wp = nw2w[c2 * 256 + tid];
        float4 s = *(const float4*)&suT[c2 * 2][0];
        d0 += s.x * bflo(wp) + s.z * bfhi(wp);
        d1 += s.y * bflo(wp) + s.w * bfhi(wp);
    }
    float h0 = h[(base + 0) * HH + tid] + d0;
    float h1 = h[(base + 1) * HH + tid] + d1;
    h[(base + 0) * HH + tid] = h0;
    h[(base + 1) * HH + tid] = h1;
    if (!has_ln) return;
    sh[0][tid] = h0; sh[1][tid] = h1;
    __syncthreads();

    int wv = tid >> 6, lane = tid & 63;
    if (wv < 2) {
        int row = base + wv;
        float v[4];
        #pragma unroll
        for (int q = 0; q < 4; ++q) v[q] = sh[wv][lane + 64 * q];
        float s = v[0] + v[1] + v[2] + v[3];
        #pragma unroll
        for (int m = 1; m < 64; m <<= 1) s += __shfl_xor(s, m);
        float mu = s * (1.0f / HH);
        float var = 0.f;
        #pragma unroll
        for (int q = 0; q < 4; ++q) { v[q] -= mu; var += v[q] * v[q]; }
        #pragma unroll
        for (int m = 1; m < 64; m <<= 1) var += __shfl_xor(var, m);
        float rstd = rsqrtf(var * (1.0f / HH) + 1e-5f);
        #pragma unroll
        for (int q = 0; q < 4; ++q) {
            int k = lane + 64 * q;
            float hv = v[q] * rstd * g[k] + bta[k];
            shnT[k][wv] = hv;
            hnout[row * HH + k] = hv;
        }
    }
    __syncthreads();

    float ai0 = eb1l[tid], ai1 = ai0;
    float aj0 = 0.f, aj1 = 0.f;
    for (int c2 = 0; c2 < 128; ++c2) {
        unsigned int wip = ew1w[c2 * 256 + tid];
        unsigned int wjp = ew1w[(128 + c2) * 256 + tid];
        float4 s = *(const float4*)&shnT[c2 * 2][0];
        ai0 += s.x * bflo(wip) + s.z * bfhi(wip);
        ai1 += s.y * bflo(wip) + s.w * bfhi(wip);
        aj0 += s.x * bflo(wjp) + s.z * bfhi(wjp);
        aj1 += s.y * bflo(wjp) + s.w * bfhi(wjp);
    }
    Ai[(base + 0) * HH + tid] = ai0; AjB[(base + 0) * HH + tid] = f2bf(aj0);
    Ai[(base + 1) * HH + tid] = ai1; AjB[(base + 1) * HH + tid] = f2bf(aj1);
}

// ---------------------------------------------------------------- decoder (2 rows/block)
__global__ __launch_bounds__(256) void k_decoder(
    const float* __restrict__ h,
    const float* __restrict__ dw1, const float* __restrict__ db1,
    const float* __restrict__ dw2, const float* __restrict__ db2,
    const float* __restrict__ dw3, const float* __restrict__ db3,
    float* __restrict__ out) {
    __shared__ float shT[HH][2];
    __shared__ float so1T[HH][2];
    __shared__ float so2T[HH][2];
    int tid = threadIdx.x;
    int base = blockIdx.x * 2;
    #pragma unroll
    for (int r = 0; r < 2; ++r) shT[tid][r] = h[(base + r) * HH + tid];
    __syncthreads();
    float a0 = db1[tid], a1 = a0;
    for (int c = 0; c < HH; ++c) {
        float w = dw1[c * HH + tid];
        float2 s = *(const float2*)&shT[c][0];
        a0 += s.x * w; a1 += s.y * w;
    }
    so1T[tid][0] = fmaxf(a0, 0.f); so1T[tid][1] = fmaxf(a1, 0.f);
    __syncthreads();
    a0 = db2[tid]; a1 = a0;
    for (int c = 0; c < HH; ++c) {
        float w = dw2[c * HH + tid];
        float2 s = *(const float2*)&so1T[c][0];
        a0 += s.x * w; a1 += s.y * w;
    }
    so2T[tid][0] = fmaxf(a0, 0.f) + shT[tid][0];
    so2T[tid][1] = fmaxf(a1, 0.f) + shT[tid][1];
    __syncthreads();
    if (tid < 6) {
        int r = tid / 3, c = tid % 3;
        float acc = db3[c];
        for (int k = 0; k < HH; ++k) acc += so2T[k][r] * dw3[k * 3 + c];
        out[(base + r) * 3 + c] = acc;
    }
}

// ---------------------------------------------------------------- launch
extern "C" void kernel_launch(void* const* d_in, const int* in_sizes, int n_in,
                              void* d_out, int out_size, void* d_ws, size_t ws_size,
                              hipStream_t stream) {
    const float* coords = (const float*)d_in[0];
    const float* feats  = (const float*)d_in[1];
    const float* t      = (const float*)d_in[2];
    const float* pe_w1  = (const float*)d_in[3];  const float* pe_b1 = (const float*)d_in[4];
    const float* pe_w2  = (const float*)d_in[5];  const float* pe_b2 = (const float*)d_in[6];
    const float* pe_w3  = (const float*)d_in[7];  const float* pe_b3 = (const float*)d_in[8];
    const float* te_w1  = (const float*)d_in[9];  const float* te_b1 = (const float*)d_in[10];
    const float* te_w2  = (const float*)d_in[11]; const float* te_b2 = (const float*)d_in[12];
    const float* ln_g   = (const float*)d_in[13]; const float* ln_b  = (const float*)d_in[14];
    const float* ew1    = (const float*)d_in[15]; const float* eb1   = (const float*)d_in[16];
    const float* ew2    = (const float*)d_in[17]; const float* eb2   = (const float*)d_in[18];
    const float* cw1    = (const float*)d_in[19]; const float* cb1   = (const float*)d_in[20];
    const float* cw2    = (const float*)d_in[21]; const float* cb2   = (const float*)d_in[22];
    const float* nw1    = (const float*)d_in[23]; const float* nb1   = (const float*)d_in[24];
    const float* nw2    = (const float*)d_in[25]; const float* nb2   = (const float*)d_in[26];
    const float* dec_w1 = (const float*)d_in[27]; const float* dec_b1 = (const float*)d_in[28];
    const float* dec_w2 = (const float*)d_in[29]; const float* dec_b2 = (const float*)d_in[30];
    const float* dec_w3 = (const float*)d_in[31]; const float* dec_b3 = (const float*)d_in[32];

    float* ws = (float*)d_ws;
    float* h      = ws;
    float* hn     = ws + RN;
    float* Ai     = ws + 2 * RN;
    float* magg   = ws + 3 * RN;
    float* x      = ws + 4 * RN;            // 1536 (reserve 2048)
    float* xdelta = ws + 4 * RN + 2048;     // 1536 (reserve 2048)
    unsigned short* AjB  = (unsigned short*)(ws + 4 * RN + 4096);
    unsigned short* ew2P = AjB + RN;                       // LL*65536
    unsigned short* cw1P = ew2P + LL * HH * HH;            // LL*65536
    unsigned short* nw1B = cw1P + LL * HH * HH;            // LL*131072
    unsigned short* ew1B = nw1B + LL * 2 * HH * HH;        // LL*131072
    unsigned short* nw2B = ew1B + LL * 2 * HH * HH;        // LL*65536

    k_convert<<<(LL * 8192 + 511) / 512, 512, 0, stream>>>(ew2, cw1, ew2P, cw1P);
    k_convert2<<<(LL * 131072 + 255) / 256, 256, 0, stream>>>(nw1, nw2, ew1, nw1B, nw2B, ew1B);
    k_encoder<<<NB * NN / 2, 256, 0, stream>>>(coords, feats, t,
        pe_w1, pe_b1, pe_w2, pe_b2, pe_w3, pe_b3, te_w1, te_b1, te_w2, te_b2, h, x);
    k_ln_aiaj<<<NB * NN / 2, 256, 0, stream>>>(h, ln_g, ln_b,
        (const unsigned int*)ew1B, eb1, hn, Ai, AjB);

    for (int l = 0; l < LL; ++l) {
        k_edge<<<NB * NN, 512, 0, stream>>>(x, Ai, AjB,
            ew1 + ((size_t)l * 513 + 512) * HH, eb2 + l * HH,
            ew2P + (size_t)l * HH * HH, cw1P + (size_t)l * HH * HH,
            cb1 + l * HH, cw2 + l * HH, cb2 + l, magg, xdelta);
        int ln = (l + 1 < LL) ? (l + 1) : LL - 1;  // params unused when has_ln=0
        k_node_ln<<<NB * NN / 2, 256, 0, stream>>>(hn, magg,
            (const unsigned int*)(nw1B + (size_t)l * 2 * HH * HH), nb1 + l * HH,
            (const unsigned int*)(nw2B + (size_t)l * HH * HH), nb2 + l * HH, h, x, xdelta,
            ln_g + ln * HH, ln_b + ln * HH,
            (const unsigned int*)(ew1B + (size_t)ln * 2 * HH * HH), eb1 + ln * HH,
            hn, Ai, AjB, (l + 1 < LL) ? 1 : 0);
    }

    k_decoder<<<NB * NN / 2, 256, 0, stream>>>(h, dec_w1, dec_b1, dec_w2, dec_b2,
                                               dec_w3, dec_b3, (float*)d_out);
}

// Round 14
// 643.894 us; speedup vs baseline: 1.1190x; 1.0004x over previous
//
#include <hip/hip_runtime.h>
#include <math.h>

static constexpr int NB = 2, NN = 256, HH = 256, DD = 64, LL = 6;
static constexpr int RN = NB * NN * HH;  // 131072
static constexpr int SROWB = 528;        // padded LDS row stride in bytes (+16B: 2-way banks, imm-foldable)

typedef __attribute__((ext_vector_type(8))) short bf16x8;
typedef __attribute__((ext_vector_type(4))) float f32x4;
typedef __attribute__((ext_vector_type(4))) float float4v;
typedef __attribute__((ext_vector_type(4))) unsigned int u32x4;

__device__ __forceinline__ float fsilu(float v) {
    return v * __builtin_amdgcn_rcpf(1.0f + __expf(-v));
}
__device__ __forceinline__ unsigned short f2bf(float f) {
    union { float f; unsigned int u; } x; x.f = f;
    unsigned int r = x.u + 0x7fffu + ((x.u >> 16) & 1u);
    return (unsigned short)(r >> 16);
}
__device__ __forceinline__ float bitsf(unsigned int u) {
    union { float f; unsigned int u; } x; x.u = u; return x.f;
}
__device__ __forceinline__ float bflo(unsigned int w) { return bitsf(w << 16); }
__device__ __forceinline__ float bfhi(unsigned int w) { return bitsf(w & 0xffff0000u); }
__device__ __forceinline__ unsigned int cvtpk(float lo, float hi) {
    unsigned int w;
    asm("v_cvt_pk_bf16_f32 %0, %1, %2" : "=v"(w) : "v"(lo), "v"(hi));
    return w;
}

// ---------------------------------------------------------------- convert (edge fragment-packed)
__global__ void k_convert(const float* __restrict__ ew2, const float* __restrict__ cw1,
                          unsigned short* __restrict__ ew2P, unsigned short* __restrict__ cw1P) {
    int g = blockIdx.x * blockDim.x + threadIdx.x;
    if (g >= LL * 8192) return;
    int l = g >> 13;
    int r = g & 8191;
    int lane = r & 63;
    int fidx = r >> 6;
    int ks = fidx >> 4;
    int wv = (fidx >> 1) & 7;
    int ct = fidx & 1;
    int col = wv * 32 + ct * 16 + (lane & 15);
    int k0 = ks * 32 + (lane >> 4) * 8;
    #pragma unroll
    for (int e = 0; e < 8; ++e) {
        ew2P[(size_t)g * 8 + e] = f2bf(ew2[((size_t)l * HH + k0 + e) * HH + col]);
        cw1P[(size_t)g * 8 + e] = f2bf(cw1[((size_t)l * HH + k0 + e) * HH + col]);
    }
}

// ---------------------------------------------------------------- convert2 (bf16 pair-packed GEMV weights)
__global__ void k_convert2(const float* __restrict__ nw1, const float* __restrict__ nw2,
                           const float* __restrict__ ew1,
                           unsigned short* __restrict__ nw1B, unsigned short* __restrict__ nw2B,
                           unsigned short* __restrict__ ew1B) {
    int idx = blockIdx.x * blockDim.x + threadIdx.x;
    if (idx >= LL * 131072) return;
    int l = idx >> 17;
    int r = idx & 131071;
    int c = r >> 8, col = r & 255;
    int dst = (l << 17) + ((c >> 1) << 9) + (col << 1) + (c & 1);
    nw1B[dst] = f2bf(nw1[(size_t)l * 131072 + c * 256 + col]);
    ew1B[dst] = f2bf(ew1[(size_t)l * 131328 + c * 256 + col]);  // 513*256 stride
    if (r < 65536) {
        int d2 = (l << 16) + ((c >> 1) << 9) + (col << 1) + (c & 1);
        nw2B[d2] = f2bf(nw2[(size_t)l * 65536 + c * 256 + col]);
    }
}

// ---------------------------------------------------------------- encoder (2 rows/block, broadcast staging)
__global__ __launch_bounds__(256) void k_encoder(
    const float* __restrict__ coords, const float* __restrict__ feats, const float* __restrict__ t,
    const float* __restrict__ pw1, const float* __restrict__ pb1,
    const float* __restrict__ pw2, const float* __restrict__ pb2,
    const float* __restrict__ pw3, const float* __restrict__ pb3,
    const float* __restrict__ tw1, const float* __restrict__ tb1,
    const float* __restrict__ tw2, const float* __restrict__ tb2,
    float* __restrict__ h, float* __restrict__ x) {
    __shared__ float spinT[68][2];
    __shared__ float shaT[HH][2];
    __shared__ float shbT[HH][2];
    __shared__ float ste1[HH];
    int tid = threadIdx.x;
    int base = blockIdx.x * 2;
    int b = base / NN;

    #pragma unroll
    for (int r = 0; r < 2; ++r) {
        int row = base + r;
        if (tid < 3) spinT[tid][r] = coords[row * 3 + tid];
        if (tid < DD) spinT[3 + tid][r] = feats[row * DD + tid];
    }
    float tv = t[b];
    ste1[tid] = fmaxf(tv * tw1[tid] + tb1[tid], 0.0f);
    if (tid < 6) {
        int r = tid / 3, c = tid % 3;
        x[(base + r) * 3 + c] = coords[(base + r) * 3 + c];
    }
    __syncthreads();

    float a0 = pb1[tid], a1 = a0;
    for (int c = 0; c < 67; ++c) {
        float w = pw1[c * HH + tid];
        float2 s = *(const float2*)&spinT[c][0];
        a0 += s.x * w; a1 += s.y * w;
    }
    shaT[tid][0] = fmaxf(a0, 0.f); shaT[tid][1] = fmaxf(a1, 0.f);
    __syncthreads();
    a0 = pb2[tid]; a1 = a0;
    for (int c = 0; c < HH; ++c) {
        float w = pw2[c * HH + tid];
        float2 s = *(const float2*)&shaT[c][0];
        a0 += s.x * w; a1 += s.y * w;
    }
    shbT[tid][0] = fmaxf(a0, 0.f); shbT[tid][1] = fmaxf(a1, 0.f);
    __syncthreads();
    a0 = pb3[tid]; a1 = a0;
    float te = tb2[tid];
    for (int c = 0; c < HH; ++c) {
        float w = pw3[c * HH + tid];
        float2 s = *(const float2*)&shbT[c][0];
        a0 += s.x * w; a1 += s.y * w;
        te += ste1[c] * tw2[c * HH + tid];
    }
    h[(base + 0) * HH + tid] = fmaxf(a0, 0.f) + te;
    h[(base + 1) * HH + tid] = fmaxf(a1, 0.f) + te;
}

// ---------------------------------------------------------------- LayerNorm + Ai/Aj (layer 0; bf16 ew1)
__global__ __launch_bounds__(256) void k_ln_aiaj(
    const float* __restrict__ h, const float* __restrict__ g, const float* __restrict__ bta,
    const unsigned int* __restrict__ ew1w, const float* __restrict__ eb1l,
    float* __restrict__ hn, float* __restrict__ Ai, unsigned short* __restrict__ AjB) {
    __shared__ float shnT[HH][2];
    int tid = threadIdx.x, wv = tid >> 6, lane = tid & 63;
    int base = blockIdx.x * 2;

    if (wv < 2) {
        int row = base + wv;
        float v[4];
        #pragma unroll
        for (int q = 0; q < 4; ++q) v[q] = h[row * HH + lane + 64 * q];
        float s = v[0] + v[1] + v[2] + v[3];
        #pragma unroll
        for (int m = 1; m < 64; m <<= 1) s += __shfl_xor(s, m);
        float mu = s * (1.0f / HH);
        float var = 0.f;
        #pragma unroll
        for (int q = 0; q < 4; ++q) { v[q] -= mu; var += v[q] * v[q]; }
        #pragma unroll
        for (int m = 1; m < 64; m <<= 1) var += __shfl_xor(var, m);
        float rstd = rsqrtf(var * (1.0f / HH) + 1e-5f);
        #pragma unroll
        for (int q = 0; q < 4; ++q) {
            int k = lane + 64 * q;
            float hv = v[q] * rstd * g[k] + bta[k];
            shnT[k][wv] = hv;
            hn[row * HH + k] = hv;
        }
    }
    __syncthreads();

    float ai0 = eb1l[tid], ai1 = ai0;
    float aj0 = 0.f, aj1 = 0.f;
    for (int c2 = 0; c2 < 128; ++c2) {
        unsigned int wip = ew1w[c2 * 256 + tid];
        unsigned int wjp = ew1w[(128 + c2) * 256 + tid];
        float4 s = *(const float4*)&shnT[c2 * 2][0];
        ai0 += s.x * bflo(wip) + s.z * bfhi(wip);
        ai1 += s.y * bflo(wip) + s.w * bfhi(wip);
        aj0 += s.x * bflo(wjp) + s.z * bfhi(wjp);
        aj1 += s.y * bflo(wjp) + s.w * bfhi(wjp);
    }
    Ai[(base + 0) * HH + tid] = ai0; AjB[(base + 0) * HH + tid] = f2bf(aj0);
    Ai[(base + 1) * HH + tid] = ai1; AjB[(base + 1) * HH + tid] = f2bf(aj1);
}

// ---------------------------------------------------------------- fused edge pipeline (MFMA)
// Round-13 structure with __launch_bounds__(512, 2): arg2 on hipcc sets the
// resident-blocks target — it caps regalloc at 512regs/(2*8waves/4simd)=128
// AND enables 2 blocks/CU residency (16 waves). Rounds 2-5 spilled under this
// cap because their working set was >128 VGPR; the current kernel compiles to
// 120 VGPR (round 13), so the cap is free and the 2nd resident block overlaps
// barrier stalls. LDS 2*70656 = 141KB < 160KB. Check: WRITE_SIZE must stay
// ~532KB (no spill) and Occupancy ~20%->~45%.
__global__ __launch_bounds__(512, 2) void k_edge(
    const float* __restrict__ x, const float* __restrict__ Ai, const unsigned short* __restrict__ AjB,
    const float* __restrict__ wd, const float* __restrict__ eb2v,
    const unsigned short* __restrict__ ew2P, const unsigned short* __restrict__ cw1P,
    const float* __restrict__ cb1v, const float* __restrict__ cw2v, const float* __restrict__ cb2p,
    float* __restrict__ magg, float* __restrict__ xdelta) {
    __shared__ float srel[64][3];
    __shared__ float sd2[64];
    __shared__ float cwpart[8][64];
    __shared__ char s_tile[64 * SROWB];  // 33.8KB
    __shared__ char m_tile[64 * SROWB];  // 33.8KB

    int tid = threadIdx.x, wv = tid >> 6, lane = tid & 63;
    int g4 = lane >> 4, l15 = lane & 15;
    int colbase = wv * 32;
    int bi = blockIdx.x;
    int b = bi >> 8, i = bi & 255;
    int ni = b * NN + i;
    int bbase = b * NN;
    int bthr = ((wv << 7) + lane) << 3;

    int k0p = (tid & 31) << 3;
    float aiv[8], wdv[8];
    {
        float4v a0 = *(const float4v*)(Ai + (size_t)ni * HH + k0p);
        float4v a1 = *(const float4v*)(Ai + (size_t)ni * HH + k0p + 4);
        float4v w0 = *(const float4v*)(wd + k0p);
        float4v w1 = *(const float4v*)(wd + k0p + 4);
        #pragma unroll
        for (int e = 0; e < 4; ++e) { aiv[e] = a0[e]; aiv[4 + e] = a1[e]; wdv[e] = w0[e]; wdv[4 + e] = w1[e]; }
    }
    float eb2r[2], cb1r[2], cw2r[2];
    #pragma unroll
    for (int ct = 0; ct < 2; ++ct) {
        int col = colbase + ct * 16 + l15;
        eb2r[ct] = eb2v[col]; cb1r[ct] = cb1v[col]; cw2r[ct] = cw2v[col];
    }
    float xi0 = x[ni * 3 + 0], xi1 = x[ni * 3 + 1], xi2 = x[ni * 3 + 2];
    float cb2 = cb2p[0];

    // ---- resident B fragments (compiler may sink these; harmless either way)
    bf16x8 Bew[8][2], Bcw[8][2];
    #pragma unroll
    for (int ks = 0; ks < 8; ++ks) {
        #pragma unroll
        for (int ct = 0; ct < 2; ++ct) {
            Bew[ks][ct] = *(const bf16x8*)(ew2P + (ks << 13) + (ct << 9) + bthr);
            Bcw[ks][ct] = *(const bf16x8*)(cw1P + (ks << 13) + (ct << 9) + bthr);
        }
    }

    // per-thread LDS byte bases (all offsets from these are compile-time)
    char* p1w = s_tile + ((tid >> 5) * SROWB + k0p * 2);
    const char* aA = s_tile + (l15 * SROWB + g4 * 16);
    const char* aM = m_tile + (l15 * SROWB + g4 * 16);
    char* mwA = m_tile + ((g4 * 4) * SROWB + (colbase + l15) * 2);
    float mgv[2] = {0.f, 0.f};
    float xd0 = 0.f, xd1 = 0.f, xd2 = 0.f;

    #pragma unroll 1
    for (int jc = 0; jc < 4; ++jc) {
        int j0 = jc * 64;
        __syncthreads();
        if (tid < 64) {
            int j = bbase + j0 + tid;
            float rx = xi0 - x[j * 3 + 0];
            float ry = xi1 - x[j * 3 + 1];
            float rz = xi2 - x[j * 3 + 2];
            srel[tid][0] = rx; srel[tid][1] = ry; srel[tid][2] = rz;
            sd2[tid] = rx * rx + ry * ry + rz * rz;
        }
        __syncthreads();

        // ---- phase 1: s tile = silu(Ai + Aj + d2*wd), 64x256 bf16
        #pragma unroll
        for (int it = 0; it < 4; ++it) {
            int row = it * 16 + (tid >> 5);
            float d2v = sd2[row];
            u32x4 ajw = *(const u32x4*)(AjB + ((size_t)(bbase + j0 + row) * HH + k0p));
            unsigned int uw0, uw1, uw2, uw3;
            uw0 = cvtpk(fsilu(aiv[0] + bflo(ajw[0]) + d2v * wdv[0]), fsilu(aiv[1] + bfhi(ajw[0]) + d2v * wdv[1]));
            uw1 = cvtpk(fsilu(aiv[2] + bflo(ajw[1]) + d2v * wdv[2]), fsilu(aiv[3] + bfhi(ajw[1]) + d2v * wdv[3]));
            uw2 = cvtpk(fsilu(aiv[4] + bflo(ajw[2]) + d2v * wdv[4]), fsilu(aiv[5] + bfhi(ajw[2]) + d2v * wdv[5]));
            uw3 = cvtpk(fsilu(aiv[6] + bflo(ajw[3]) + d2v * wdv[6]), fsilu(aiv[7] + bfhi(ajw[3]) + d2v * wdv[7]));
            u32x4 sv = {uw0, uw1, uw2, uw3};
            *reinterpret_cast<u32x4*>(p1w + it * 16 * SROWB) = sv;
        }
        __syncthreads();

        // ---- phase 2: m = silu(s @ ew2 + eb2), two 32-row half-passes
        #pragma unroll 1
        for (int rh = 0; rh < 2; ++rh) {
            f32x4 acc[2][2];
            acc[0][0] = (f32x4){0.f,0.f,0.f,0.f}; acc[0][1] = (f32x4){0.f,0.f,0.f,0.f};
            acc[1][0] = (f32x4){0.f,0.f,0.f,0.f}; acc[1][1] = (f32x4){0.f,0.f,0.f,0.f};
            const char* aBase = aA + rh * 32 * SROWB;
            #pragma unroll
            for (int ks = 0; ks < 8; ++ks) {
                bf16x8 a0 = *reinterpret_cast<const bf16x8*>(aBase + ks * 64);
                bf16x8 a1 = *reinterpret_cast<const bf16x8*>(aBase + 16 * SROWB + ks * 64);
                acc[0][0] = __builtin_amdgcn_mfma_f32_16x16x32_bf16(a0, Bew[ks][0], acc[0][0], 0, 0, 0);
                acc[0][1] = __builtin_amdgcn_mfma_f32_16x16x32_bf16(a0, Bew[ks][1], acc[0][1], 0, 0, 0);
                acc[1][0] = __builtin_amdgcn_mfma_f32_16x16x32_bf16(a1, Bew[ks][0], acc[1][0], 0, 0, 0);
                acc[1][1] = __builtin_amdgcn_mfma_f32_16x16x32_bf16(a1, Bew[ks][1], acc[1][1], 0, 0, 0);
            }
            char* mw = mwA + rh * 32 * SROWB;
            #pragma unroll
            for (int rt = 0; rt < 2; ++rt) {
                #pragma unroll
                for (int r = 0; r < 4; ++r) {
                    float v0 = fsilu(acc[rt][0][r] + eb2r[0]);
                    float v1 = fsilu(acc[rt][1][r] + eb2r[1]);
                    mgv[0] += v0; mgv[1] += v1;
                    unsigned int w = cvtpk(v0, v1);
                    char* p = mw + (rt * 16 + r) * SROWB;
                    *reinterpret_cast<unsigned short*>(p) = (unsigned short)w;
                    *reinterpret_cast<unsigned short*>(p + 32) = (unsigned short)(w >> 16);
                }
            }
        }
        __syncthreads();

        // ---- phase 3: c = silu(m @ cw1 + cb1); cw-row-dot with cw2 (two half-passes)
        #pragma unroll 1
        for (int rh = 0; rh < 2; ++rh) {
            f32x4 acc[2][2];
            acc[0][0] = (f32x4){0.f,0.f,0.f,0.f}; acc[0][1] = (f32x4){0.f,0.f,0.f,0.f};
            acc[1][0] = (f32x4){0.f,0.f,0.f,0.f}; acc[1][1] = (f32x4){0.f,0.f,0.f,0.f};
            const char* aBase = aM + rh * 32 * SROWB;
            #pragma unroll
            for (int ks = 0; ks < 8; ++ks) {
                bf16x8 a0 = *reinterpret_cast<const bf16x8*>(aBase + ks * 64);
                bf16x8 a1 = *reinterpret_cast<const bf16x8*>(aBase + 16 * SROWB + ks * 64);
                acc[0][0] = __builtin_amdgcn_mfma_f32_16x16x32_bf16(a0, Bcw[ks][0], acc[0][0], 0, 0, 0);
                acc[0][1] = __builtin_amdgcn_mfma_f32_16x16x32_bf16(a0, Bcw[ks][1], acc[0][1], 0, 0, 0);
                acc[1][0] = __builtin_amdgcn_mfma_f32_16x16x32_bf16(a1, Bcw[ks][0], acc[1][0], 0, 0, 0);
                acc[1][1] = __builtin_amdgcn_mfma_f32_16x16x32_bf16(a1, Bcw[ks][1], acc[1][1], 0, 0, 0);
            }
            float rs[8];
            #pragma unroll
            for (int q = 0; q < 8; ++q) rs[q] = 0.f;
            #pragma unroll
            for (int ct = 0; ct < 2; ++ct) {
                #pragma unroll
                for (int rt = 0; rt < 2; ++rt)
                    #pragma unroll
                    for (int r = 0; r < 4; ++r)
                        rs[rt * 4 + r] += fsilu(acc[rt][ct][r] + cb1r[ct]) * cw2r[ct];
            }
            #pragma unroll
            for (int m = 1; m <= 8; m <<= 1)
                #pragma unroll
                for (int q = 0; q < 8; ++q) rs[q] += __shfl_xor(rs[q], m);
            if (l15 == 0) {
                #pragma unroll
                for (int rt = 0; rt < 2; ++rt)
                    #pragma unroll
                    for (int r = 0; r < 4; ++r)
                        cwpart[wv][rh * 32 + rt * 16 + g4 * 4 + r] = rs[rt * 4 + r];
            }
        }
        __syncthreads();
        if (tid < 64) {
            float cwv = cb2;
            #pragma unroll
            for (int w = 0; w < 8; ++w) cwv += cwpart[w][tid];
            float p0 = srel[tid][0] * cwv;
            float p1 = srel[tid][1] * cwv;
            float p2 = srel[tid][2] * cwv;
            #pragma unroll
            for (int m = 1; m < 64; m <<= 1) {
                p0 += __shfl_xor(p0, m); p1 += __shfl_xor(p1, m); p2 += __shfl_xor(p2, m);
            }
            xd0 += p0; xd1 += p1; xd2 += p2;
        }
    }

    #pragma unroll
    for (int ct = 0; ct < 2; ++ct) {
        mgv[ct] += __shfl_xor(mgv[ct], 16);
        mgv[ct] += __shfl_xor(mgv[ct], 32);
    }
    if (lane < 16) {
        #pragma unroll
        for (int ct = 0; ct < 2; ++ct)
            magg[(size_t)ni * HH + colbase + ct * 16 + lane] = mgv[ct];
    }
    if (tid == 0) {
        xdelta[ni * 3 + 0] = xd0 * (1.0f / NN);
        xdelta[ni * 3 + 1] = xd1 * (1.0f / NN);
        xdelta[ni * 3 + 2] = xd2 * (1.0f / NN);
    }
}

// ---------------------------------------------------------------- fused node update + next-layer LN/Ai/Aj
__global__ __launch_bounds__(256) void k_node_ln(
    const float* __restrict__ hn, const float* __restrict__ magg,
    const unsigned int* __restrict__ nw1w, const float* __restrict__ nb1l,
    const unsigned int* __restrict__ nw2w, const float* __restrict__ nb2l,
    float* __restrict__ h, float* __restrict__ x, const float* __restrict__ xdelta,
    const float* __restrict__ g, const float* __restrict__ bta,
    const unsigned int* __restrict__ ew1w, const float* __restrict__ eb1l,
    float* __restrict__ hnout, float* __restrict__ Ai, unsigned short* __restrict__ AjB,
    int has_ln) {
    __shared__ float s2T[2 * HH][2];
    __shared__ float suT[HH][2];
    __shared__ float sh[2][HH];
    __shared__ float shnT[HH][2];
    int tid = threadIdx.x;
    int base = blockIdx.x * 2;
    #pragma unroll
    for (int r = 0; r < 2; ++r) {
        s2T[tid][r] = hn[(base + r) * HH + tid];
        s2T[HH + tid][r] = magg[(base + r) * HH + tid];
    }
    if (tid < 6) {
        int r = tid / 3, c = tid % 3;
        x[(base + r) * 3 + c] += xdelta[(base + r) * 3 + c];
    }
    __syncthreads();
    float a0 = nb1l[tid], a1 = a0;
    for (int c2 = 0; c2 < 256; ++c2) {
        unsigned int wp = nw1w[c2 * 256 + tid];
        float4 s = *(const float4*)&s2T[c2 * 2][0];
        a0 += s.x * bflo(wp) + s.z * bfhi(wp);
        a1 += s.y * bflo(wp) + s.w * bfhi(wp);
    }
    suT[tid][0] = fsilu(a0); suT[tid][1] = fsilu(a1);
    __syncthreads();
    float d0 = nb2l[tid], d1 = d0;
    for (int c2 = 0; c2 < 128; ++c2) {
        unsigned int wp = nw2w[c2 * 256 + tid];
        float4 s = *(const float4*)&suT[c2 * 2][0];
        d0 += s.x * bflo(wp) + s.z * bfhi(wp);
        d1 += s.y * bflo(wp) + s.w * bfhi(wp);
    }
    float h0 = h[(base + 0) * HH + tid] + d0;
    float h1 = h[(base + 1) * HH + tid] + d1;
    h[(base + 0) * HH + tid] = h0;
    h[(base + 1) * HH + tid] = h1;
    if (!has_ln) return;
    sh[0][tid] = h0; sh[1][tid] = h1;
    __syncthreads();

    int wv = tid >> 6, lane = tid & 63;
    if (wv < 2) {
        int row = base + wv;
        float v[4];
        #pragma unroll
        for (int q = 0; q < 4; ++q) v[q] = sh[wv][lane + 64 * q];
        float s = v[0] + v[1] + v[2] + v[3];
        #pragma unroll
        for (int m = 1; m < 64; m <<= 1) s += __shfl_xor(s, m);
        float mu = s * (1.0f / HH);
        float var = 0.f;
        #pragma unroll
        for (int q = 0; q < 4; ++q) { v[q] -= mu; var += v[q] * v[q]; }
        #pragma unroll
        for (int m = 1; m < 64; m <<= 1) var += __shfl_xor(var, m);
        float rstd = rsqrtf(var * (1.0f / HH) + 1e-5f);
        #pragma unroll
        for (int q = 0; q < 4; ++q) {
            int k = lane + 64 * q;
            float hv = v[q] * rstd * g[k] + bta[k];
            shnT[k][wv] = hv;
            hnout[row * HH + k] = hv;
        }
    }
    __syncthreads();

    float ai0 = eb1l[tid], ai1 = ai0;
    float aj0 = 0.f, aj1 = 0.f;
    for (int c2 = 0; c2 < 128; ++c2) {
        unsigned int wip = ew1w[c2 * 256 + tid];
        unsigned int wjp = ew1w[(128 + c2) * 256 + tid];
        float4 s = *(const float4*)&shnT[c2 * 2][0];
        ai0 += s.x * bflo(wip) + s.z * bfhi(wip);
        ai1 += s.y * bflo(wip) + s.w * bfhi(wip);
        aj0 += s.x * bflo(wjp) + s.z * bfhi(wjp);
        aj1 += s.y * bflo(wjp) + s.w * bfhi(wjp);
    }
    Ai[(base + 0) * HH + tid] = ai0; AjB[(base + 0) * HH + tid] = f2bf(aj0);
    Ai[(base + 1) * HH + tid] = ai1; AjB[(base + 1) * HH + tid] = f2bf(aj1);
}

// ---------------------------------------------------------------- decoder (2 rows/block)
__global__ __launch_bounds__(256) void k_decoder(
    const float* __restrict__ h,
    const float* __restrict__ dw1, const float* __restrict__ db1,
    const float* __restrict__ dw2, const float* __restrict__ db2,
    const float* __restrict__ dw3, const float* __restrict__ db3,
    float* __restrict__ out) {
    __shared__ float shT[HH][2];
    __shared__ float so1T[HH][2];
    __shared__ float so2T[HH][2];
    int tid = threadIdx.x;
    int base = blockIdx.x * 2;
    #pragma unroll
    for (int r = 0; r < 2; ++r) shT[tid][r] = h[(base + r) * HH + tid];
    __syncthreads();
    float a0 = db1[tid], a1 = a0;
    for (int c = 0; c < HH; ++c) {
        float w = dw1[c * HH + tid];
        float2 s = *(const float2*)&shT[c][0];
        a0 += s.x * w; a1 += s.y * w;
    }
    so1T[tid][0] = fmaxf(a0, 0.f); so1T[tid][1] = fmaxf(a1, 0.f);
    __syncthreads();
    a0 = db2[tid]; a1 = a0;
    for (int c = 0; c < HH; ++c) {
        float w = dw2[c * HH + tid];
        float2 s = *(const float2*)&so1T[c][0];
        a0 += s.x * w; a1 += s.y * w;
    }
    so2T[tid][0] = fmaxf(a0, 0.f) + shT[tid][0];
    so2T[tid][1] = fmaxf(a1, 0.f) + shT[tid][1];
    __syncthreads();
    if (tid < 6) {
        int r = tid / 3, c = tid % 3;
        float acc = db3[c];
        for (int k = 0; k < HH; ++k) acc += so2T[k][r] * dw3[k * 3 + c];
        out[(base + r) * 3 + c] = acc;
    }
}

// ---------------------------------------------------------------- launch
extern "C" void kernel_launch(void* const* d_in, const int* in_sizes, int n_in,
                              void* d_out, int out_size, void* d_ws, size_t ws_size,
                              hipStream_t stream) {
    const float* coords = (const float*)d_in[0];
    const float* feats  = (const float*)d_in[1];
    const float* t      = (const float*)d_in[2];
    const float* pe_w1  = (const float*)d_in[3];  const float* pe_b1 = (const float*)d_in[4];
    const float* pe_w2  = (const float*)d_in[5];  const float* pe_b2 = (const float*)d_in[6];
    const float* pe_w3  = (const float*)d_in[7];  const float* pe_b3 = (const float*)d_in[8];
    const float* te_w1  = (const float*)d_in[9];  const float* te_b1 = (const float*)d_in[10];
    const float* te_w2  = (const float*)d_in[11]; const float* te_b2 = (const float*)d_in[12];
    const float* ln_g   = (const float*)d_in[13]; const float* ln_b  = (const float*)d_in[14];
    const float* ew1    = (const float*)d_in[15]; const float* eb1   = (const float*)d_in[16];
    const float* ew2    = (const float*)d_in[17]; const float* eb2   = (const float*)d_in[18];
    const float* cw1    = (const float*)d_in[19]; const float* cb1   = (const float*)d_in[20];
    const float* cw2    = (const float*)d_in[21]; const float* cb2   = (const float*)d_in[22];
    const float* nw1    = (const float*)d_in[23]; const float* nb1   = (const float*)d_in[24];
    const float* nw2    = (const float*)d_in[25]; const float* nb2   = (const float*)d_in[26];
    const float* dec_w1 = (const float*)d_in[27]; const float* dec_b1 = (const float*)d_in[28];
    const float* dec_w2 = (const float*)d_in[29]; const float* dec_b2 = (const float*)d_in[30];
    const float* dec_w3 = (const float*)d_in[31]; const float* dec_b3 = (const float*)d_in[32];

    float* ws = (float*)d_ws;
    float* h      = ws;
    float* hn     = ws + RN;
    float* Ai     = ws + 2 * RN;
    float* magg   = ws + 3 * RN;
    float* x      = ws + 4 * RN;            // 1536 (reserve 2048)
    float* xdelta = ws + 4 * RN + 2048;     // 1536 (reserve 2048)
    unsigned short* AjB  = (unsigned short*)(ws + 4 * RN + 4096);
    unsigned short* ew2P = AjB + RN;                       // LL*65536
    unsigned short* cw1P = ew2P + LL * HH * HH;            // LL*65536
    unsigned short* nw1B = cw1P + LL * HH * HH;            // LL*131072
    unsigned short* ew1B = nw1B + LL * 2 * HH * HH;        // LL*131072
    unsigned short* nw2B = ew1B + LL * 2 * HH * HH;        // LL*65536

    k_convert<<<(LL * 8192 + 511) / 512, 512, 0, stream>>>(ew2, cw1, ew2P, cw1P);
    k_convert2<<<(LL * 131072 + 255) / 256, 256, 0, stream>>>(nw1, nw2, ew1, nw1B, nw2B, ew1B);
    k_encoder<<<NB * NN / 2, 256, 0, stream>>>(coords, feats, t,
        pe_w1, pe_b1, pe_w2, pe_b2, pe_w3, pe_b3, te_w1, te_b1, te_w2, te_b2, h, x);
    k_ln_aiaj<<<NB * NN / 2, 256, 0, stream>>>(h, ln_g, ln_b,
        (const unsigned int*)ew1B, eb1, hn, Ai, AjB);

    for (int l = 0; l < LL; ++l) {
        k_edge<<<NB * NN, 512, 0, stream>>>(x, Ai, AjB,
            ew1 + ((size_t)l * 513 + 512) * HH, eb2 + l * HH,
            ew2P + (size_t)l * HH * HH, cw1P + (size_t)l * HH * HH,
            cb1 + l * HH, cw2 + l * HH, cb2 + l, magg, xdelta);
        int ln = (l + 1 < LL) ? (l + 1) : LL - 1;  // params unused when has_ln=0
        k_node_ln<<<NB * NN / 2, 256, 0, stream>>>(hn, magg,
            (const unsigned int*)(nw1B + (size_t)l * 2 * HH * HH), nb1 + l * HH,
            (const unsigned int*)(nw2B + (size_t)l * HH * HH), nb2 + l * HH, h, x, xdelta,
            ln_g + ln * HH, ln_b + ln * HH,
            (const unsigned int*)(ew1B + (size_t)ln * 2 * HH * HH), eb1 + ln * HH,
            hn, Ai, AjB, (l + 1 < LL) ? 1 : 0);
    }

    k_decoder<<<NB * NN / 2, 256, 0, stream>>>(h, dec_w1, dec_b1, dec_w2, dec_b2,
                                               dec_w3, dec_b3, (float*)d_out);
}

// Round 15
// 627.480 us; speedup vs baseline: 1.1483x; 1.0262x over previous
//
#include <hip/hip_runtime.h>
#include <math.h>

static constexpr int NB = 2, NN = 256, HH = 256, DD = 64, LL = 6;
static constexpr int RN = NB * NN * HH;  // 131072
static constexpr int SROWB = 528;        // padded LDS row stride in bytes (+16B: 2-way banks, imm-foldable)

typedef __attribute__((ext_vector_type(8))) short bf16x8;
typedef __attribute__((ext_vector_type(4))) float f32x4;
typedef __attribute__((ext_vector_type(4))) float float4v;
typedef __attribute__((ext_vector_type(4))) unsigned int u32x4;

__device__ __forceinline__ float fsilu(float v) {
    return v * __builtin_amdgcn_rcpf(1.0f + __expf(-v));
}
__device__ __forceinline__ unsigned short f2bf(float f) {
    union { float f; unsigned int u; } x; x.f = f;
    unsigned int r = x.u + 0x7fffu + ((x.u >> 16) & 1u);
    return (unsigned short)(r >> 16);
}
__device__ __forceinline__ float bitsf(unsigned int u) {
    union { float f; unsigned int u; } x; x.u = u; return x.f;
}
__device__ __forceinline__ float bflo(unsigned int w) { return bitsf(w << 16); }
__device__ __forceinline__ float bfhi(unsigned int w) { return bitsf(w & 0xffff0000u); }
__device__ __forceinline__ unsigned int cvtpk(float lo, float hi) {
    unsigned int w;
    asm("v_cvt_pk_bf16_f32 %0, %1, %2" : "=v"(w) : "v"(lo), "v"(hi));
    return w;
}

// ---------------------------------------------------------------- convert (edge fragment-packed)
__global__ void k_convert(const float* __restrict__ ew2, const float* __restrict__ cw1,
                          unsigned short* __restrict__ ew2P, unsigned short* __restrict__ cw1P) {
    int g = blockIdx.x * blockDim.x + threadIdx.x;
    if (g >= LL * 8192) return;
    int l = g >> 13;
    int r = g & 8191;
    int lane = r & 63;
    int fidx = r >> 6;
    int ks = fidx >> 4;
    int wv = (fidx >> 1) & 7;
    int ct = fidx & 1;
    int col = wv * 32 + ct * 16 + (lane & 15);
    int k0 = ks * 32 + (lane >> 4) * 8;
    #pragma unroll
    for (int e = 0; e < 8; ++e) {
        ew2P[(size_t)g * 8 + e] = f2bf(ew2[((size_t)l * HH + k0 + e) * HH + col]);
        cw1P[(size_t)g * 8 + e] = f2bf(cw1[((size_t)l * HH + k0 + e) * HH + col]);
    }
}

// ---------------------------------------------------------------- convert2 (bf16 pair-packed GEMV weights)
__global__ void k_convert2(const float* __restrict__ nw1, const float* __restrict__ nw2,
                           const float* __restrict__ ew1,
                           unsigned short* __restrict__ nw1B, unsigned short* __restrict__ nw2B,
                           unsigned short* __restrict__ ew1B) {
    int idx = blockIdx.x * blockDim.x + threadIdx.x;
    if (idx >= LL * 131072) return;
    int l = idx >> 17;
    int r = idx & 131071;
    int c = r >> 8, col = r & 255;
    int dst = (l << 17) + ((c >> 1) << 9) + (col << 1) + (c & 1);
    nw1B[dst] = f2bf(nw1[(size_t)l * 131072 + c * 256 + col]);
    ew1B[dst] = f2bf(ew1[(size_t)l * 131328 + c * 256 + col]);  // 513*256 stride
    if (r < 65536) {
        int d2 = (l << 16) + ((c >> 1) << 9) + (col << 1) + (c & 1);
        nw2B[d2] = f2bf(nw2[(size_t)l * 65536 + c * 256 + col]);
    }
}

// ---------------------------------------------------------------- encoder (2 rows/block, broadcast staging)
__global__ __launch_bounds__(256) void k_encoder(
    const float* __restrict__ coords, const float* __restrict__ feats, const float* __restrict__ t,
    const float* __restrict__ pw1, const float* __restrict__ pb1,
    const float* __restrict__ pw2, const float* __restrict__ pb2,
    const float* __restrict__ pw3, const float* __restrict__ pb3,
    const float* __restrict__ tw1, const float* __restrict__ tb1,
    const float* __restrict__ tw2, const float* __restrict__ tb2,
    float* __restrict__ h, float* __restrict__ x) {
    __shared__ float spinT[68][2];
    __shared__ float shaT[HH][2];
    __shared__ float shbT[HH][2];
    __shared__ float ste1[HH];
    int tid = threadIdx.x;
    int base = blockIdx.x * 2;
    int b = base / NN;

    #pragma unroll
    for (int r = 0; r < 2; ++r) {
        int row = base + r;
        if (tid < 3) spinT[tid][r] = coords[row * 3 + tid];
        if (tid < DD) spinT[3 + tid][r] = feats[row * DD + tid];
    }
    float tv = t[b];
    ste1[tid] = fmaxf(tv * tw1[tid] + tb1[tid], 0.0f);
    if (tid < 6) {
        int r = tid / 3, c = tid % 3;
        x[(base + r) * 3 + c] = coords[(base + r) * 3 + c];
    }
    __syncthreads();

    float a0 = pb1[tid], a1 = a0;
    for (int c = 0; c < 67; ++c) {
        float w = pw1[c * HH + tid];
        float2 s = *(const float2*)&spinT[c][0];
        a0 += s.x * w; a1 += s.y * w;
    }
    shaT[tid][0] = fmaxf(a0, 0.f); shaT[tid][1] = fmaxf(a1, 0.f);
    __syncthreads();
    a0 = pb2[tid]; a1 = a0;
    for (int c = 0; c < HH; ++c) {
        float w = pw2[c * HH + tid];
        float2 s = *(const float2*)&shaT[c][0];
        a0 += s.x * w; a1 += s.y * w;
    }
    shbT[tid][0] = fmaxf(a0, 0.f); shbT[tid][1] = fmaxf(a1, 0.f);
    __syncthreads();
    a0 = pb3[tid]; a1 = a0;
    float te = tb2[tid];
    for (int c = 0; c < HH; ++c) {
        float w = pw3[c * HH + tid];
        float2 s = *(const float2*)&shbT[c][0];
        a0 += s.x * w; a1 += s.y * w;
        te += ste1[c] * tw2[c * HH + tid];
    }
    h[(base + 0) * HH + tid] = fmaxf(a0, 0.f) + te;
    h[(base + 1) * HH + tid] = fmaxf(a1, 0.f) + te;
}

// ---------------------------------------------------------------- LayerNorm + Ai/Aj (layer 0; bf16 ew1)
__global__ __launch_bounds__(256) void k_ln_aiaj(
    const float* __restrict__ h, const float* __restrict__ g, const float* __restrict__ bta,
    const unsigned int* __restrict__ ew1w, const float* __restrict__ eb1l,
    float* __restrict__ hn, float* __restrict__ Ai, unsigned short* __restrict__ AjB) {
    __shared__ float shnT[HH][2];
    int tid = threadIdx.x, wv = tid >> 6, lane = tid & 63;
    int base = blockIdx.x * 2;

    if (wv < 2) {
        int row = base + wv;
        float v[4];
        #pragma unroll
        for (int q = 0; q < 4; ++q) v[q] = h[row * HH + lane + 64 * q];
        float s = v[0] + v[1] + v[2] + v[3];
        #pragma unroll
        for (int m = 1; m < 64; m <<= 1) s += __shfl_xor(s, m);
        float mu = s * (1.0f / HH);
        float var = 0.f;
        #pragma unroll
        for (int q = 0; q < 4; ++q) { v[q] -= mu; var += v[q] * v[q]; }
        #pragma unroll
        for (int m = 1; m < 64; m <<= 1) var += __shfl_xor(var, m);
        float rstd = rsqrtf(var * (1.0f / HH) + 1e-5f);
        #pragma unroll
        for (int q = 0; q < 4; ++q) {
            int k = lane + 64 * q;
            float hv = v[q] * rstd * g[k] + bta[k];
            shnT[k][wv] = hv;
            hn[row * HH + k] = hv;
        }
    }
    __syncthreads();

    float ai0 = eb1l[tid], ai1 = ai0;
    float aj0 = 0.f, aj1 = 0.f;
    for (int c2 = 0; c2 < 128; ++c2) {
        unsigned int wip = ew1w[c2 * 256 + tid];
        unsigned int wjp = ew1w[(128 + c2) * 256 + tid];
        float4 s = *(const float4*)&shnT[c2 * 2][0];
        ai0 += s.x * bflo(wip) + s.z * bfhi(wip);
        ai1 += s.y * bflo(wip) + s.w * bfhi(wip);
        aj0 += s.x * bflo(wjp) + s.z * bfhi(wjp);
        aj1 += s.y * bflo(wjp) + s.w * bfhi(wjp);
    }
    Ai[(base + 0) * HH + tid] = ai0; AjB[(base + 0) * HH + tid] = f2bf(aj0);
    Ai[(base + 1) * HH + tid] = ai1; AjB[(base + 1) * HH + tid] = f2bf(aj1);
}

// ---------------------------------------------------------------- fused edge pipeline (MFMA)
// Round-13/14 structure with 128-row j-tiles (jc=2): halves the per-block
// barrier count (20->10) and single-wave phases (8->4) — the phase-
// serialization cost that dominates at our pinned 1-block/CU, 8-wave
// operating point (rounds 9-14: no knob moves residency past 1 block).
// LDS ~138KB (fine at 1 block/CU). __launch_bounds__(512, 1): arg2 is min
// BLOCKS/CU on hipcc; >=2 caps regalloc and spills when working set >128
// VGPR (rounds 2-5, 8). DO NOT raise.
__global__ __launch_bounds__(512, 1) void k_edge(
    const float* __restrict__ x, const float* __restrict__ Ai, const unsigned short* __restrict__ AjB,
    const float* __restrict__ wd, const float* __restrict__ eb2v,
    const unsigned short* __restrict__ ew2P, const unsigned short* __restrict__ cw1P,
    const float* __restrict__ cb1v, const float* __restrict__ cw2v, const float* __restrict__ cb2p,
    float* __restrict__ magg, float* __restrict__ xdelta) {
    __shared__ float srel[128][3];
    __shared__ float sd2[128];
    __shared__ float cwpart[8][128];
    __shared__ char s_tile[128 * SROWB];  // 67.6KB
    __shared__ char m_tile[128 * SROWB];  // 67.6KB

    int tid = threadIdx.x, wv = tid >> 6, lane = tid & 63;
    int g4 = lane >> 4, l15 = lane & 15;
    int colbase = wv * 32;
    int bi = blockIdx.x;
    int b = bi >> 8, i = bi & 255;
    int ni = b * NN + i;
    int bbase = b * NN;
    int bthr = ((wv << 7) + lane) << 3;

    int k0p = (tid & 31) << 3;
    float aiv[8], wdv[8];
    {
        float4v a0 = *(const float4v*)(Ai + (size_t)ni * HH + k0p);
        float4v a1 = *(const float4v*)(Ai + (size_t)ni * HH + k0p + 4);
        float4v w0 = *(const float4v*)(wd + k0p);
        float4v w1 = *(const float4v*)(wd + k0p + 4);
        #pragma unroll
        for (int e = 0; e < 4; ++e) { aiv[e] = a0[e]; aiv[4 + e] = a1[e]; wdv[e] = w0[e]; wdv[4 + e] = w1[e]; }
    }
    float eb2r[2], cb1r[2], cw2r[2];
    #pragma unroll
    for (int ct = 0; ct < 2; ++ct) {
        int col = colbase + ct * 16 + l15;
        eb2r[ct] = eb2v[col]; cb1r[ct] = cb1v[col]; cw2r[ct] = cw2v[col];
    }
    float xi0 = x[ni * 3 + 0], xi1 = x[ni * 3 + 1], xi2 = x[ni * 3 + 2];
    float cb2 = cb2p[0];

    // ---- resident B fragments (compiler may sink these; harmless either way)
    bf16x8 Bew[8][2], Bcw[8][2];
    #pragma unroll
    for (int ks = 0; ks < 8; ++ks) {
        #pragma unroll
        for (int ct = 0; ct < 2; ++ct) {
            Bew[ks][ct] = *(const bf16x8*)(ew2P + (ks << 13) + (ct << 9) + bthr);
            Bcw[ks][ct] = *(const bf16x8*)(cw1P + (ks << 13) + (ct << 9) + bthr);
        }
    }

    // per-thread LDS byte bases (all offsets from these are compile-time)
    char* p1w = s_tile + ((tid >> 5) * SROWB + k0p * 2);
    const char* aA = s_tile + (l15 * SROWB + g4 * 16);
    const char* aM = m_tile + (l15 * SROWB + g4 * 16);
    char* mwA = m_tile + ((g4 * 4) * SROWB + (colbase + l15) * 2);
    float mgv[2] = {0.f, 0.f};
    float xd0 = 0.f, xd1 = 0.f, xd2 = 0.f;

    #pragma unroll 1
    for (int jc = 0; jc < 2; ++jc) {
        int j0 = jc * 128;
        __syncthreads();
        if (tid < 128) {
            int j = bbase + j0 + tid;
            float rx = xi0 - x[j * 3 + 0];
            float ry = xi1 - x[j * 3 + 1];
            float rz = xi2 - x[j * 3 + 2];
            srel[tid][0] = rx; srel[tid][1] = ry; srel[tid][2] = rz;
            sd2[tid] = rx * rx + ry * ry + rz * rz;
        }
        __syncthreads();

        // ---- phase 1: s tile = silu(Ai + Aj + d2*wd), 128x256 bf16
        #pragma unroll
        for (int it = 0; it < 8; ++it) {
            int row = it * 16 + (tid >> 5);
            float d2v = sd2[row];
            u32x4 ajw = *(const u32x4*)(AjB + ((size_t)(bbase + j0 + row) * HH + k0p));
            unsigned int uw0, uw1, uw2, uw3;
            uw0 = cvtpk(fsilu(aiv[0] + bflo(ajw[0]) + d2v * wdv[0]), fsilu(aiv[1] + bfhi(ajw[0]) + d2v * wdv[1]));
            uw1 = cvtpk(fsilu(aiv[2] + bflo(ajw[1]) + d2v * wdv[2]), fsilu(aiv[3] + bfhi(ajw[1]) + d2v * wdv[3]));
            uw2 = cvtpk(fsilu(aiv[4] + bflo(ajw[2]) + d2v * wdv[4]), fsilu(aiv[5] + bfhi(ajw[2]) + d2v * wdv[5]));
            uw3 = cvtpk(fsilu(aiv[6] + bflo(ajw[3]) + d2v * wdv[6]), fsilu(aiv[7] + bfhi(ajw[3]) + d2v * wdv[7]));
            u32x4 sv = {uw0, uw1, uw2, uw3};
            *reinterpret_cast<u32x4*>(p1w + it * 16 * SROWB) = sv;
        }
        __syncthreads();

        // ---- phase 2: m = silu(s @ ew2 + eb2), four 32-row half-passes
        #pragma unroll 1
        for (int rh = 0; rh < 4; ++rh) {
            f32x4 acc[2][2];
            acc[0][0] = (f32x4){0.f,0.f,0.f,0.f}; acc[0][1] = (f32x4){0.f,0.f,0.f,0.f};
            acc[1][0] = (f32x4){0.f,0.f,0.f,0.f}; acc[1][1] = (f32x4){0.f,0.f,0.f,0.f};
            const char* aBase = aA + rh * 32 * SROWB;
            #pragma unroll
            for (int ks = 0; ks < 8; ++ks) {
                bf16x8 a0 = *reinterpret_cast<const bf16x8*>(aBase + ks * 64);
                bf16x8 a1 = *reinterpret_cast<const bf16x8*>(aBase + 16 * SROWB + ks * 64);
                acc[0][0] = __builtin_amdgcn_mfma_f32_16x16x32_bf16(a0, Bew[ks][0], acc[0][0], 0, 0, 0);
                acc[0][1] = __builtin_amdgcn_mfma_f32_16x16x32_bf16(a0, Bew[ks][1], acc[0][1], 0, 0, 0);
                acc[1][0] = __builtin_amdgcn_mfma_f32_16x16x32_bf16(a1, Bew[ks][0], acc[1][0], 0, 0, 0);
                acc[1][1] = __builtin_amdgcn_mfma_f32_16x16x32_bf16(a1, Bew[ks][1], acc[1][1], 0, 0, 0);
            }
            char* mw = mwA + rh * 32 * SROWB;
            #pragma unroll
            for (int rt = 0; rt < 2; ++rt) {
                #pragma unroll
                for (int r = 0; r < 4; ++r) {
                    float v0 = fsilu(acc[rt][0][r] + eb2r[0]);
                    float v1 = fsilu(acc[rt][1][r] + eb2r[1]);
                    mgv[0] += v0; mgv[1] += v1;
                    unsigned int w = cvtpk(v0, v1);
                    char* p = mw + (rt * 16 + r) * SROWB;
                    *reinterpret_cast<unsigned short*>(p) = (unsigned short)w;
                    *reinterpret_cast<unsigned short*>(p + 32) = (unsigned short)(w >> 16);
                }
            }
        }
        __syncthreads();

        // ---- phase 3: c = silu(m @ cw1 + cb1); cw-row-dot with cw2 (four half-passes)
        #pragma unroll 1
        for (int rh = 0; rh < 4; ++rh) {
            f32x4 acc[2][2];
            acc[0][0] = (f32x4){0.f,0.f,0.f,0.f}; acc[0][1] = (f32x4){0.f,0.f,0.f,0.f};
            acc[1][0] = (f32x4){0.f,0.f,0.f,0.f}; acc[1][1] = (f32x4){0.f,0.f,0.f,0.f};
            const char* aBase = aM + rh * 32 * SROWB;
            #pragma unroll
            for (int ks = 0; ks < 8; ++ks) {
                bf16x8 a0 = *reinterpret_cast<const bf16x8*>(aBase + ks * 64);
                bf16x8 a1 = *reinterpret_cast<const bf16x8*>(aBase + 16 * SROWB + ks * 64);
                acc[0][0] = __builtin_amdgcn_mfma_f32_16x16x32_bf16(a0, Bcw[ks][0], acc[0][0], 0, 0, 0);
                acc[0][1] = __builtin_amdgcn_mfma_f32_16x16x32_bf16(a0, Bcw[ks][1], acc[0][1], 0, 0, 0);
                acc[1][0] = __builtin_amdgcn_mfma_f32_16x16x32_bf16(a1, Bcw[ks][0], acc[1][0], 0, 0, 0);
                acc[1][1] = __builtin_amdgcn_mfma_f32_16x16x32_bf16(a1, Bcw[ks][1], acc[1][1], 0, 0, 0);
            }
            float rs[8];
            #pragma unroll
            for (int q = 0; q < 8; ++q) rs[q] = 0.f;
            #pragma unroll
            for (int ct = 0; ct < 2; ++ct) {
                #pragma unroll
                for (int rt = 0; rt < 2; ++rt)
                    #pragma unroll
                    for (int r = 0; r < 4; ++r)
                        rs[rt * 4 + r] += fsilu(acc[rt][ct][r] + cb1r[ct]) * cw2r[ct];
            }
            #pragma unroll
            for (int m = 1; m <= 8; m <<= 1)
                #pragma unroll
                for (int q = 0; q < 8; ++q) rs[q] += __shfl_xor(rs[q], m);
            if (l15 == 0) {
                #pragma unroll
                for (int rt = 0; rt < 2; ++rt)
                    #pragma unroll
                    for (int r = 0; r < 4; ++r)
                        cwpart[wv][rh * 32 + rt * 16 + g4 * 4 + r] = rs[rt * 4 + r];
            }
        }
        __syncthreads();
        if (tid < 64) {
            #pragma unroll 1
            for (int q = 0; q < 2; ++q) {
                int lr = q * 64 + tid;
                float cwv = cb2;
                #pragma unroll
                for (int w = 0; w < 8; ++w) cwv += cwpart[w][lr];
                float p0 = srel[lr][0] * cwv;
                float p1 = srel[lr][1] * cwv;
                float p2 = srel[lr][2] * cwv;
                #pragma unroll
                for (int m = 1; m < 64; m <<= 1) {
                    p0 += __shfl_xor(p0, m); p1 += __shfl_xor(p1, m); p2 += __shfl_xor(p2, m);
                }
                xd0 += p0; xd1 += p1; xd2 += p2;
            }
        }
    }

    #pragma unroll
    for (int ct = 0; ct < 2; ++ct) {
        mgv[ct] += __shfl_xor(mgv[ct], 16);
        mgv[ct] += __shfl_xor(mgv[ct], 32);
    }
    if (lane < 16) {
        #pragma unroll
        for (int ct = 0; ct < 2; ++ct)
            magg[(size_t)ni * HH + colbase + ct * 16 + lane] = mgv[ct];
    }
    if (tid == 0) {
        xdelta[ni * 3 + 0] = xd0 * (1.0f / NN);
        xdelta[ni * 3 + 1] = xd1 * (1.0f / NN);
        xdelta[ni * 3 + 2] = xd2 * (1.0f / NN);
    }
}

// ---------------------------------------------------------------- fused node update + next-layer LN/Ai/Aj
__global__ __launch_bounds__(256) void k_node_ln(
    const float* __restrict__ hn, const float* __restrict__ magg,
    const unsigned int* __restrict__ nw1w, const float* __restrict__ nb1l,
    const unsigned int* __restrict__ nw2w, const float* __restrict__ nb2l,
    float* __restrict__ h, float* __restrict__ x, const float* __restrict__ xdelta,
    const float* __restrict__ g, const float* __restrict__ bta,
    const unsigned int* __restrict__ ew1w, const float* __restrict__ eb1l,
    float* __restrict__ hnout, float* __restrict__ Ai, unsigned short* __restrict__ AjB,
    int has_ln) {
    __shared__ float s2T[2 * HH][2];
    __shared__ float suT[HH][2];
    __shared__ float sh[2][HH];
    __shared__ float shnT[HH][2];
    int tid = threadIdx.x;
    int base = blockIdx.x * 2;
    #pragma unroll
    for (int r = 0; r < 2; ++r) {
        s2T[tid][r] = hn[(base + r) * HH + tid];
        s2T[HH + tid][r] = magg[(base + r) * HH + tid];
    }
    if (tid < 6) {
        int r = tid / 3, c = tid % 3;
        x[(base + r) * 3 + c] += xdelta[(base + r) * 3 + c];
    }
    __syncthreads();
    float a0 = nb1l[tid], a1 = a0;
    for (int c2 = 0; c2 < 256; ++c2) {
        unsigned int wp = nw1w[c2 * 256 + tid];
        float4 s = *(const float4*)&s2T[c2 * 2][0];
        a0 += s.x * bflo(wp) + s.z * bfhi(wp);
        a1 += s.y * bflo(wp) + s.w * bfhi(wp);
    }
    suT[tid][0] = fsilu(a0); suT[tid][1] = fsilu(a1);
    __syncthreads();
    float d0 = nb2l[tid], d1 = d0;
    for (int c2 = 0; c2 < 128; ++c2) {
        unsigned int wp = nw2w[c2 * 256 + tid];
        float4 s = *(const float4*)&suT[c2 * 2][0];
        d0 += s.x * bflo(wp) + s.z * bfhi(wp);
        d1 += s.y * bflo(wp) + s.w * bfhi(wp);
    }
    float h0 = h[(base + 0) * HH + tid] + d0;
    float h1 = h[(base + 1) * HH + tid] + d1;
    h[(base + 0) * HH + tid] = h0;
    h[(base + 1) * HH + tid] = h1;
    if (!has_ln) return;
    sh[0][tid] = h0; sh[1][tid] = h1;
    __syncthreads();

    int wv = tid >> 6, lane = tid & 63;
    if (wv < 2) {
        int row = base + wv;
        float v[4];
        #pragma unroll
        for (int q = 0; q < 4; ++q) v[q] = sh[wv][lane + 64 * q];
        float s = v[0] + v[1] + v[2] + v[3];
        #pragma unroll
        for (int m = 1; m < 64; m <<= 1) s += __shfl_xor(s, m);
        float mu = s * (1.0f / HH);
        float var = 0.f;
        #pragma unroll
        for (int q = 0; q < 4; ++q) { v[q] -= mu; var += v[q] * v[q]; }
        #pragma unroll
        for (int m = 1; m < 64; m <<= 1) var += __shfl_xor(var, m);
        float rstd = rsqrtf(var * (1.0f / HH) + 1e-5f);
        #pragma unroll
        for (int q = 0; q < 4; ++q) {
            int k = lane + 64 * q;
            float hv = v[q] * rstd * g[k] + bta[k];
            shnT[k][wv] = hv;
            hnout[row * HH + k] = hv;
        }
    }
    __syncthreads();

    float ai0 = eb1l[tid], ai1 = ai0;
    float aj0 = 0.f, aj1 = 0.f;
    for (int c2 = 0; c2 < 128; ++c2) {
        unsigned int wip = ew1w[c2 * 256 + tid];
        unsigned int wjp = ew1w[(128 + c2) * 256 + tid];
        float4 s = *(const float4*)&shnT[c2 * 2][0];
        ai0 += s.x * bflo(wip) + s.z * bfhi(wip);
        ai1 += s.y * bflo(wip) + s.w * bfhi(wip);
        aj0 += s.x * bflo(wjp) + s.z * bfhi(wjp);
        aj1 += s.y * bflo(wjp) + s.w * bfhi(wjp);
    }
    Ai[(base + 0) * HH + tid] = ai0; AjB[(base + 0) * HH + tid] = f2bf(aj0);
    Ai[(base + 1) * HH + tid] = ai1; AjB[(base + 1) * HH + tid] = f2bf(aj1);
}

// ---------------------------------------------------------------- decoder (2 rows/block)
__global__ __launch_bounds__(256) void k_decoder(
    const float* __restrict__ h,
    const float* __restrict__ dw1, const float* __restrict__ db1,
    const float* __restrict__ dw2, const float* __restrict__ db2,
    const float* __restrict__ dw3, const float* __restrict__ db3,
    float* __restrict__ out) {
    __shared__ float shT[HH][2];
    __shared__ float so1T[HH][2];
    __shared__ float so2T[HH][2];
    int tid = threadIdx.x;
    int base = blockIdx.x * 2;
    #pragma unroll
    for (int r = 0; r < 2; ++r) shT[tid][r] = h[(base + r) * HH + tid];
    __syncthreads();
    float a0 = db1[tid], a1 = a0;
    for (int c = 0; c < HH; ++c) {
        float w = dw1[c * HH + tid];
        float2 s = *(const float2*)&shT[c][0];
        a0 += s.x * w; a1 += s.y * w;
    }
    so1T[tid][0] = fmaxf(a0, 0.f); so1T[tid][1] = fmaxf(a1, 0.f);
    __syncthreads();
    a0 = db2[tid]; a1 = a0;
    for (int c = 0; c < HH; ++c) {
        float w = dw2[c * HH + tid];
        float2 s = *(const float2*)&so1T[c][0];
        a0 += s.x * w; a1 += s.y * w;
    }
    so2T[tid][0] = fmaxf(a0, 0.f) + shT[tid][0];
    so2T[tid][1] = fmaxf(a1, 0.f) + shT[tid][1];
    __syncthreads();
    if (tid < 6) {
        int r = tid / 3, c = tid % 3;
        float acc = db3[c];
        for (int k = 0; k < HH; ++k) acc += so2T[k][r] * dw3[k * 3 + c];
        out[(base + r) * 3 + c] = acc;
    }
}

// ---------------------------------------------------------------- launch
extern "C" void kernel_launch(void* const* d_in, const int* in_sizes, int n_in,
                              void* d_out, int out_size, void* d_ws, size_t ws_size,
                              hipStream_t stream) {
    const float* coords = (const float*)d_in[0];
    const float* feats  = (const float*)d_in[1];
    const float* t      = (const float*)d_in[2];
    const float* pe_w1  = (const float*)d_in[3];  const float* pe_b1 = (const float*)d_in[4];
    const float* pe_w2  = (const float*)d_in[5];  const float* pe_b2 = (const float*)d_in[6];
    const float* pe_w3  = (const float*)d_in[7];  const float* pe_b3 = (const float*)d_in[8];
    const float* te_w1  = (const float*)d_in[9];  const float* te_b1 = (const float*)d_in[10];
    const float* te_w2  = (const float*)d_in[11]; const float* te_b2 = (const float*)d_in[12];
    const float* ln_g   = (const float*)d_in[13]; const float* ln_b  = (const float*)d_in[14];
    const float* ew1    = (const float*)d_in[15]; const float* eb1   = (const float*)d_in[16];
    const float* ew2    = (const float*)d_in[17]; const float* eb2   = (const float*)d_in[18];
    const float* cw1    = (const float*)d_in[19]; const float* cb1   = (const float*)d_in[20];
    const float* cw2    = (const float*)d_in[21]; const float* cb2   = (const float*)d_in[22];
    const float* nw1    = (const float*)d_in[23]; const float* nb1   = (const float*)d_in[24];
    const float* nw2    = (const float*)d_in[25]; const float* nb2   = (const float*)d_in[26];
    const float* dec_w1 = (const float*)d_in[27]; const float* dec_b1 = (const float*)d_in[28];
    const float* dec_w2 = (const float*)d_in[29]; const float* dec_b2 = (const float*)d_in[30];
    const float* dec_w3 = (const float*)d_in[31]; const float* dec_b3 = (const float*)d_in[32];

    float* ws = (float*)d_ws;
    float* h      = ws;
    float* hn     = ws + RN;
    float* Ai     = ws + 2 * RN;
    float* magg   = ws + 3 * RN;
    float* x      = ws + 4 * RN;            // 1536 (reserve 2048)
    float* xdelta = ws + 4 * RN + 2048;     // 1536 (reserve 2048)
    unsigned short* AjB  = (unsigned short*)(ws + 4 * RN + 4096);
    unsigned short* ew2P = AjB + RN;                       // LL*65536
    unsigned short* cw1P = ew2P + LL * HH * HH;            // LL*65536
    unsigned short* nw1B = cw1P + LL * HH * HH;            // LL*131072
    unsigned short* ew1B = nw1B + LL * 2 * HH * HH;        // LL*131072
    unsigned short* nw2B = ew1B + LL * 2 * HH * HH;        // LL*65536

    k_convert<<<(LL * 8192 + 511) / 512, 512, 0, stream>>>(ew2, cw1, ew2P, cw1P);
    k_convert2<<<(LL * 131072 + 255) / 256, 256, 0, stream>>>(nw1, nw2, ew1, nw1B, nw2B, ew1B);
    k_encoder<<<NB * NN / 2, 256, 0, stream>>>(coords, feats, t,
        pe_w1, pe_b1, pe_w2, pe_b2, pe_w3, pe_b3, te_w1, te_b1, te_w2, te_b2, h, x);
    k_ln_aiaj<<<NB * NN / 2, 256, 0, stream>>>(h, ln_g, ln_b,
        (const unsigned int*)ew1B, eb1, hn, Ai, AjB);

    for (int l = 0; l < LL; ++l) {
        k_edge<<<NB * NN, 512, 0, stream>>>(x, Ai, AjB,
            ew1 + ((size_t)l * 513 + 512) * HH, eb2 + l * HH,
            ew2P + (size_t)l * HH * HH, cw1P + (size_t)l * HH * HH,
            cb1 + l * HH, cw2 + l * HH, cb2 + l, magg, xdelta);
        int ln = (l + 1 < LL) ? (l + 1) : LL - 1;  // params unused when has_ln=0
        k_node_ln<<<NB * NN / 2, 256, 0, stream>>>(hn, magg,
            (const unsigned int*)(nw1B + (size_t)l * 2 * HH * HH), nb1 + l * HH,
            (const unsigned int*)(nw2B + (size_t)l * HH * HH), nb2 + l * HH, h, x, xdelta,
            ln_g + ln * HH, ln_b + ln * HH,
            (const unsigned int*)(ew1B + (size_t)ln * 2 * HH * HH), eb1 + ln * HH,
            hn, Ai, AjB, (l + 1 < LL) ? 1 : 0);
    }

    k_decoder<<<NB * NN / 2, 256, 0, stream>>>(h, dec_w1, dec_b1, dec_w2, dec_b2,
                                               dec_w3, dec_b3, (float*)d_out);
}

// Round 16
// 580.947 us; speedup vs baseline: 1.2403x; 1.0801x over previous
//
#include <hip/hip_runtime.h>
#include <math.h>

static constexpr int NB = 2, NN = 256, HH = 256, DD = 64, LL = 6;
static constexpr int RN = NB * NN * HH;  // 131072
static constexpr int SROWB = 528;        // padded LDS row stride (bytes): 2-way banks, imm-foldable

typedef __attribute__((ext_vector_type(8))) short bf16x8;
typedef __attribute__((ext_vector_type(4))) float f32x4;
typedef __attribute__((ext_vector_type(4))) float float4v;
typedef __attribute__((ext_vector_type(4))) unsigned int u32x4;

__device__ __forceinline__ float fsilu(float v) {
    return v * __builtin_amdgcn_rcpf(1.0f + __expf(-v));
}
__device__ __forceinline__ unsigned short f2bf(float f) {
    union { float f; unsigned int u; } x; x.f = f;
    unsigned int r = x.u + 0x7fffu + ((x.u >> 16) & 1u);
    return (unsigned short)(r >> 16);
}
__device__ __forceinline__ float bitsf(unsigned int u) {
    union { float f; unsigned int u; } x; x.u = u; return x.f;
}
__device__ __forceinline__ float bflo(unsigned int w) { return bitsf(w << 16); }
__device__ __forceinline__ float bfhi(unsigned int w) { return bitsf(w & 0xffff0000u); }
__device__ __forceinline__ unsigned int cvtpk(float lo, float hi) {
    unsigned int w;
    asm("v_cvt_pk_bf16_f32 %0, %1, %2" : "=v"(w) : "v"(lo), "v"(hi));
    return w;
}

// ---------------------------------------------------------------- convert (edge fragment-packed)
__global__ void k_convert(const float* __restrict__ ew2, const float* __restrict__ cw1,
                          unsigned short* __restrict__ ew2P, unsigned short* __restrict__ cw1P) {
    int g = blockIdx.x * blockDim.x + threadIdx.x;
    if (g >= LL * 8192) return;
    int l = g >> 13;
    int r = g & 8191;
    int lane = r & 63;
    int fidx = r >> 6;
    int ks = fidx >> 4;
    int wv = (fidx >> 1) & 7;
    int ct = fidx & 1;
    int col = wv * 32 + ct * 16 + (lane & 15);
    int k0 = ks * 32 + (lane >> 4) * 8;
    #pragma unroll
    for (int e = 0; e < 8; ++e) {
        ew2P[(size_t)g * 8 + e] = f2bf(ew2[((size_t)l * HH + k0 + e) * HH + col]);
        cw1P[(size_t)g * 8 + e] = f2bf(cw1[((size_t)l * HH + k0 + e) * HH + col]);
    }
}

// ---------------------------------------------------------------- convert2 (bf16 pair-packed GEMV weights)
__global__ void k_convert2(const float* __restrict__ nw1, const float* __restrict__ nw2,
                           const float* __restrict__ ew1,
                           unsigned short* __restrict__ nw1B, unsigned short* __restrict__ nw2B,
                           unsigned short* __restrict__ ew1B) {
    int idx = blockIdx.x * blockDim.x + threadIdx.x;
    if (idx >= LL * 131072) return;
    int l = idx >> 17;
    int r = idx & 131071;
    int c = r >> 8, col = r & 255;
    int dst = (l << 17) + ((c >> 1) << 9) + (col << 1) + (c & 1);
    nw1B[dst] = f2bf(nw1[(size_t)l * 131072 + c * 256 + col]);
    ew1B[dst] = f2bf(ew1[(size_t)l * 131328 + c * 256 + col]);  // 513*256 stride
    if (r < 65536) {
        int d2 = (l << 16) + ((c >> 1) << 9) + (col << 1) + (c & 1);
        nw2B[d2] = f2bf(nw2[(size_t)l * 65536 + c * 256 + col]);
    }
}

// ---------------------------------------------------------------- encoder (2 rows/block, broadcast staging)
__global__ __launch_bounds__(256) void k_encoder(
    const float* __restrict__ coords, const float* __restrict__ feats, const float* __restrict__ t,
    const float* __restrict__ pw1, const float* __restrict__ pb1,
    const float* __restrict__ pw2, const float* __restrict__ pb2,
    const float* __restrict__ pw3, const float* __restrict__ pb3,
    const float* __restrict__ tw1, const float* __restrict__ tb1,
    const float* __restrict__ tw2, const float* __restrict__ tb2,
    float* __restrict__ h, float* __restrict__ x) {
    __shared__ float spinT[68][2];
    __shared__ float shaT[HH][2];
    __shared__ float shbT[HH][2];
    __shared__ float ste1[HH];
    int tid = threadIdx.x;
    int base = blockIdx.x * 2;
    int b = base / NN;

    #pragma unroll
    for (int r = 0; r < 2; ++r) {
        int row = base + r;
        if (tid < 3) spinT[tid][r] = coords[row * 3 + tid];
        if (tid < DD) spinT[3 + tid][r] = feats[row * DD + tid];
    }
    float tv = t[b];
    ste1[tid] = fmaxf(tv * tw1[tid] + tb1[tid], 0.0f);
    if (tid < 6) {
        int r = tid / 3, c = tid % 3;
        x[(base + r) * 3 + c] = coords[(base + r) * 3 + c];
    }
    __syncthreads();

    float a0 = pb1[tid], a1 = a0;
    for (int c = 0; c < 67; ++c) {
        float w = pw1[c * HH + tid];
        float2 s = *(const float2*)&spinT[c][0];
        a0 += s.x * w; a1 += s.y * w;
    }
    shaT[tid][0] = fmaxf(a0, 0.f); shaT[tid][1] = fmaxf(a1, 0.f);
    __syncthreads();
    a0 = pb2[tid]; a1 = a0;
    for (int c = 0; c < HH; ++c) {
        float w = pw2[c * HH + tid];
        float2 s = *(const float2*)&shaT[c][0];
        a0 += s.x * w; a1 += s.y * w;
    }
    shbT[tid][0] = fmaxf(a0, 0.f); shbT[tid][1] = fmaxf(a1, 0.f);
    __syncthreads();
    a0 = pb3[tid]; a1 = a0;
    float te = tb2[tid];
    for (int c = 0; c < HH; ++c) {
        float w = pw3[c * HH + tid];
        float2 s = *(const float2*)&shbT[c][0];
        a0 += s.x * w; a1 += s.y * w;
        te += ste1[c] * tw2[c * HH + tid];
    }
    h[(base + 0) * HH + tid] = fmaxf(a0, 0.f) + te;
    h[(base + 1) * HH + tid] = fmaxf(a1, 0.f) + te;
}

// ---------------------------------------------------------------- LayerNorm + Ai/Aj (layer 0; bf16 ew1)
__global__ __launch_bounds__(256) void k_ln_aiaj(
    const float* __restrict__ h, const float* __restrict__ g, const float* __restrict__ bta,
    const unsigned int* __restrict__ ew1w, const float* __restrict__ eb1l,
    float* __restrict__ hn, float* __restrict__ Ai, unsigned short* __restrict__ AjB) {
    __shared__ float shnT[HH][2];
    int tid = threadIdx.x, wv = tid >> 6, lane = tid & 63;
    int base = blockIdx.x * 2;

    if (wv < 2) {
        int row = base + wv;
        float v[4];
        #pragma unroll
        for (int q = 0; q < 4; ++q) v[q] = h[row * HH + lane + 64 * q];
        float s = v[0] + v[1] + v[2] + v[3];
        #pragma unroll
        for (int m = 1; m < 64; m <<= 1) s += __shfl_xor(s, m);
        float mu = s * (1.0f / HH);
        float var = 0.f;
        #pragma unroll
        for (int q = 0; q < 4; ++q) { v[q] -= mu; var += v[q] * v[q]; }
        #pragma unroll
        for (int m = 1; m < 64; m <<= 1) var += __shfl_xor(var, m);
        float rstd = rsqrtf(var * (1.0f / HH) + 1e-5f);
        #pragma unroll
        for (int q = 0; q < 4; ++q) {
            int k = lane + 64 * q;
            float hv = v[q] * rstd * g[k] + bta[k];
            shnT[k][wv] = hv;
            hn[row * HH + k] = hv;
        }
    }
    __syncthreads();

    float ai0 = eb1l[tid], ai1 = ai0;
    float aj0 = 0.f, aj1 = 0.f;
    for (int c2 = 0; c2 < 128; ++c2) {
        unsigned int wip = ew1w[c2 * 256 + tid];
        unsigned int wjp = ew1w[(128 + c2) * 256 + tid];
        float4 s = *(const float4*)&shnT[c2 * 2][0];
        ai0 += s.x * bflo(wip) + s.z * bfhi(wip);
        ai1 += s.y * bflo(wip) + s.w * bfhi(wip);
        aj0 += s.x * bflo(wjp) + s.z * bfhi(wjp);
        aj1 += s.y * bflo(wjp) + s.w * bfhi(wjp);
    }
    Ai[(base + 0) * HH + tid] = ai0; AjB[(base + 0) * HH + tid] = f2bf(aj0);
    Ai[(base + 1) * HH + tid] = ai1; AjB[(base + 1) * HH + tid] = f2bf(aj1);
}

// ---------------------------------------------------------------- fused edge + node update + next-layer LN/Ai/Aj
// Main loop = round-15 structure (80us, mixed pipe-bound, stable). Tail fuses
// the former k_node_ln: block i owns row i's magg/xdelta/h/hn end-to-end, so
// the node MLP + LN + next-layer Ai/Aj run in-block (3 GEMVs, 512-thread
// col x k-half split over bf16 pair-packed weights, ~640KB L2/block).
// Race safety: x / Ai / AjB are read by ALL blocks during the main loop ->
// tail writes go to PING-PONG buffers (xnext/Ainext/AjBnext); h/hn are
// row-local (only block i touches row i). Removes 6 dispatches + gaps.
// __launch_bounds__(512, 1): arg2 is min BLOCKS/CU on hipcc; >=2 caps
// regalloc and spills when working set >128 VGPR (rounds 2-5, 8). DO NOT raise.
__global__ __launch_bounds__(512, 1) void k_edge(
    const float* __restrict__ x, const float* __restrict__ Ai, const unsigned short* __restrict__ AjB,
    const float* __restrict__ wd, const float* __restrict__ eb2v,
    const unsigned short* __restrict__ ew2P, const unsigned short* __restrict__ cw1P,
    const float* __restrict__ cb1v, const float* __restrict__ cw2v, const float* __restrict__ cb2p,
    float* __restrict__ h, float* __restrict__ hn,
    float* __restrict__ xnext, float* __restrict__ Ainext, unsigned short* __restrict__ AjBnext,
    const unsigned int* __restrict__ nw1w, const float* __restrict__ nb1l,
    const unsigned int* __restrict__ nw2w, const float* __restrict__ nb2l,
    const float* __restrict__ gamv, const float* __restrict__ betv,
    const unsigned int* __restrict__ ew1wn, const float* __restrict__ eb1n,
    int has_ln) {
    __shared__ float srel[128][3];
    __shared__ float sd2[128];
    __shared__ float cwpart[8][128];
    __shared__ float smagg[256];
    __shared__ char s_tile[128 * SROWB];  // 67.6KB (tail reuses as scratch)
    __shared__ char m_tile[128 * SROWB];  // 67.6KB

    int tid = threadIdx.x, wv = tid >> 6, lane = tid & 63;
    int g4 = lane >> 4, l15 = lane & 15;
    int colbase = wv * 32;
    int bi = blockIdx.x;
    int b = bi >> 8, i = bi & 255;
    int ni = b * NN + i;
    int bbase = b * NN;
    int bthr = ((wv << 7) + lane) << 3;

    int k0p = (tid & 31) << 3;
    float aiv[8], wdv[8];
    {
        float4v a0 = *(const float4v*)(Ai + (size_t)ni * HH + k0p);
        float4v a1 = *(const float4v*)(Ai + (size_t)ni * HH + k0p + 4);
        float4v w0 = *(const float4v*)(wd + k0p);
        float4v w1 = *(const float4v*)(wd + k0p + 4);
        #pragma unroll
        for (int e = 0; e < 4; ++e) { aiv[e] = a0[e]; aiv[4 + e] = a1[e]; wdv[e] = w0[e]; wdv[4 + e] = w1[e]; }
    }
    float eb2r[2], cb1r[2], cw2r[2];
    #pragma unroll
    for (int ct = 0; ct < 2; ++ct) {
        int col = colbase + ct * 16 + l15;
        eb2r[ct] = eb2v[col]; cb1r[ct] = cb1v[col]; cw2r[ct] = cw2v[col];
    }
    float xi0 = x[ni * 3 + 0], xi1 = x[ni * 3 + 1], xi2 = x[ni * 3 + 2];
    float cb2 = cb2p[0];

    bf16x8 Bew[8][2], Bcw[8][2];
    #pragma unroll
    for (int ks = 0; ks < 8; ++ks) {
        #pragma unroll
        for (int ct = 0; ct < 2; ++ct) {
            Bew[ks][ct] = *(const bf16x8*)(ew2P + (ks << 13) + (ct << 9) + bthr);
            Bcw[ks][ct] = *(const bf16x8*)(cw1P + (ks << 13) + (ct << 9) + bthr);
        }
    }

    char* p1w = s_tile + ((tid >> 5) * SROWB + k0p * 2);
    const char* aA = s_tile + (l15 * SROWB + g4 * 16);
    const char* aM = m_tile + (l15 * SROWB + g4 * 16);
    char* mwA = m_tile + ((g4 * 4) * SROWB + (colbase + l15) * 2);
    float mgv[2] = {0.f, 0.f};
    float xd0 = 0.f, xd1 = 0.f, xd2 = 0.f;

    #pragma unroll 1
    for (int jc = 0; jc < 2; ++jc) {
        int j0 = jc * 128;
        __syncthreads();
        if (tid < 128) {
            int j = bbase + j0 + tid;
            float rx = xi0 - x[j * 3 + 0];
            float ry = xi1 - x[j * 3 + 1];
            float rz = xi2 - x[j * 3 + 2];
            srel[tid][0] = rx; srel[tid][1] = ry; srel[tid][2] = rz;
            sd2[tid] = rx * rx + ry * ry + rz * rz;
        }
        __syncthreads();

        // ---- phase 1
        #pragma unroll
        for (int it = 0; it < 8; ++it) {
            int row = it * 16 + (tid >> 5);
            float d2v = sd2[row];
            u32x4 ajw = *(const u32x4*)(AjB + ((size_t)(bbase + j0 + row) * HH + k0p));
            unsigned int uw0, uw1, uw2, uw3;
            uw0 = cvtpk(fsilu(aiv[0] + bflo(ajw[0]) + d2v * wdv[0]), fsilu(aiv[1] + bfhi(ajw[0]) + d2v * wdv[1]));
            uw1 = cvtpk(fsilu(aiv[2] + bflo(ajw[1]) + d2v * wdv[2]), fsilu(aiv[3] + bfhi(ajw[1]) + d2v * wdv[3]));
            uw2 = cvtpk(fsilu(aiv[4] + bflo(ajw[2]) + d2v * wdv[4]), fsilu(aiv[5] + bfhi(ajw[2]) + d2v * wdv[5]));
            uw3 = cvtpk(fsilu(aiv[6] + bflo(ajw[3]) + d2v * wdv[6]), fsilu(aiv[7] + bfhi(ajw[3]) + d2v * wdv[7]));
            u32x4 sv = {uw0, uw1, uw2, uw3};
            *reinterpret_cast<u32x4*>(p1w + it * 16 * SROWB) = sv;
        }
        __syncthreads();

        // ---- phase 2
        #pragma unroll 1
        for (int rh = 0; rh < 4; ++rh) {
            f32x4 acc[2][2];
            acc[0][0] = (f32x4){0.f,0.f,0.f,0.f}; acc[0][1] = (f32x4){0.f,0.f,0.f,0.f};
            acc[1][0] = (f32x4){0.f,0.f,0.f,0.f}; acc[1][1] = (f32x4){0.f,0.f,0.f,0.f};
            const char* aBase = aA + rh * 32 * SROWB;
            #pragma unroll
            for (int ks = 0; ks < 8; ++ks) {
                bf16x8 a0 = *reinterpret_cast<const bf16x8*>(aBase + ks * 64);
                bf16x8 a1 = *reinterpret_cast<const bf16x8*>(aBase + 16 * SROWB + ks * 64);
                acc[0][0] = __builtin_amdgcn_mfma_f32_16x16x32_bf16(a0, Bew[ks][0], acc[0][0], 0, 0, 0);
                acc[0][1] = __builtin_amdgcn_mfma_f32_16x16x32_bf16(a0, Bew[ks][1], acc[0][1], 0, 0, 0);
                acc[1][0] = __builtin_amdgcn_mfma_f32_16x16x32_bf16(a1, Bew[ks][0], acc[1][0], 0, 0, 0);
                acc[1][1] = __builtin_amdgcn_mfma_f32_16x16x32_bf16(a1, Bew[ks][1], acc[1][1], 0, 0, 0);
            }
            char* mw = mwA + rh * 32 * SROWB;
            #pragma unroll
            for (int rt = 0; rt < 2; ++rt) {
                #pragma unroll
                for (int r = 0; r < 4; ++r) {
                    float v0 = fsilu(acc[rt][0][r] + eb2r[0]);
                    float v1 = fsilu(acc[rt][1][r] + eb2r[1]);
                    mgv[0] += v0; mgv[1] += v1;
                    unsigned int w = cvtpk(v0, v1);
                    char* p = mw + (rt * 16 + r) * SROWB;
                    *reinterpret_cast<unsigned short*>(p) = (unsigned short)w;
                    *reinterpret_cast<unsigned short*>(p + 32) = (unsigned short)(w >> 16);
                }
            }
        }
        __syncthreads();

        // ---- phase 3
        #pragma unroll 1
        for (int rh = 0; rh < 4; ++rh) {
            f32x4 acc[2][2];
            acc[0][0] = (f32x4){0.f,0.f,0.f,0.f}; acc[0][1] = (f32x4){0.f,0.f,0.f,0.f};
            acc[1][0] = (f32x4){0.f,0.f,0.f,0.f}; acc[1][1] = (f32x4){0.f,0.f,0.f,0.f};
            const char* aBase = aM + rh * 32 * SROWB;
            #pragma unroll
            for (int ks = 0; ks < 8; ++ks) {
                bf16x8 a0 = *reinterpret_cast<const bf16x8*>(aBase + ks * 64);
                bf16x8 a1 = *reinterpret_cast<const bf16x8*>(aBase + 16 * SROWB + ks * 64);
                acc[0][0] = __builtin_amdgcn_mfma_f32_16x16x32_bf16(a0, Bcw[ks][0], acc[0][0], 0, 0, 0);
                acc[0][1] = __builtin_amdgcn_mfma_f32_16x16x32_bf16(a0, Bcw[ks][1], acc[0][1], 0, 0, 0);
                acc[1][0] = __builtin_amdgcn_mfma_f32_16x16x32_bf16(a1, Bcw[ks][0], acc[1][0], 0, 0, 0);
                acc[1][1] = __builtin_amdgcn_mfma_f32_16x16x32_bf16(a1, Bcw[ks][1], acc[1][1], 0, 0, 0);
            }
            float rs[8];
            #pragma unroll
            for (int q = 0; q < 8; ++q) rs[q] = 0.f;
            #pragma unroll
            for (int ct = 0; ct < 2; ++ct) {
                #pragma unroll
                for (int rt = 0; rt < 2; ++rt)
                    #pragma unroll
                    for (int r = 0; r < 4; ++r)
                        rs[rt * 4 + r] += fsilu(acc[rt][ct][r] + cb1r[ct]) * cw2r[ct];
            }
            #pragma unroll
            for (int m = 1; m <= 8; m <<= 1)
                #pragma unroll
                for (int q = 0; q < 8; ++q) rs[q] += __shfl_xor(rs[q], m);
            if (l15 == 0) {
                #pragma unroll
                for (int rt = 0; rt < 2; ++rt)
                    #pragma unroll
                    for (int r = 0; r < 4; ++r)
                        cwpart[wv][rh * 32 + rt * 16 + g4 * 4 + r] = rs[rt * 4 + r];
            }
        }
        __syncthreads();
        if (tid < 64) {
            #pragma unroll 1
            for (int q = 0; q < 2; ++q) {
                int lr = q * 64 + tid;
                float cwv = cb2;
                #pragma unroll
                for (int w = 0; w < 8; ++w) cwv += cwpart[w][lr];
                float p0 = srel[lr][0] * cwv;
                float p1 = srel[lr][1] * cwv;
                float p2 = srel[lr][2] * cwv;
                #pragma unroll
                for (int m = 1; m < 64; m <<= 1) {
                    p0 += __shfl_xor(p0, m); p1 += __shfl_xor(p1, m); p2 += __shfl_xor(p2, m);
                }
                xd0 += p0; xd1 += p1; xd2 += p2;
            }
        }
    }

    // ================= fused tail: node update + LN + next-layer Ai/Aj =================
    #pragma unroll
    for (int ct = 0; ct < 2; ++ct) {
        mgv[ct] += __shfl_xor(mgv[ct], 16);
        mgv[ct] += __shfl_xor(mgv[ct], 32);
    }
    if (lane < 16) {
        smagg[colbase + lane] = mgv[0];
        smagg[colbase + 16 + lane] = mgv[1];
    }
    if (has_ln && tid == 0) {
        xnext[ni * 3 + 0] = xi0 + xd0 * (1.0f / NN);
        xnext[ni * 3 + 1] = xi1 + xd1 * (1.0f / NN);
        xnext[ni * 3 + 2] = xi2 + xd2 * (1.0f / NN);
    }
    __syncthreads();

    // LDS scratch regions (s_tile is dead after the jc loop)
    float* s2v   = (float*)s_tile;            // 512
    float* part  = (float*)(s_tile + 4096);   // 512
    float* suv   = (float*)(s_tile + 8192);   // 256
    float* shrow = (float*)(s_tile + 12288);  // 256
    float* shnv  = (float*)(s_tile + 16384);  // 256
    float* red   = (float*)(s_tile + 20480);  // 16

    if (tid < 256) {
        s2v[tid] = hn[(size_t)ni * HH + tid];
        s2v[HH + tid] = smagg[tid];
    }
    __syncthreads();
    {   // u-partials: col = tid&255, k-half = tid>>8 (c2 in [kh*128, kh*128+128))
        int col = tid & 255, kh = tid >> 8;
        const unsigned int* w = nw1w + (kh * 128) * 256;
        const float* sv = s2v + kh * 256;
        float p = 0.f;
        for (int c2 = 0; c2 < 128; ++c2) {
            unsigned int wp = w[c2 * 256 + col];
            float2 sp = *(const float2*)&sv[c2 * 2];
            p += sp.x * bflo(wp) + sp.y * bfhi(wp);
        }
        part[tid] = p;
    }
    __syncthreads();
    if (tid < 256) suv[tid] = fsilu(part[tid] + part[256 + tid] + nb1l[tid]);
    __syncthreads();
    {   // d-partials: nw2 (c2 total 128; halves of 64)
        int col = tid & 255, kh = tid >> 8;
        const unsigned int* w = nw2w + (kh * 64) * 256;
        const float* sv = suv + kh * 128;
        float p = 0.f;
        for (int c2 = 0; c2 < 64; ++c2) {
            unsigned int wp = w[c2 * 256 + col];
            float2 sp = *(const float2*)&sv[c2 * 2];
            p += sp.x * bflo(wp) + sp.y * bfhi(wp);
        }
        part[tid] = p;
    }
    __syncthreads();
    if (tid < 256) {
        float hv = h[(size_t)ni * HH + tid] + part[tid] + part[256 + tid] + nb2l[tid];
        h[(size_t)ni * HH + tid] = hv;
        shrow[tid] = hv;
    }
    __syncthreads();
    if (!has_ln) return;

    {   // LayerNorm: block reduce sum & sumsq (waves 4-7 contribute zeros)
        float v = (tid < 256) ? shrow[tid] : 0.f;
        float s1 = v, sq = v * v;
        #pragma unroll
        for (int m = 1; m < 64; m <<= 1) { s1 += __shfl_xor(s1, m); sq += __shfl_xor(sq, m); }
        if (lane == 0) { red[wv] = s1; red[8 + wv] = sq; }
    }
    __syncthreads();
    {
        float mu  = (red[0] + red[1] + red[2] + red[3]) * (1.0f / HH);
        float msq = (red[8] + red[9] + red[10] + red[11]) * (1.0f / HH);
        float rstd = rsqrtf(msq - mu * mu + 1e-5f);
        if (tid < 256) {
            float hv = (shrow[tid] - mu) * rstd * gamv[tid] + betv[tid];
            shnv[tid] = hv;
            hn[(size_t)ni * HH + tid] = hv;
        }
    }
    __syncthreads();
    {   // next-layer Ai (half 0) / Aj (half 1)
        int col = tid & 255, hf = tid >> 8;
        const unsigned int* w = ew1wn + (hf * 128) * 256;
        float p = (hf == 0) ? eb1n[col] : 0.f;
        for (int c2 = 0; c2 < 128; ++c2) {
            unsigned int wp = w[c2 * 256 + col];
            float2 sp = *(const float2*)&shnv[c2 * 2];
            p += sp.x * bflo(wp) + sp.y * bfhi(wp);
        }
        if (hf == 0) Ainext[(size_t)ni * HH + col] = p;
        else AjBnext[(size_t)ni * HH + col] = f2bf(p);
    }
}

// ---------------------------------------------------------------- decoder (2 rows/block)
__global__ __launch_bounds__(256) void k_decoder(
    const float* __restrict__ h,
    const float* __restrict__ dw1, const float* __restrict__ db1,
    const float* __restrict__ dw2, const float* __restrict__ db2,
    const float* __restrict__ dw3, const float* __restrict__ db3,
    float* __restrict__ out) {
    __shared__ float shT[HH][2];
    __shared__ float so1T[HH][2];
    __shared__ float so2T[HH][2];
    int tid = threadIdx.x;
    int base = blockIdx.x * 2;
    #pragma unroll
    for (int r = 0; r < 2; ++r) shT[tid][r] = h[(base + r) * HH + tid];
    __syncthreads();
    float a0 = db1[tid], a1 = a0;
    for (int c = 0; c < HH; ++c) {
        float w = dw1[c * HH + tid];
        float2 s = *(const float2*)&shT[c][0];
        a0 += s.x * w; a1 += s.y * w;
    }
    so1T[tid][0] = fmaxf(a0, 0.f); so1T[tid][1] = fmaxf(a1, 0.f);
    __syncthreads();
    a0 = db2[tid]; a1 = a0;
    for (int c = 0; c < HH; ++c) {
        float w = dw2[c * HH + tid];
        float2 s = *(const float2*)&so1T[c][0];
        a0 += s.x * w; a1 += s.y * w;
    }
    so2T[tid][0] = fmaxf(a0, 0.f) + shT[tid][0];
    so2T[tid][1] = fmaxf(a1, 0.f) + shT[tid][1];
    __syncthreads();
    if (tid < 6) {
        int r = tid / 3, c = tid % 3;
        float acc = db3[c];
        for (int k = 0; k < HH; ++k) acc += so2T[k][r] * dw3[k * 3 + c];
        out[(base + r) * 3 + c] = acc;
    }
}

// ---------------------------------------------------------------- launch
extern "C" void kernel_launch(void* const* d_in, const int* in_sizes, int n_in,
                              void* d_out, int out_size, void* d_ws, size_t ws_size,
                              hipStream_t stream) {
    const float* coords = (const float*)d_in[0];
    const float* feats  = (const float*)d_in[1];
    const float* t      = (const float*)d_in[2];
    const float* pe_w1  = (const float*)d_in[3];  const float* pe_b1 = (const float*)d_in[4];
    const float* pe_w2  = (const float*)d_in[5];  const float* pe_b2 = (const float*)d_in[6];
    const float* pe_w3  = (const float*)d_in[7];  const float* pe_b3 = (const float*)d_in[8];
    const float* te_w1  = (const float*)d_in[9];  const float* te_b1 = (const float*)d_in[10];
    const float* te_w2  = (const float*)d_in[11]; const float* te_b2 = (const float*)d_in[12];
    const float* ln_g   = (const float*)d_in[13]; const float* ln_b  = (const float*)d_in[14];
    const float* ew1    = (const float*)d_in[15]; const float* eb1   = (const float*)d_in[16];
    const float* ew2    = (const float*)d_in[17]; const float* eb2   = (const float*)d_in[18];
    const float* cw1    = (const float*)d_in[19]; const float* cb1   = (const float*)d_in[20];
    const float* cw2    = (const float*)d_in[21]; const float* cb2   = (const float*)d_in[22];
    const float* nw1    = (const float*)d_in[23]; const float* nb1   = (const float*)d_in[24];
    const float* nw2    = (const float*)d_in[25]; const float* nb2   = (const float*)d_in[26];
    const float* dec_w1 = (const float*)d_in[27]; const float* dec_b1 = (const float*)d_in[28];
    const float* dec_w2 = (const float*)d_in[29]; const float* dec_b2 = (const float*)d_in[30];
    const float* dec_w3 = (const float*)d_in[31]; const float* dec_b3 = (const float*)d_in[32];

    float* ws = (float*)d_ws;
    float* h    = ws;
    float* hn   = ws + RN;
    float* Ai0  = ws + 2 * RN;
    float* Ai1  = ws + 3 * RN;
    float* xb0  = ws + 4 * RN;              // 1536 (reserve 2048)
    float* xb1  = ws + 4 * RN + 2048;       // 1536 (reserve 2048)
    unsigned short* Aj0  = (unsigned short*)(ws + 4 * RN + 4096);
    unsigned short* Aj1  = Aj0 + RN;
    unsigned short* ew2P = Aj1 + RN;                       // LL*65536
    unsigned short* cw1P = ew2P + LL * HH * HH;            // LL*65536
    unsigned short* nw1B = cw1P + LL * HH * HH;            // LL*131072
    unsigned short* ew1B = nw1B + LL * 2 * HH * HH;        // LL*131072
    unsigned short* nw2B = ew1B + LL * 2 * HH * HH;        // LL*65536

    k_convert<<<(LL * 8192 + 511) / 512, 512, 0, stream>>>(ew2, cw1, ew2P, cw1P);
    k_convert2<<<(LL * 131072 + 255) / 256, 256, 0, stream>>>(nw1, nw2, ew1, nw1B, nw2B, ew1B);
    k_encoder<<<NB * NN / 2, 256, 0, stream>>>(coords, feats, t,
        pe_w1, pe_b1, pe_w2, pe_b2, pe_w3, pe_b3, te_w1, te_b1, te_w2, te_b2, h, xb0);
    k_ln_aiaj<<<NB * NN / 2, 256, 0, stream>>>(h, ln_g, ln_b,
        (const unsigned int*)ew1B, eb1, hn, Ai0, Aj0);

    for (int l = 0; l < LL; ++l) {
        const float* xin = (l & 1) ? xb1 : xb0;
        float* xout      = (l & 1) ? xb0 : xb1;
        const float* AiIn = (l & 1) ? Ai1 : Ai0;
        float* AiOut      = (l & 1) ? Ai0 : Ai1;
        const unsigned short* AjIn = (l & 1) ? Aj1 : Aj0;
        unsigned short* AjOut      = (l & 1) ? Aj0 : Aj1;
        int ln = (l + 1 < LL) ? (l + 1) : LL - 1;  // tail params unused when has_ln=0
        k_edge<<<NB * NN, 512, 0, stream>>>(xin, AiIn, AjIn,
            ew1 + ((size_t)l * 513 + 512) * HH, eb2 + l * HH,
            ew2P + (size_t)l * HH * HH, cw1P + (size_t)l * HH * HH,
            cb1 + l * HH, cw2 + l * HH, cb2 + l,
            h, hn, xout, AiOut, AjOut,
            (const unsigned int*)(nw1B + (size_t)l * 2 * HH * HH), nb1 + l * HH,
            (const unsigned int*)(nw2B + (size_t)l * HH * HH), nb2 + l * HH,
            ln_g + ln * HH, ln_b + ln * HH,
            (const unsigned int*)(ew1B + (size_t)ln * 2 * HH * HH), eb1 + ln * HH,
            (l + 1 < LL) ? 1 : 0);
    }

    k_decoder<<<NB * NN / 2, 256, 0, stream>>>(h, dec_w1, dec_b1, dec_w2, dec_b2,
                                               dec_w3, dec_b3, (float*)d_out);
}

// Round 17
// 515.155 us; speedup vs baseline: 1.3987x; 1.1277x over previous
//
#include <hip/hip_runtime.h>
#include <math.h>

static constexpr int NB = 2, NN = 256, HH = 256, DD = 64, LL = 6;
static constexpr int RN = NB * NN * HH;  // 131072
static constexpr int SROWB = 528;        // padded LDS row stride (bytes): 2-way banks, imm-foldable

typedef __attribute__((ext_vector_type(8))) short bf16x8;
typedef __attribute__((ext_vector_type(4))) float f32x4;
typedef __attribute__((ext_vector_type(4))) float float4v;
typedef __attribute__((ext_vector_type(4))) unsigned int u32x4;

__device__ __forceinline__ float fsilu(float v) {
    return v * __builtin_amdgcn_rcpf(1.0f + __expf(-v));
}
__device__ __forceinline__ unsigned short f2bf(float f) {
    union { float f; unsigned int u; } x; x.f = f;
    unsigned int r = x.u + 0x7fffu + ((x.u >> 16) & 1u);
    return (unsigned short)(r >> 16);
}
__device__ __forceinline__ float bitsf(unsigned int u) {
    union { float f; unsigned int u; } x; x.u = u; return x.f;
}
__device__ __forceinline__ float bflo(unsigned int w) { return bitsf(w << 16); }
__device__ __forceinline__ float bfhi(unsigned int w) { return bitsf(w & 0xffff0000u); }
__device__ __forceinline__ unsigned int cvtpk(float lo, float hi) {
    unsigned int w;
    asm("v_cvt_pk_bf16_f32 %0, %1, %2" : "=v"(w) : "v"(lo), "v"(hi));
    return w;
}

// ---------------------------------------------------------------- convert (edge fragment-packed)
__global__ void k_convert(const float* __restrict__ ew2, const float* __restrict__ cw1,
                          unsigned short* __restrict__ ew2P, unsigned short* __restrict__ cw1P) {
    int g = blockIdx.x * blockDim.x + threadIdx.x;
    if (g >= LL * 8192) return;
    int l = g >> 13;
    int r = g & 8191;
    int lane = r & 63;
    int fidx = r >> 6;
    int ks = fidx >> 4;
    int wv = (fidx >> 1) & 7;
    int ct = fidx & 1;
    int col = wv * 32 + ct * 16 + (lane & 15);
    int k0 = ks * 32 + (lane >> 4) * 8;
    #pragma unroll
    for (int e = 0; e < 8; ++e) {
        ew2P[(size_t)g * 8 + e] = f2bf(ew2[((size_t)l * HH + k0 + e) * HH + col]);
        cw1P[(size_t)g * 8 + e] = f2bf(cw1[((size_t)l * HH + k0 + e) * HH + col]);
    }
}

// ---------------------------------------------------------------- convert2 (bf16 pair-packed GEMV weights)
__global__ void k_convert2(const float* __restrict__ nw1, const float* __restrict__ nw2,
                           const float* __restrict__ ew1,
                           unsigned short* __restrict__ nw1B, unsigned short* __restrict__ nw2B,
                           unsigned short* __restrict__ ew1B) {
    int idx = blockIdx.x * blockDim.x + threadIdx.x;
    if (idx >= LL * 131072) return;
    int l = idx >> 17;
    int r = idx & 131071;
    int c = r >> 8, col = r & 255;
    int dst = (l << 17) + ((c >> 1) << 9) + (col << 1) + (c & 1);
    nw1B[dst] = f2bf(nw1[(size_t)l * 131072 + c * 256 + col]);
    ew1B[dst] = f2bf(ew1[(size_t)l * 131328 + c * 256 + col]);  // 513*256 stride
    if (r < 65536) {
        int d2 = (l << 16) + ((c >> 1) << 9) + (col << 1) + (c & 1);
        nw2B[d2] = f2bf(nw2[(size_t)l * 65536 + c * 256 + col]);
    }
}

// ---------------------------------------------------------------- encoder (2 rows/block, broadcast staging)
__global__ __launch_bounds__(256) void k_encoder(
    const float* __restrict__ coords, const float* __restrict__ feats, const float* __restrict__ t,
    const float* __restrict__ pw1, const float* __restrict__ pb1,
    const float* __restrict__ pw2, const float* __restrict__ pb2,
    const float* __restrict__ pw3, const float* __restrict__ pb3,
    const float* __restrict__ tw1, const float* __restrict__ tb1,
    const float* __restrict__ tw2, const float* __restrict__ tb2,
    float* __restrict__ h, float* __restrict__ x) {
    __shared__ float spinT[68][2];
    __shared__ float shaT[HH][2];
    __shared__ float shbT[HH][2];
    __shared__ float ste1[HH];
    int tid = threadIdx.x;
    int base = blockIdx.x * 2;
    int b = base / NN;

    #pragma unroll
    for (int r = 0; r < 2; ++r) {
        int row = base + r;
        if (tid < 3) spinT[tid][r] = coords[row * 3 + tid];
        if (tid < DD) spinT[3 + tid][r] = feats[row * DD + tid];
    }
    float tv = t[b];
    ste1[tid] = fmaxf(tv * tw1[tid] + tb1[tid], 0.0f);
    if (tid < 6) {
        int r = tid / 3, c = tid % 3;
        x[(base + r) * 3 + c] = coords[(base + r) * 3 + c];
    }
    __syncthreads();

    float a0 = pb1[tid], a1 = a0;
    for (int c = 0; c < 67; ++c) {
        float w = pw1[c * HH + tid];
        float2 s = *(const float2*)&spinT[c][0];
        a0 += s.x * w; a1 += s.y * w;
    }
    shaT[tid][0] = fmaxf(a0, 0.f); shaT[tid][1] = fmaxf(a1, 0.f);
    __syncthreads();
    a0 = pb2[tid]; a1 = a0;
    for (int c = 0; c < HH; ++c) {
        float w = pw2[c * HH + tid];
        float2 s = *(const float2*)&shaT[c][0];
        a0 += s.x * w; a1 += s.y * w;
    }
    shbT[tid][0] = fmaxf(a0, 0.f); shbT[tid][1] = fmaxf(a1, 0.f);
    __syncthreads();
    a0 = pb3[tid]; a1 = a0;
    float te = tb2[tid];
    for (int c = 0; c < HH; ++c) {
        float w = pw3[c * HH + tid];
        float2 s = *(const float2*)&shbT[c][0];
        a0 += s.x * w; a1 += s.y * w;
        te += ste1[c] * tw2[c * HH + tid];
    }
    h[(base + 0) * HH + tid] = fmaxf(a0, 0.f) + te;
    h[(base + 1) * HH + tid] = fmaxf(a1, 0.f) + te;
}

// ---------------------------------------------------------------- LayerNorm + Ai/Aj (layer 0; bf16 ew1)
__global__ __launch_bounds__(256) void k_ln_aiaj(
    const float* __restrict__ h, const float* __restrict__ g, const float* __restrict__ bta,
    const unsigned int* __restrict__ ew1w, const float* __restrict__ eb1l,
    float* __restrict__ hn, float* __restrict__ Ai, unsigned short* __restrict__ AjB) {
    __shared__ float shnT[HH][2];
    int tid = threadIdx.x, wv = tid >> 6, lane = tid & 63;
    int base = blockIdx.x * 2;

    if (wv < 2) {
        int row = base + wv;
        float v[4];
        #pragma unroll
        for (int q = 0; q < 4; ++q) v[q] = h[row * HH + lane + 64 * q];
        float s = v[0] + v[1] + v[2] + v[3];
        #pragma unroll
        for (int m = 1; m < 64; m <<= 1) s += __shfl_xor(s, m);
        float mu = s * (1.0f / HH);
        float var = 0.f;
        #pragma unroll
        for (int q = 0; q < 4; ++q) { v[q] -= mu; var += v[q] * v[q]; }
        #pragma unroll
        for (int m = 1; m < 64; m <<= 1) var += __shfl_xor(var, m);
        float rstd = rsqrtf(var * (1.0f / HH) + 1e-5f);
        #pragma unroll
        for (int q = 0; q < 4; ++q) {
            int k = lane + 64 * q;
            float hv = v[q] * rstd * g[k] + bta[k];
            shnT[k][wv] = hv;
            hn[row * HH + k] = hv;
        }
    }
    __syncthreads();

    float ai0 = eb1l[tid], ai1 = ai0;
    float aj0 = 0.f, aj1 = 0.f;
    for (int c2 = 0; c2 < 128; ++c2) {
        unsigned int wip = ew1w[c2 * 256 + tid];
        unsigned int wjp = ew1w[(128 + c2) * 256 + tid];
        float4 s = *(const float4*)&shnT[c2 * 2][0];
        ai0 += s.x * bflo(wip) + s.z * bfhi(wip);
        ai1 += s.y * bflo(wip) + s.w * bfhi(wip);
        aj0 += s.x * bflo(wjp) + s.z * bfhi(wjp);
        aj1 += s.y * bflo(wjp) + s.w * bfhi(wjp);
    }
    Ai[(base + 0) * HH + tid] = ai0; AjB[(base + 0) * HH + tid] = f2bf(aj0);
    Ai[(base + 1) * HH + tid] = ai1; AjB[(base + 1) * HH + tid] = f2bf(aj1);
}

// ---------------------------------------------------------------- fused edge + node update + next-layer LN/Ai/Aj
// 2 ROWS PER BLOCK (grid 256 = 1 block/CU, single block-wave): the main edge
// loop runs twice with the SAME resident B-fragments, and the tail processes
// both rows with the old k_node_ln's 2-row interleaved-broadcast GEMV —
// halving tail weight traffic vs round 16 and removing the 2nd block-wave.
// Ping-pong x/Ai/AjB for race safety; h/hn rows are block-local.
// __launch_bounds__(512, 1): arg2 is min BLOCKS/CU on hipcc; >=2 caps
// regalloc and spills when working set >128 VGPR (rounds 2-5, 8). DO NOT raise.
__global__ __launch_bounds__(512, 1) void k_edge(
    const float* __restrict__ x, const float* __restrict__ Ai, const unsigned short* __restrict__ AjB,
    const float* __restrict__ wd, const float* __restrict__ eb2v,
    const unsigned short* __restrict__ ew2P, const unsigned short* __restrict__ cw1P,
    const float* __restrict__ cb1v, const float* __restrict__ cw2v, const float* __restrict__ cb2p,
    float* __restrict__ h, float* __restrict__ hn,
    float* __restrict__ xnext, float* __restrict__ Ainext, unsigned short* __restrict__ AjBnext,
    const unsigned int* __restrict__ nw1w, const float* __restrict__ nb1l,
    const unsigned int* __restrict__ nw2w, const float* __restrict__ nb2l,
    const float* __restrict__ gamv, const float* __restrict__ betv,
    const unsigned int* __restrict__ ew1wn, const float* __restrict__ eb1n,
    int has_ln) {
    __shared__ float srel[128][3];
    __shared__ float sd2[128];
    __shared__ float cwpart[8][128];
    __shared__ float smagg2[2][256];
    __shared__ __attribute__((aligned(16))) char s_tile[128 * SROWB];  // 67.6KB (tail reuses)
    __shared__ __attribute__((aligned(16))) char m_tile[128 * SROWB];  // 67.6KB

    int tid = threadIdx.x, wv = tid >> 6, lane = tid & 63;
    int g4 = lane >> 4, l15 = lane & 15;
    int colbase = wv * 32;
    int ni0 = blockIdx.x * 2;
    int ni1 = ni0 + 1;
    int b = ni0 >> 8;
    int bbase = b * NN;
    int bthr = ((wv << 7) + lane) << 3;
    int k0p = (tid & 31) << 3;

    float wdv[8];
    {
        float4v w0 = *(const float4v*)(wd + k0p);
        float4v w1 = *(const float4v*)(wd + k0p + 4);
        #pragma unroll
        for (int e = 0; e < 4; ++e) { wdv[e] = w0[e]; wdv[4 + e] = w1[e]; }
    }
    float eb2r[2], cb1r[2], cw2r[2];
    #pragma unroll
    for (int ct = 0; ct < 2; ++ct) {
        int col = colbase + ct * 16 + l15;
        eb2r[ct] = eb2v[col]; cb1r[ct] = cb1v[col]; cw2r[ct] = cw2v[col];
    }
    float cb2 = cb2p[0];

    bf16x8 Bew[8][2], Bcw[8][2];
    #pragma unroll
    for (int ks = 0; ks < 8; ++ks) {
        #pragma unroll
        for (int ct = 0; ct < 2; ++ct) {
            Bew[ks][ct] = *(const bf16x8*)(ew2P + (ks << 13) + (ct << 9) + bthr);
            Bcw[ks][ct] = *(const bf16x8*)(cw1P + (ks << 13) + (ct << 9) + bthr);
        }
    }

    char* p1w = s_tile + ((tid >> 5) * SROWB + k0p * 2);
    const char* aA = s_tile + (l15 * SROWB + g4 * 16);
    const char* aM = m_tile + (l15 * SROWB + g4 * 16);
    char* mwA = m_tile + ((g4 * 4) * SROWB + (colbase + l15) * 2);

    #pragma unroll 1
    for (int ir = 0; ir < 2; ++ir) {
        int ni = ni0 + ir;
        float aiv[8];
        {
            float4v a0 = *(const float4v*)(Ai + (size_t)ni * HH + k0p);
            float4v a1 = *(const float4v*)(Ai + (size_t)ni * HH + k0p + 4);
            #pragma unroll
            for (int e = 0; e < 4; ++e) { aiv[e] = a0[e]; aiv[4 + e] = a1[e]; }
        }
        float xi0 = x[ni * 3 + 0], xi1 = x[ni * 3 + 1], xi2 = x[ni * 3 + 2];
        float mgv[2] = {0.f, 0.f};
        float xd0 = 0.f, xd1 = 0.f, xd2 = 0.f;

        #pragma unroll 1
        for (int jc = 0; jc < 2; ++jc) {
            int j0 = jc * 128;
            __syncthreads();
            if (tid < 128) {
                int j = bbase + j0 + tid;
                float rx = xi0 - x[j * 3 + 0];
                float ry = xi1 - x[j * 3 + 1];
                float rz = xi2 - x[j * 3 + 2];
                srel[tid][0] = rx; srel[tid][1] = ry; srel[tid][2] = rz;
                sd2[tid] = rx * rx + ry * ry + rz * rz;
            }
            __syncthreads();

            // ---- phase 1
            #pragma unroll
            for (int it = 0; it < 8; ++it) {
                int row = it * 16 + (tid >> 5);
                float d2v = sd2[row];
                u32x4 ajw = *(const u32x4*)(AjB + ((size_t)(bbase + j0 + row) * HH + k0p));
                unsigned int uw0, uw1, uw2, uw3;
                uw0 = cvtpk(fsilu(aiv[0] + bflo(ajw[0]) + d2v * wdv[0]), fsilu(aiv[1] + bfhi(ajw[0]) + d2v * wdv[1]));
                uw1 = cvtpk(fsilu(aiv[2] + bflo(ajw[1]) + d2v * wdv[2]), fsilu(aiv[3] + bfhi(ajw[1]) + d2v * wdv[3]));
                uw2 = cvtpk(fsilu(aiv[4] + bflo(ajw[2]) + d2v * wdv[4]), fsilu(aiv[5] + bfhi(ajw[2]) + d2v * wdv[5]));
                uw3 = cvtpk(fsilu(aiv[6] + bflo(ajw[3]) + d2v * wdv[6]), fsilu(aiv[7] + bfhi(ajw[3]) + d2v * wdv[7]));
                u32x4 sv = {uw0, uw1, uw2, uw3};
                *reinterpret_cast<u32x4*>(p1w + it * 16 * SROWB) = sv;
            }
            __syncthreads();

            // ---- phase 2
            #pragma unroll 1
            for (int rh = 0; rh < 4; ++rh) {
                f32x4 acc[2][2];
                acc[0][0] = (f32x4){0.f,0.f,0.f,0.f}; acc[0][1] = (f32x4){0.f,0.f,0.f,0.f};
                acc[1][0] = (f32x4){0.f,0.f,0.f,0.f}; acc[1][1] = (f32x4){0.f,0.f,0.f,0.f};
                const char* aBase = aA + rh * 32 * SROWB;
                #pragma unroll
                for (int ks = 0; ks < 8; ++ks) {
                    bf16x8 a0 = *reinterpret_cast<const bf16x8*>(aBase + ks * 64);
                    bf16x8 a1 = *reinterpret_cast<const bf16x8*>(aBase + 16 * SROWB + ks * 64);
                    acc[0][0] = __builtin_amdgcn_mfma_f32_16x16x32_bf16(a0, Bew[ks][0], acc[0][0], 0, 0, 0);
                    acc[0][1] = __builtin_amdgcn_mfma_f32_16x16x32_bf16(a0, Bew[ks][1], acc[0][1], 0, 0, 0);
                    acc[1][0] = __builtin_amdgcn_mfma_f32_16x16x32_bf16(a1, Bew[ks][0], acc[1][0], 0, 0, 0);
                    acc[1][1] = __builtin_amdgcn_mfma_f32_16x16x32_bf16(a1, Bew[ks][1], acc[1][1], 0, 0, 0);
                }
                char* mw = mwA + rh * 32 * SROWB;
                #pragma unroll
                for (int rt = 0; rt < 2; ++rt) {
                    #pragma unroll
                    for (int r = 0; r < 4; ++r) {
                        float v0 = fsilu(acc[rt][0][r] + eb2r[0]);
                        float v1 = fsilu(acc[rt][1][r] + eb2r[1]);
                        mgv[0] += v0; mgv[1] += v1;
                        unsigned int w = cvtpk(v0, v1);
                        char* p = mw + (rt * 16 + r) * SROWB;
                        *reinterpret_cast<unsigned short*>(p) = (unsigned short)w;
                        *reinterpret_cast<unsigned short*>(p + 32) = (unsigned short)(w >> 16);
                    }
                }
            }
            __syncthreads();

            // ---- phase 3
            #pragma unroll 1
            for (int rh = 0; rh < 4; ++rh) {
                f32x4 acc[2][2];
                acc[0][0] = (f32x4){0.f,0.f,0.f,0.f}; acc[0][1] = (f32x4){0.f,0.f,0.f,0.f};
                acc[1][0] = (f32x4){0.f,0.f,0.f,0.f}; acc[1][1] = (f32x4){0.f,0.f,0.f,0.f};
                const char* aBase = aM + rh * 32 * SROWB;
                #pragma unroll
                for (int ks = 0; ks < 8; ++ks) {
                    bf16x8 a0 = *reinterpret_cast<const bf16x8*>(aBase + ks * 64);
                    bf16x8 a1 = *reinterpret_cast<const bf16x8*>(aBase + 16 * SROWB + ks * 64);
                    acc[0][0] = __builtin_amdgcn_mfma_f32_16x16x32_bf16(a0, Bcw[ks][0], acc[0][0], 0, 0, 0);
                    acc[0][1] = __builtin_amdgcn_mfma_f32_16x16x32_bf16(a0, Bcw[ks][1], acc[0][1], 0, 0, 0);
                    acc[1][0] = __builtin_amdgcn_mfma_f32_16x16x32_bf16(a1, Bcw[ks][0], acc[1][0], 0, 0, 0);
                    acc[1][1] = __builtin_amdgcn_mfma_f32_16x16x32_bf16(a1, Bcw[ks][1], acc[1][1], 0, 0, 0);
                }
                float rs[8];
                #pragma unroll
                for (int q = 0; q < 8; ++q) rs[q] = 0.f;
                #pragma unroll
                for (int ct = 0; ct < 2; ++ct) {
                    #pragma unroll
                    for (int rt = 0; rt < 2; ++rt)
                        #pragma unroll
                        for (int r = 0; r < 4; ++r)
                            rs[rt * 4 + r] += fsilu(acc[rt][ct][r] + cb1r[ct]) * cw2r[ct];
                }
                #pragma unroll
                for (int m = 1; m <= 8; m <<= 1)
                    #pragma unroll
                    for (int q = 0; q < 8; ++q) rs[q] += __shfl_xor(rs[q], m);
                if (l15 == 0) {
                    #pragma unroll
                    for (int rt = 0; rt < 2; ++rt)
                        #pragma unroll
                        for (int r = 0; r < 4; ++r)
                            cwpart[wv][rh * 32 + rt * 16 + g4 * 4 + r] = rs[rt * 4 + r];
                }
            }
            __syncthreads();
            if (tid < 64) {
                #pragma unroll 1
                for (int q = 0; q < 2; ++q) {
                    int lr = q * 64 + tid;
                    float cwv = cb2;
                    #pragma unroll
                    for (int w = 0; w < 8; ++w) cwv += cwpart[w][lr];
                    float p0 = srel[lr][0] * cwv;
                    float p1 = srel[lr][1] * cwv;
                    float p2 = srel[lr][2] * cwv;
                    #pragma unroll
                    for (int m = 1; m < 64; m <<= 1) {
                        p0 += __shfl_xor(p0, m); p1 += __shfl_xor(p1, m); p2 += __shfl_xor(p2, m);
                    }
                    xd0 += p0; xd1 += p1; xd2 += p2;
                }
            }
        }

        // per-row epilogue: magg -> LDS, x update -> ping-pong
        #pragma unroll
        for (int ct = 0; ct < 2; ++ct) {
            mgv[ct] += __shfl_xor(mgv[ct], 16);
            mgv[ct] += __shfl_xor(mgv[ct], 32);
        }
        if (lane < 16) {
            smagg2[ir][colbase + lane] = mgv[0];
            smagg2[ir][colbase + 16 + lane] = mgv[1];
        }
        if (has_ln && tid == 0) {
            xnext[ni * 3 + 0] = xi0 + xd0 * (1.0f / NN);
            xnext[ni * 3 + 1] = xi1 + xd1 * (1.0f / NN);
            xnext[ni * 3 + 2] = xi2 + xd2 * (1.0f / NN);
        }
    }
    __syncthreads();

    // ================= 2-row fused tail =================
    float* s2T   = (float*)s_tile;            // [512][2]
    float* part0 = (float*)(s_tile + 4096);   // [512]
    float* part1 = (float*)(s_tile + 6144);   // [512]
    float* suT   = (float*)(s_tile + 8192);   // [256][2]
    float* shrow = (float*)(s_tile + 10240);  // [256][2]
    float* shnT  = (float*)(s_tile + 12288);  // [256][2]

    if (tid < 256) {
        s2T[tid * 2 + 0] = hn[(size_t)ni0 * HH + tid];
        s2T[tid * 2 + 1] = hn[(size_t)ni1 * HH + tid];
        s2T[(HH + tid) * 2 + 0] = smagg2[0][tid];
        s2T[(HH + tid) * 2 + 1] = smagg2[1][tid];
    }
    __syncthreads();
    {   // u = silu(nw1 . [hn;magg] + nb1), col x k-half split
        int col = tid & 255, kh = tid >> 8;
        const unsigned int* w = nw1w + (kh * 128) * 256;
        const float* sv = s2T + kh * 512;
        float p0 = 0.f, p1 = 0.f;
        for (int c2 = 0; c2 < 128; ++c2) {
            unsigned int wp = w[c2 * 256 + col];
            float4 sp = *(const float4*)&sv[c2 * 4];
            p0 += sp.x * bflo(wp) + sp.z * bfhi(wp);
            p1 += sp.y * bflo(wp) + sp.w * bfhi(wp);
        }
        part0[tid] = p0; part1[tid] = p1;
    }
    __syncthreads();
    if (tid < 256) {
        float bb = nb1l[tid];
        suT[tid * 2 + 0] = fsilu(part0[tid] + part0[256 + tid] + bb);
        suT[tid * 2 + 1] = fsilu(part1[tid] + part1[256 + tid] + bb);
    }
    __syncthreads();
    {   // d = nw2 . u + nb2
        int col = tid & 255, kh = tid >> 8;
        const unsigned int* w = nw2w + (kh * 64) * 256;
        const float* sv = suT + kh * 256;
        float p0 = 0.f, p1 = 0.f;
        for (int c2 = 0; c2 < 64; ++c2) {
            unsigned int wp = w[c2 * 256 + col];
            float4 sp = *(const float4*)&sv[c2 * 4];
            p0 += sp.x * bflo(wp) + sp.z * bfhi(wp);
            p1 += sp.y * bflo(wp) + sp.w * bfhi(wp);
        }
        part0[tid] = p0; part1[tid] = p1;
    }
    __syncthreads();
    if (tid < 256) {
        float bb = nb2l[tid];
        float h0v = h[(size_t)ni0 * HH + tid] + part0[tid] + part0[256 + tid] + bb;
        float h1v = h[(size_t)ni1 * HH + tid] + part1[tid] + part1[256 + tid] + bb;
        h[(size_t)ni0 * HH + tid] = h0v;
        h[(size_t)ni1 * HH + tid] = h1v;
        shrow[tid * 2 + 0] = h0v;
        shrow[tid * 2 + 1] = h1v;
    }
    __syncthreads();
    if (!has_ln) return;

    if (wv < 2) {  // LN per row (wave wv handles row wv)
        float v[4];
        #pragma unroll
        for (int q = 0; q < 4; ++q) v[q] = shrow[(lane + 64 * q) * 2 + wv];
        float s = v[0] + v[1] + v[2] + v[3];
        #pragma unroll
        for (int m = 1; m < 64; m <<= 1) s += __shfl_xor(s, m);
        float mu = s * (1.0f / HH);
        float var = 0.f;
        #pragma unroll
        for (int q = 0; q < 4; ++q) { v[q] -= mu; var += v[q] * v[q]; }
        #pragma unroll
        for (int m = 1; m < 64; m <<= 1) var += __shfl_xor(var, m);
        float rstd = rsqrtf(var * (1.0f / HH) + 1e-5f);
        #pragma unroll
        for (int q = 0; q < 4; ++q) {
            int k = lane + 64 * q;
            float hv = v[q] * rstd * gamv[k] + betv[k];
            shnT[k * 2 + wv] = hv;
            hn[(size_t)(ni0 + wv) * HH + k] = hv;
        }
    }
    __syncthreads();
    {   // next-layer Ai (hf 0) / Aj (hf 1), both rows
        int col = tid & 255, hf = tid >> 8;
        const unsigned int* w = ew1wn + (hf * 128) * 256;
        float p0 = (hf == 0) ? eb1n[col] : 0.f;
        float p1 = p0;
        for (int c2 = 0; c2 < 128; ++c2) {
            unsigned int wp = w[c2 * 256 + col];
            float4 sp = *(const float4*)&shnT[c2 * 4];
            p0 += sp.x * bflo(wp) + sp.z * bfhi(wp);
            p1 += sp.y * bflo(wp) + sp.w * bfhi(wp);
        }
        if (hf == 0) {
            Ainext[(size_t)ni0 * HH + col] = p0;
            Ainext[(size_t)ni1 * HH + col] = p1;
        } else {
            AjBnext[(size_t)ni0 * HH + col] = f2bf(p0);
            AjBnext[(size_t)ni1 * HH + col] = f2bf(p1);
        }
    }
}

// ---------------------------------------------------------------- decoder (2 rows/block)
__global__ __launch_bounds__(256) void k_decoder(
    const float* __restrict__ h,
    const float* __restrict__ dw1, const float* __restrict__ db1,
    const float* __restrict__ dw2, const float* __restrict__ db2,
    const float* __restrict__ dw3, const float* __restrict__ db3,
    float* __restrict__ out) {
    __shared__ float shT[HH][2];
    __shared__ float so1T[HH][2];
    __shared__ float so2T[HH][2];
    int tid = threadIdx.x;
    int base = blockIdx.x * 2;
    #pragma unroll
    for (int r = 0; r < 2; ++r) shT[tid][r] = h[(base + r) * HH + tid];
    __syncthreads();
    float a0 = db1[tid], a1 = a0;
    for (int c = 0; c < HH; ++c) {
        float w = dw1[c * HH + tid];
        float2 s = *(const float2*)&shT[c][0];
        a0 += s.x * w; a1 += s.y * w;
    }
    so1T[tid][0] = fmaxf(a0, 0.f); so1T[tid][1] = fmaxf(a1, 0.f);
    __syncthreads();
    a0 = db2[tid]; a1 = a0;
    for (int c = 0; c < HH; ++c) {
        float w = dw2[c * HH + tid];
        float2 s = *(const float2*)&so1T[c][0];
        a0 += s.x * w; a1 += s.y * w;
    }
    so2T[tid][0] = fmaxf(a0, 0.f) + shT[tid][0];
    so2T[tid][1] = fmaxf(a1, 0.f) + shT[tid][1];
    __syncthreads();
    if (tid < 6) {
        int r = tid / 3, c = tid % 3;
        float acc = db3[c];
        for (int k = 0; k < HH; ++k) acc += so2T[k][r] * dw3[k * 3 + c];
        out[(base + r) * 3 + c] = acc;
    }
}

// ---------------------------------------------------------------- launch
extern "C" void kernel_launch(void* const* d_in, const int* in_sizes, int n_in,
                              void* d_out, int out_size, void* d_ws, size_t ws_size,
                              hipStream_t stream) {
    const float* coords = (const float*)d_in[0];
    const float* feats  = (const float*)d_in[1];
    const float* t      = (const float*)d_in[2];
    const float* pe_w1  = (const float*)d_in[3];  const float* pe_b1 = (const float*)d_in[4];
    const float* pe_w2  = (const float*)d_in[5];  const float* pe_b2 = (const float*)d_in[6];
    const float* pe_w3  = (const float*)d_in[7];  const float* pe_b3 = (const float*)d_in[8];
    const float* te_w1  = (const float*)d_in[9];  const float* te_b1 = (const float*)d_in[10];
    const float* te_w2  = (const float*)d_in[11]; const float* te_b2 = (const float*)d_in[12];
    const float* ln_g   = (const float*)d_in[13]; const float* ln_b  = (const float*)d_in[14];
    const float* ew1    = (const float*)d_in[15]; const float* eb1   = (const float*)d_in[16];
    const float* ew2    = (const float*)d_in[17]; const float* eb2   = (const float*)d_in[18];
    const float* cw1    = (const float*)d_in[19]; const float* cb1   = (const float*)d_in[20];
    const float* cw2    = (const float*)d_in[21]; const float* cb2   = (const float*)d_in[22];
    const float* nw1    = (const float*)d_in[23]; const float* nb1   = (const float*)d_in[24];
    const float* nw2    = (const float*)d_in[25]; const float* nb2   = (const float*)d_in[26];
    const float* dec_w1 = (const float*)d_in[27]; const float* dec_b1 = (const float*)d_in[28];
    const float* dec_w2 = (const float*)d_in[29]; const float* dec_b2 = (const float*)d_in[30];
    const float* dec_w3 = (const float*)d_in[31]; const float* dec_b3 = (const float*)d_in[32];

    float* ws = (float*)d_ws;
    float* h    = ws;
    float* hn   = ws + RN;
    float* Ai0  = ws + 2 * RN;
    float* Ai1  = ws + 3 * RN;
    float* xb0  = ws + 4 * RN;              // 1536 (reserve 2048)
    float* xb1  = ws + 4 * RN + 2048;       // 1536 (reserve 2048)
    unsigned short* Aj0  = (unsigned short*)(ws + 4 * RN + 4096);
    unsigned short* Aj1  = Aj0 + RN;
    unsigned short* ew2P = Aj1 + RN;                       // LL*65536
    unsigned short* cw1P = ew2P + LL * HH * HH;            // LL*65536
    unsigned short* nw1B = cw1P + LL * HH * HH;            // LL*131072
    unsigned short* ew1B = nw1B + LL * 2 * HH * HH;        // LL*131072
    unsigned short* nw2B = ew1B + LL * 2 * HH * HH;        // LL*65536

    k_convert<<<(LL * 8192 + 511) / 512, 512, 0, stream>>>(ew2, cw1, ew2P, cw1P);
    k_convert2<<<(LL * 131072 + 255) / 256, 256, 0, stream>>>(nw1, nw2, ew1, nw1B, nw2B, ew1B);
    k_encoder<<<NB * NN / 2, 256, 0, stream>>>(coords, feats, t,
        pe_w1, pe_b1, pe_w2, pe_b2, pe_w3, pe_b3, te_w1, te_b1, te_w2, te_b2, h, xb0);
    k_ln_aiaj<<<NB * NN / 2, 256, 0, stream>>>(h, ln_g, ln_b,
        (const unsigned int*)ew1B, eb1, hn, Ai0, Aj0);

    for (int l = 0; l < LL; ++l) {
        const float* xin = (l & 1) ? xb1 : xb0;
        float* xout      = (l & 1) ? xb0 : xb1;
        const float* AiIn = (l & 1) ? Ai1 : Ai0;
        float* AiOut      = (l & 1) ? Ai0 : Ai1;
        const unsigned short* AjIn = (l & 1) ? Aj1 : Aj0;
        unsigned short* AjOut      = (l & 1) ? Aj0 : Aj1;
        int ln = (l + 1 < LL) ? (l + 1) : LL - 1;  // tail params unused when has_ln=0
        k_edge<<<NB * NN / 2, 512, 0, stream>>>(xin, AiIn, AjIn,
            ew1 + ((size_t)l * 513 + 512) * HH, eb2 + l * HH,
            ew2P + (size_t)l * HH * HH, cw1P + (size_t)l * HH * HH,
            cb1 + l * HH, cw2 + l * HH, cb2 + l,
            h, hn, xout, AiOut, AjOut,
            (const unsigned int*)(nw1B + (size_t)l * 2 * HH * HH), nb1 + l * HH,
            (const unsigned int*)(nw2B + (size_t)l * HH * HH), nb2 + l * HH,
            ln_g + ln * HH, ln_b + ln * HH,
            (const unsigned int*)(ew1B + (size_t)ln * 2 * HH * HH), eb1 + ln * HH,
            (l + 1 < LL) ? 1 : 0);
    }

    k_decoder<<<NB * NN / 2, 256, 0, stream>>>(h, dec_w1, dec_b1, dec_w2, dec_b2,
                                               dec_w3, dec_b3, (float*)d_out);
}

// Round 18
// 513.991 us; speedup vs baseline: 1.4018x; 1.0023x over previous
//
#include <hip/hip_runtime.h>
#include <math.h>

static constexpr int NB = 2, NN = 256, HH = 256, DD = 64, LL = 6;
static constexpr int RN = NB * NN * HH;  // 131072
static constexpr int SROWB = 528;        // padded LDS row stride (bytes): 2-way banks, imm-foldable

typedef __attribute__((ext_vector_type(8))) short bf16x8;
typedef __attribute__((ext_vector_type(4))) float f32x4;
typedef __attribute__((ext_vector_type(4))) float float4v;
typedef __attribute__((ext_vector_type(4))) unsigned int u32x4;

__device__ __forceinline__ float fsilu(float v) {
    return v * __builtin_amdgcn_rcpf(1.0f + __expf(-v));
}
__device__ __forceinline__ unsigned short f2bf(float f) {
    union { float f; unsigned int u; } x; x.f = f;
    unsigned int r = x.u + 0x7fffu + ((x.u >> 16) & 1u);
    return (unsigned short)(r >> 16);
}
__device__ __forceinline__ float bitsf(unsigned int u) {
    union { float f; unsigned int u; } x; x.u = u; return x.f;
}
__device__ __forceinline__ float bflo(unsigned int w) { return bitsf(w << 16); }
__device__ __forceinline__ float bfhi(unsigned int w) { return bitsf(w & 0xffff0000u); }
__device__ __forceinline__ unsigned int cvtpk(float lo, float hi) {
    unsigned int w;
    asm("v_cvt_pk_bf16_f32 %0, %1, %2" : "=v"(w) : "v"(lo), "v"(hi));
    return w;
}

// ---------------------------------------------------------------- convert (edge fragment-packed)
__global__ void k_convert(const float* __restrict__ ew2, const float* __restrict__ cw1,
                          unsigned short* __restrict__ ew2P, unsigned short* __restrict__ cw1P) {
    int g = blockIdx.x * blockDim.x + threadIdx.x;
    if (g >= LL * 8192) return;
    int l = g >> 13;
    int r = g & 8191;
    int lane = r & 63;
    int fidx = r >> 6;
    int ks = fidx >> 4;
    int wv = (fidx >> 1) & 7;
    int ct = fidx & 1;
    int col = wv * 32 + ct * 16 + (lane & 15);
    int k0 = ks * 32 + (lane >> 4) * 8;
    #pragma unroll
    for (int e = 0; e < 8; ++e) {
        ew2P[(size_t)g * 8 + e] = f2bf(ew2[((size_t)l * HH + k0 + e) * HH + col]);
        cw1P[(size_t)g * 8 + e] = f2bf(cw1[((size_t)l * HH + k0 + e) * HH + col]);
    }
}

// ---------------------------------------------------------------- convert2 (bf16 pair-packed GEMV weights)
__global__ void k_convert2(const float* __restrict__ nw1, const float* __restrict__ nw2,
                           const float* __restrict__ ew1,
                           unsigned short* __restrict__ nw1B, unsigned short* __restrict__ nw2B,
                           unsigned short* __restrict__ ew1B) {
    int idx = blockIdx.x * blockDim.x + threadIdx.x;
    if (idx >= LL * 131072) return;
    int l = idx >> 17;
    int r = idx & 131071;
    int c = r >> 8, col = r & 255;
    int dst = (l << 17) + ((c >> 1) << 9) + (col << 1) + (c & 1);
    nw1B[dst] = f2bf(nw1[(size_t)l * 131072 + c * 256 + col]);
    ew1B[dst] = f2bf(ew1[(size_t)l * 131328 + c * 256 + col]);  // 513*256 stride
    if (r < 65536) {
        int d2 = (l << 16) + ((c >> 1) << 9) + (col << 1) + (c & 1);
        nw2B[d2] = f2bf(nw2[(size_t)l * 65536 + c * 256 + col]);
    }
}

// ---------------------------------------------------------------- encoder (2 rows/block, broadcast staging)
__global__ __launch_bounds__(256) void k_encoder(
    const float* __restrict__ coords, const float* __restrict__ feats, const float* __restrict__ t,
    const float* __restrict__ pw1, const float* __restrict__ pb1,
    const float* __restrict__ pw2, const float* __restrict__ pb2,
    const float* __restrict__ pw3, const float* __restrict__ pb3,
    const float* __restrict__ tw1, const float* __restrict__ tb1,
    const float* __restrict__ tw2, const float* __restrict__ tb2,
    float* __restrict__ h, float* __restrict__ x) {
    __shared__ float spinT[68][2];
    __shared__ float shaT[HH][2];
    __shared__ float shbT[HH][2];
    __shared__ float ste1[HH];
    int tid = threadIdx.x;
    int base = blockIdx.x * 2;
    int b = base / NN;

    #pragma unroll
    for (int r = 0; r < 2; ++r) {
        int row = base + r;
        if (tid < 3) spinT[tid][r] = coords[row * 3 + tid];
        if (tid < DD) spinT[3 + tid][r] = feats[row * DD + tid];
    }
    float tv = t[b];
    ste1[tid] = fmaxf(tv * tw1[tid] + tb1[tid], 0.0f);
    if (tid < 6) {
        int r = tid / 3, c = tid % 3;
        x[(base + r) * 3 + c] = coords[(base + r) * 3 + c];
    }
    __syncthreads();

    float a0 = pb1[tid], a1 = a0;
    for (int c = 0; c < 67; ++c) {
        float w = pw1[c * HH + tid];
        float2 s = *(const float2*)&spinT[c][0];
        a0 += s.x * w; a1 += s.y * w;
    }
    shaT[tid][0] = fmaxf(a0, 0.f); shaT[tid][1] = fmaxf(a1, 0.f);
    __syncthreads();
    a0 = pb2[tid]; a1 = a0;
    for (int c = 0; c < HH; ++c) {
        float w = pw2[c * HH + tid];
        float2 s = *(const float2*)&shaT[c][0];
        a0 += s.x * w; a1 += s.y * w;
    }
    shbT[tid][0] = fmaxf(a0, 0.f); shbT[tid][1] = fmaxf(a1, 0.f);
    __syncthreads();
    a0 = pb3[tid]; a1 = a0;
    float te = tb2[tid];
    for (int c = 0; c < HH; ++c) {
        float w = pw3[c * HH + tid];
        float2 s = *(const float2*)&shbT[c][0];
        a0 += s.x * w; a1 += s.y * w;
        te += ste1[c] * tw2[c * HH + tid];
    }
    h[(base + 0) * HH + tid] = fmaxf(a0, 0.f) + te;
    h[(base + 1) * HH + tid] = fmaxf(a1, 0.f) + te;
}

// ---------------------------------------------------------------- LayerNorm + Ai/Aj (layer 0; bf16 ew1)
__global__ __launch_bounds__(256) void k_ln_aiaj(
    const float* __restrict__ h, const float* __restrict__ g, const float* __restrict__ bta,
    const unsigned int* __restrict__ ew1w, const float* __restrict__ eb1l,
    float* __restrict__ hn, float* __restrict__ Ai, unsigned short* __restrict__ AjB) {
    __shared__ float shnT[HH][2];
    int tid = threadIdx.x, wv = tid >> 6, lane = tid & 63;
    int base = blockIdx.x * 2;

    if (wv < 2) {
        int row = base + wv;
        float v[4];
        #pragma unroll
        for (int q = 0; q < 4; ++q) v[q] = h[row * HH + lane + 64 * q];
        float s = v[0] + v[1] + v[2] + v[3];
        #pragma unroll
        for (int m = 1; m < 64; m <<= 1) s += __shfl_xor(s, m);
        float mu = s * (1.0f / HH);
        float var = 0.f;
        #pragma unroll
        for (int q = 0; q < 4; ++q) { v[q] -= mu; var += v[q] * v[q]; }
        #pragma unroll
        for (int m = 1; m < 64; m <<= 1) var += __shfl_xor(var, m);
        float rstd = rsqrtf(var * (1.0f / HH) + 1e-5f);
        #pragma unroll
        for (int q = 0; q < 4; ++q) {
            int k = lane + 64 * q;
            float hv = v[q] * rstd * g[k] + bta[k];
            shnT[k][wv] = hv;
            hn[row * HH + k] = hv;
        }
    }
    __syncthreads();

    float ai0a = eb1l[tid], ai1a = ai0a, ai0b = 0.f, ai1b = 0.f;
    float aj0a = 0.f, aj1a = 0.f, aj0b = 0.f, aj1b = 0.f;
    #pragma unroll 4
    for (int c2 = 0; c2 < 128; c2 += 2) {
        unsigned int wipA = ew1w[c2 * 256 + tid];
        unsigned int wjpA = ew1w[(128 + c2) * 256 + tid];
        unsigned int wipB = ew1w[(c2 + 1) * 256 + tid];
        unsigned int wjpB = ew1w[(129 + c2) * 256 + tid];
        float4 sA = *(const float4*)&shnT[c2 * 2][0];
        float4 sB = *(const float4*)&shnT[c2 * 2 + 2][0];
        ai0a += sA.x * bflo(wipA) + sA.z * bfhi(wipA);
        ai1a += sA.y * bflo(wipA) + sA.w * bfhi(wipA);
        aj0a += sA.x * bflo(wjpA) + sA.z * bfhi(wjpA);
        aj1a += sA.y * bflo(wjpA) + sA.w * bfhi(wjpA);
        ai0b += sB.x * bflo(wipB) + sB.z * bfhi(wipB);
        ai1b += sB.y * bflo(wipB) + sB.w * bfhi(wipB);
        aj0b += sB.x * bflo(wjpB) + sB.z * bfhi(wjpB);
        aj1b += sB.y * bflo(wjpB) + sB.w * bfhi(wjpB);
    }
    Ai[(base + 0) * HH + tid] = ai0a + ai0b; AjB[(base + 0) * HH + tid] = f2bf(aj0a + aj0b);
    Ai[(base + 1) * HH + tid] = ai1a + ai1b; AjB[(base + 1) * HH + tid] = f2bf(aj1a + aj1b);
}

// ---------------------------------------------------------------- fused edge + node update + next-layer LN/Ai/Aj
// Round-17 2-rows/block structure with: (a) srel/sd2 staging removed — d2
// computed inline from L2-resident x (kills 1 single-wave phase + 1 barrier
// per jc); (b) tail GEMVs use dual accumulators + unroll to break the
// dependent-FMA chain that made the tail latency-bound (~20us vs ~6us BW).
// __launch_bounds__(512, 1): arg2 is min BLOCKS/CU on hipcc; >=2 caps
// regalloc and spills when working set >128 VGPR (rounds 2-5, 8). DO NOT raise.
__global__ __launch_bounds__(512, 1) void k_edge(
    const float* __restrict__ x, const float* __restrict__ Ai, const unsigned short* __restrict__ AjB,
    const float* __restrict__ wd, const float* __restrict__ eb2v,
    const unsigned short* __restrict__ ew2P, const unsigned short* __restrict__ cw1P,
    const float* __restrict__ cb1v, const float* __restrict__ cw2v, const float* __restrict__ cb2p,
    float* __restrict__ h, float* __restrict__ hn,
    float* __restrict__ xnext, float* __restrict__ Ainext, unsigned short* __restrict__ AjBnext,
    const unsigned int* __restrict__ nw1w, const float* __restrict__ nb1l,
    const unsigned int* __restrict__ nw2w, const float* __restrict__ nb2l,
    const float* __restrict__ gamv, const float* __restrict__ betv,
    const unsigned int* __restrict__ ew1wn, const float* __restrict__ eb1n,
    int has_ln) {
    __shared__ float cwpart[8][128];
    __shared__ float smagg2[2][256];
    __shared__ __attribute__((aligned(16))) char s_tile[128 * SROWB];  // 67.6KB (tail reuses)
    __shared__ __attribute__((aligned(16))) char m_tile[128 * SROWB];  // 67.6KB

    int tid = threadIdx.x, wv = tid >> 6, lane = tid & 63;
    int g4 = lane >> 4, l15 = lane & 15;
    int colbase = wv * 32;
    int ni0 = blockIdx.x * 2;
    int ni1 = ni0 + 1;
    int b = ni0 >> 8;
    int bbase = b * NN;
    int bthr = ((wv << 7) + lane) << 3;
    int k0p = (tid & 31) << 3;

    float wdv[8];
    {
        float4v w0 = *(const float4v*)(wd + k0p);
        float4v w1 = *(const float4v*)(wd + k0p + 4);
        #pragma unroll
        for (int e = 0; e < 4; ++e) { wdv[e] = w0[e]; wdv[4 + e] = w1[e]; }
    }
    float eb2r[2], cb1r[2], cw2r[2];
    #pragma unroll
    for (int ct = 0; ct < 2; ++ct) {
        int col = colbase + ct * 16 + l15;
        eb2r[ct] = eb2v[col]; cb1r[ct] = cb1v[col]; cw2r[ct] = cw2v[col];
    }
    float cb2 = cb2p[0];

    bf16x8 Bew[8][2], Bcw[8][2];
    #pragma unroll
    for (int ks = 0; ks < 8; ++ks) {
        #pragma unroll
        for (int ct = 0; ct < 2; ++ct) {
            Bew[ks][ct] = *(const bf16x8*)(ew2P + (ks << 13) + (ct << 9) + bthr);
            Bcw[ks][ct] = *(const bf16x8*)(cw1P + (ks << 13) + (ct << 9) + bthr);
        }
    }

    char* p1w = s_tile + ((tid >> 5) * SROWB + k0p * 2);
    const char* aA = s_tile + (l15 * SROWB + g4 * 16);
    const char* aM = m_tile + (l15 * SROWB + g4 * 16);
    char* mwA = m_tile + ((g4 * 4) * SROWB + (colbase + l15) * 2);

    #pragma unroll 1
    for (int ir = 0; ir < 2; ++ir) {
        int ni = ni0 + ir;
        float aiv[8];
        {
            float4v a0 = *(const float4v*)(Ai + (size_t)ni * HH + k0p);
            float4v a1 = *(const float4v*)(Ai + (size_t)ni * HH + k0p + 4);
            #pragma unroll
            for (int e = 0; e < 4; ++e) { aiv[e] = a0[e]; aiv[4 + e] = a1[e]; }
        }
        float xi0 = x[ni * 3 + 0], xi1 = x[ni * 3 + 1], xi2 = x[ni * 3 + 2];
        float mgv[2] = {0.f, 0.f};
        float xd0 = 0.f, xd1 = 0.f, xd2 = 0.f;

        #pragma unroll 1
        for (int jc = 0; jc < 2; ++jc) {
            int j0 = jc * 128;
            __syncthreads();  // protect s_tile/m_tile/cwpart from previous iter readers

            // ---- phase 1: s tile = silu(Ai + Aj + d2*wd), d2 inline
            #pragma unroll
            for (int it = 0; it < 8; ++it) {
                int row = it * 16 + (tid >> 5);
                int j = bbase + j0 + row;
                float rx = xi0 - x[j * 3 + 0];
                float ry = xi1 - x[j * 3 + 1];
                float rz = xi2 - x[j * 3 + 2];
                float d2v = rx * rx + ry * ry + rz * rz;
                u32x4 ajw = *(const u32x4*)(AjB + ((size_t)j * HH + k0p));
                unsigned int uw0, uw1, uw2, uw3;
                uw0 = cvtpk(fsilu(aiv[0] + bflo(ajw[0]) + d2v * wdv[0]), fsilu(aiv[1] + bfhi(ajw[0]) + d2v * wdv[1]));
                uw1 = cvtpk(fsilu(aiv[2] + bflo(ajw[1]) + d2v * wdv[2]), fsilu(aiv[3] + bfhi(ajw[1]) + d2v * wdv[3]));
                uw2 = cvtpk(fsilu(aiv[4] + bflo(ajw[2]) + d2v * wdv[4]), fsilu(aiv[5] + bfhi(ajw[2]) + d2v * wdv[5]));
                uw3 = cvtpk(fsilu(aiv[6] + bflo(ajw[3]) + d2v * wdv[6]), fsilu(aiv[7] + bfhi(ajw[3]) + d2v * wdv[7]));
                u32x4 sv = {uw0, uw1, uw2, uw3};
                *reinterpret_cast<u32x4*>(p1w + it * 16 * SROWB) = sv;
            }
            __syncthreads();

            // ---- phase 2
            #pragma unroll 1
            for (int rh = 0; rh < 4; ++rh) {
                f32x4 acc[2][2];
                acc[0][0] = (f32x4){0.f,0.f,0.f,0.f}; acc[0][1] = (f32x4){0.f,0.f,0.f,0.f};
                acc[1][0] = (f32x4){0.f,0.f,0.f,0.f}; acc[1][1] = (f32x4){0.f,0.f,0.f,0.f};
                const char* aBase = aA + rh * 32 * SROWB;
                #pragma unroll
                for (int ks = 0; ks < 8; ++ks) {
                    bf16x8 a0 = *reinterpret_cast<const bf16x8*>(aBase + ks * 64);
                    bf16x8 a1 = *reinterpret_cast<const bf16x8*>(aBase + 16 * SROWB + ks * 64);
                    acc[0][0] = __builtin_amdgcn_mfma_f32_16x16x32_bf16(a0, Bew[ks][0], acc[0][0], 0, 0, 0);
                    acc[0][1] = __builtin_amdgcn_mfma_f32_16x16x32_bf16(a0, Bew[ks][1], acc[0][1], 0, 0, 0);
                    acc[1][0] = __builtin_amdgcn_mfma_f32_16x16x32_bf16(a1, Bew[ks][0], acc[1][0], 0, 0, 0);
                    acc[1][1] = __builtin_amdgcn_mfma_f32_16x16x32_bf16(a1, Bew[ks][1], acc[1][1], 0, 0, 0);
                }
                char* mw = mwA + rh * 32 * SROWB;
                #pragma unroll
                for (int rt = 0; rt < 2; ++rt) {
                    #pragma unroll
                    for (int r = 0; r < 4; ++r) {
                        float v0 = fsilu(acc[rt][0][r] + eb2r[0]);
                        float v1 = fsilu(acc[rt][1][r] + eb2r[1]);
                        mgv[0] += v0; mgv[1] += v1;
                        unsigned int w = cvtpk(v0, v1);
                        char* p = mw + (rt * 16 + r) * SROWB;
                        *reinterpret_cast<unsigned short*>(p) = (unsigned short)w;
                        *reinterpret_cast<unsigned short*>(p + 32) = (unsigned short)(w >> 16);
                    }
                }
            }
            __syncthreads();

            // ---- phase 3
            #pragma unroll 1
            for (int rh = 0; rh < 4; ++rh) {
                f32x4 acc[2][2];
                acc[0][0] = (f32x4){0.f,0.f,0.f,0.f}; acc[0][1] = (f32x4){0.f,0.f,0.f,0.f};
                acc[1][0] = (f32x4){0.f,0.f,0.f,0.f}; acc[1][1] = (f32x4){0.f,0.f,0.f,0.f};
                const char* aBase = aM + rh * 32 * SROWB;
                #pragma unroll
                for (int ks = 0; ks < 8; ++ks) {
                    bf16x8 a0 = *reinterpret_cast<const bf16x8*>(aBase + ks * 64);
                    bf16x8 a1 = *reinterpret_cast<const bf16x8*>(aBase + 16 * SROWB + ks * 64);
                    acc[0][0] = __builtin_amdgcn_mfma_f32_16x16x32_bf16(a0, Bcw[ks][0], acc[0][0], 0, 0, 0);
                    acc[0][1] = __builtin_amdgcn_mfma_f32_16x16x32_bf16(a0, Bcw[ks][1], acc[0][1], 0, 0, 0);
                    acc[1][0] = __builtin_amdgcn_mfma_f32_16x16x32_bf16(a1, Bcw[ks][0], acc[1][0], 0, 0, 0);
                    acc[1][1] = __builtin_amdgcn_mfma_f32_16x16x32_bf16(a1, Bcw[ks][1], acc[1][1], 0, 0, 0);
                }
                float rs[8];
                #pragma unroll
                for (int q = 0; q < 8; ++q) rs[q] = 0.f;
                #pragma unroll
                for (int ct = 0; ct < 2; ++ct) {
                    #pragma unroll
                    for (int rt = 0; rt < 2; ++rt)
                        #pragma unroll
                        for (int r = 0; r < 4; ++r)
                            rs[rt * 4 + r] += fsilu(acc[rt][ct][r] + cb1r[ct]) * cw2r[ct];
                }
                #pragma unroll
                for (int m = 1; m <= 8; m <<= 1)
                    #pragma unroll
                    for (int q = 0; q < 8; ++q) rs[q] += __shfl_xor(rs[q], m);
                if (l15 == 0) {
                    #pragma unroll
                    for (int rt = 0; rt < 2; ++rt)
                        #pragma unroll
                        for (int r = 0; r < 4; ++r)
                            cwpart[wv][rh * 32 + rt * 16 + g4 * 4 + r] = rs[rt * 4 + r];
                }
            }
            __syncthreads();
            if (tid < 64) {
                #pragma unroll 1
                for (int q = 0; q < 2; ++q) {
                    int lr = q * 64 + tid;
                    float cwv = cb2;
                    #pragma unroll
                    for (int w = 0; w < 8; ++w) cwv += cwpart[w][lr];
                    int j = bbase + j0 + lr;
                    float p0 = (xi0 - x[j * 3 + 0]) * cwv;
                    float p1 = (xi1 - x[j * 3 + 1]) * cwv;
                    float p2 = (xi2 - x[j * 3 + 2]) * cwv;
                    #pragma unroll
                    for (int m = 1; m < 64; m <<= 1) {
                        p0 += __shfl_xor(p0, m); p1 += __shfl_xor(p1, m); p2 += __shfl_xor(p2, m);
                    }
                    xd0 += p0; xd1 += p1; xd2 += p2;
                }
            }
        }

        // per-row epilogue: magg -> LDS, x update -> ping-pong
        #pragma unroll
        for (int ct = 0; ct < 2; ++ct) {
            mgv[ct] += __shfl_xor(mgv[ct], 16);
            mgv[ct] += __shfl_xor(mgv[ct], 32);
        }
        if (lane < 16) {
            smagg2[ir][colbase + lane] = mgv[0];
            smagg2[ir][colbase + 16 + lane] = mgv[1];
        }
        if (has_ln && tid == 0) {
            xnext[ni * 3 + 0] = xi0 + xd0 * (1.0f / NN);
            xnext[ni * 3 + 1] = xi1 + xd1 * (1.0f / NN);
            xnext[ni * 3 + 2] = xi2 + xd2 * (1.0f / NN);
        }
    }
    __syncthreads();

    // ================= 2-row fused tail =================
    float* s2T   = (float*)s_tile;            // [512][2]
    float* part0 = (float*)(s_tile + 4096);   // [512]
    float* part1 = (float*)(s_tile + 6144);   // [512]
    float* suT   = (float*)(s_tile + 8192);   // [256][2]
    float* shrow = (float*)(s_tile + 10240);  // [256][2]
    float* shnT  = (float*)(s_tile + 12288);  // [256][2]

    if (tid < 256) {
        s2T[tid * 2 + 0] = hn[(size_t)ni0 * HH + tid];
        s2T[tid * 2 + 1] = hn[(size_t)ni1 * HH + tid];
        s2T[(HH + tid) * 2 + 0] = smagg2[0][tid];
        s2T[(HH + tid) * 2 + 1] = smagg2[1][tid];
    }
    __syncthreads();
    {   // u = silu(nw1 . [hn;magg] + nb1), col x k-half split, dual-acc
        int col = tid & 255, kh = tid >> 8;
        const unsigned int* w = nw1w + (kh * 128) * 256;
        const float* sv = s2T + kh * 512;
        float p0a = 0.f, p1a = 0.f, p0b = 0.f, p1b = 0.f;
        #pragma unroll 4
        for (int c2 = 0; c2 < 128; c2 += 2) {
            unsigned int wpA = w[c2 * 256 + col];
            unsigned int wpB = w[(c2 + 1) * 256 + col];
            float4 sA = *(const float4*)&sv[c2 * 4];
            float4 sB = *(const float4*)&sv[c2 * 4 + 4];
            p0a += sA.x * bflo(wpA) + sA.z * bfhi(wpA);
            p1a += sA.y * bflo(wpA) + sA.w * bfhi(wpA);
            p0b += sB.x * bflo(wpB) + sB.z * bfhi(wpB);
            p1b += sB.y * bflo(wpB) + sB.w * bfhi(wpB);
        }
        part0[tid] = p0a + p0b; part1[tid] = p1a + p1b;
    }
    __syncthreads();
    if (tid < 256) {
        float bb = nb1l[tid];
        suT[tid * 2 + 0] = fsilu(part0[tid] + part0[256 + tid] + bb);
        suT[tid * 2 + 1] = fsilu(part1[tid] + part1[256 + tid] + bb);
    }
    __syncthreads();
    {   // d = nw2 . u + nb2, dual-acc
        int col = tid & 255, kh = tid >> 8;
        const unsigned int* w = nw2w + (kh * 64) * 256;
        const float* sv = suT + kh * 256;
        float p0a = 0.f, p1a = 0.f, p0b = 0.f, p1b = 0.f;
        #pragma unroll 4
        for (int c2 = 0; c2 < 64; c2 += 2) {
            unsigned int wpA = w[c2 * 256 + col];
            unsigned int wpB = w[(c2 + 1) * 256 + col];
            float4 sA = *(const float4*)&sv[c2 * 4];
            float4 sB = *(const float4*)&sv[c2 * 4 + 4];
            p0a += sA.x * bflo(wpA) + sA.z * bfhi(wpA);
            p1a += sA.y * bflo(wpA) + sA.w * bfhi(wpA);
            p0b += sB.x * bflo(wpB) + sB.z * bfhi(wpB);
            p1b += sB.y * bflo(wpB) + sB.w * bfhi(wpB);
        }
        part0[tid] = p0a + p0b; part1[tid] = p1a + p1b;
    }
    __syncthreads();
    if (tid < 256) {
        float bb = nb2l[tid];
        float h0v = h[(size_t)ni0 * HH + tid] + part0[tid] + part0[256 + tid] + bb;
        float h1v = h[(size_t)ni1 * HH + tid] + part1[tid] + part1[256 + tid] + bb;
        h[(size_t)ni0 * HH + tid] = h0v;
        h[(size_t)ni1 * HH + tid] = h1v;
        shrow[tid * 2 + 0] = h0v;
        shrow[tid * 2 + 1] = h1v;
    }
    __syncthreads();
    if (!has_ln) return;

    if (wv < 2) {  // LN per row (wave wv handles row wv)
        float v[4];
        #pragma unroll
        for (int q = 0; q < 4; ++q) v[q] = shrow[(lane + 64 * q) * 2 + wv];
        float s = v[0] + v[1] + v[2] + v[3];
        #pragma unroll
        for (int m = 1; m < 64; m <<= 1) s += __shfl_xor(s, m);
        float mu = s * (1.0f / HH);
        float var = 0.f;
        #pragma unroll
        for (int q = 0; q < 4; ++q) { v[q] -= mu; var += v[q] * v[q]; }
        #pragma unroll
        for (int m = 1; m < 64; m <<= 1) var += __shfl_xor(var, m);
        float rstd = rsqrtf(var * (1.0f / HH) + 1e-5f);
        #pragma unroll
        for (int q = 0; q < 4; ++q) {
            int k = lane + 64 * q;
            float hv = v[q] * rstd * gamv[k] + betv[k];
            shnT[k * 2 + wv] = hv;
            hn[(size_t)(ni0 + wv) * HH + k] = hv;
        }
    }
    __syncthreads();
    {   // next-layer Ai (hf 0) / Aj (hf 1), both rows, dual-acc
        int col = tid & 255, hf = tid >> 8;
        const unsigned int* w = ew1wn + (hf * 128) * 256;
        float p0a = (hf == 0) ? eb1n[col] : 0.f;
        float p1a = p0a;
        float p0b = 0.f, p1b = 0.f;
        #pragma unroll 4
        for (int c2 = 0; c2 < 128; c2 += 2) {
            unsigned int wpA = w[c2 * 256 + col];
            unsigned int wpB = w[(c2 + 1) * 256 + col];
            float4 sA = *(const float4*)&shnT[c2 * 4];
            float4 sB = *(const float4*)&shnT[c2 * 4 + 4];
            p0a += sA.x * bflo(wpA) + sA.z * bfhi(wpA);
            p1a += sA.y * bflo(wpA) + sA.w * bfhi(wpA);
            p0b += sB.x * bflo(wpB) + sB.z * bfhi(wpB);
            p1b += sB.y * bflo(wpB) + sB.w * bfhi(wpB);
        }
        float p0 = p0a + p0b, p1 = p1a + p1b;
        if (hf == 0) {
            Ainext[(size_t)ni0 * HH + col] = p0;
            Ainext[(size_t)ni1 * HH + col] = p1;
        } else {
            AjBnext[(size_t)ni0 * HH + col] = f2bf(p0);
            AjBnext[(size_t)ni1 * HH + col] = f2bf(p1);
        }
    }
}

// ---------------------------------------------------------------- decoder (2 rows/block)
__global__ __launch_bounds__(256) void k_decoder(
    const float* __restrict__ h,
    const float* __restrict__ dw1, const float* __restrict__ db1,
    const float* __restrict__ dw2, const float* __restrict__ db2,
    const float* __restrict__ dw3, const float* __restrict__ db3,
    float* __restrict__ out) {
    __shared__ float shT[HH][2];
    __shared__ float so1T[HH][2];
    __shared__ float so2T[HH][2];
    int tid = threadIdx.x;
    int base = blockIdx.x * 2;
    #pragma unroll
    for (int r = 0; r < 2; ++r) shT[tid][r] = h[(base + r) * HH + tid];
    __syncthreads();
    float a0 = db1[tid], a1 = a0;
    for (int c = 0; c < HH; ++c) {
        float w = dw1[c * HH + tid];
        float2 s = *(const float2*)&shT[c][0];
        a0 += s.x * w; a1 += s.y * w;
    }
    so1T[tid][0] = fmaxf(a0, 0.f); so1T[tid][1] = fmaxf(a1, 0.f);
    __syncthreads();
    a0 = db2[tid]; a1 = a0;
    for (int c = 0; c < HH; ++c) {
        float w = dw2[c * HH + tid];
        float2 s = *(const float2*)&so1T[c][0];
        a0 += s.x * w; a1 += s.y * w;
    }
    so2T[tid][0] = fmaxf(a0, 0.f) + shT[tid][0];
    so2T[tid][1] = fmaxf(a1, 0.f) + shT[tid][1];
    __syncthreads();
    if (tid < 6) {
        int r = tid / 3, c = tid % 3;
        float acc = db3[c];
        for (int k = 0; k < HH; ++k) acc += so2T[k][r] * dw3[k * 3 + c];
        out[(base + r) * 3 + c] = acc;
    }
}

// ---------------------------------------------------------------- launch
extern "C" void kernel_launch(void* const* d_in, const int* in_sizes, int n_in,
                              void* d_out, int out_size, void* d_ws, size_t ws_size,
                              hipStream_t stream) {
    const float* coords = (const float*)d_in[0];
    const float* feats  = (const float*)d_in[1];
    const float* t      = (const float*)d_in[2];
    const float* pe_w1  = (const float*)d_in[3];  const float* pe_b1 = (const float*)d_in[4];
    const float* pe_w2  = (const float*)d_in[5];  const float* pe_b2 = (const float*)d_in[6];
    const float* pe_w3  = (const float*)d_in[7];  const float* pe_b3 = (const float*)d_in[8];
    const float* te_w1  = (const float*)d_in[9];  const float* te_b1 = (const float*)d_in[10];
    const float* te_w2  = (const float*)d_in[11]; const float* te_b2 = (const float*)d_in[12];
    const float* ln_g   = (const float*)d_in[13]; const float* ln_b  = (const float*)d_in[14];
    const float* ew1    = (const float*)d_in[15]; const float* eb1   = (const float*)d_in[16];
    const float* ew2    = (const float*)d_in[17]; const float* eb2   = (const float*)d_in[18];
    const float* cw1    = (const float*)d_in[19]; const float* cb1   = (const float*)d_in[20];
    const float* cw2    = (const float*)d_in[21]; const float* cb2   = (const float*)d_in[22];
    const float* nw1    = (const float*)d_in[23]; const float* nb1   = (const float*)d_in[24];
    const float* nw2    = (const float*)d_in[25]; const float* nb2   = (const float*)d_in[26];
    const float* dec_w1 = (const float*)d_in[27]; const float* dec_b1 = (const float*)d_in[28];
    const float* dec_w2 = (const float*)d_in[29]; const float* dec_b2 = (const float*)d_in[30];
    const float* dec_w3 = (const float*)d_in[31]; const float* dec_b3 = (const float*)d_in[32];

    float* ws = (float*)d_ws;
    float* h    = ws;
    float* hn   = ws + RN;
    float* Ai0  = ws + 2 * RN;
    float* Ai1  = ws + 3 * RN;
    float* xb0  = ws + 4 * RN;              // 1536 (reserve 2048)
    float* xb1  = ws + 4 * RN + 2048;       // 1536 (reserve 2048)
    unsigned short* Aj0  = (unsigned short*)(ws + 4 * RN + 4096);
    unsigned short* Aj1  = Aj0 + RN;
    unsigned short* ew2P = Aj1 + RN;                       // LL*65536
    unsigned short* cw1P = ew2P + LL * HH * HH;            // LL*65536
    unsigned short* nw1B = cw1P + LL * HH * HH;            // LL*131072
    unsigned short* ew1B = nw1B + LL * 2 * HH * HH;        // LL*131072
    unsigned short* nw2B = ew1B + LL * 2 * HH * HH;        // LL*65536

    k_convert<<<(LL * 8192 + 511) / 512, 512, 0, stream>>>(ew2, cw1, ew2P, cw1P);
    k_convert2<<<(LL * 131072 + 255) / 256, 256, 0, stream>>>(nw1, nw2, ew1, nw1B, nw2B, ew1B);
    k_encoder<<<NB * NN / 2, 256, 0, stream>>>(coords, feats, t,
        pe_w1, pe_b1, pe_w2, pe_b2, pe_w3, pe_b3, te_w1, te_b1, te_w2, te_b2, h, xb0);
    k_ln_aiaj<<<NB * NN / 2, 256, 0, stream>>>(h, ln_g, ln_b,
        (const unsigned int*)ew1B, eb1, hn, Ai0, Aj0);

    for (int l = 0; l < LL; ++l) {
        const float* xin = (l & 1) ? xb1 : xb0;
        float* xout      = (l & 1) ? xb0 : xb1;
        const float* AiIn = (l & 1) ? Ai1 : Ai0;
        float* AiOut      = (l & 1) ? Ai0 : Ai1;
        const unsigned short* AjIn = (l & 1) ? Aj1 : Aj0;
        unsigned short* AjOut      = (l & 1) ? Aj0 : Aj1;
        int ln = (l + 1 < LL) ? (l + 1) : LL - 1;  // tail params unused when has_ln=0
        k_edge<<<NB * NN / 2, 512, 0, stream>>>(xin, AiIn, AjIn,
            ew1 + ((size_t)l * 513 + 512) * HH, eb2 + l * HH,
            ew2P + (size_t)l * HH * HH, cw1P + (size_t)l * HH * HH,
            cb1 + l * HH, cw2 + l * HH, cb2 + l,
            h, hn, xout, AiOut, AjOut,
            (const unsigned int*)(nw1B + (size_t)l * 2 * HH * HH), nb1 + l * HH,
            (const unsigned int*)(nw2B + (size_t)l * HH * HH), nb2 + l * HH,
            ln_g + ln * HH, ln_b + ln * HH,
            (const unsigned int*)(ew1B + (size_t)ln * 2 * HH * HH), eb1 + ln * HH,
            (l + 1 < LL) ? 1 : 0);
    }

    k_decoder<<<NB * NN / 2, 256, 0, stream>>>(h, dec_w1, dec_b1, dec_w2, dec_b2,
                                               dec_w3, dec_b3, (float*)d_out);
}